// Round 1
// baseline (441.188 us; speedup 1.0000x reference)
//
#include <hip/hip_runtime.h>
#include <hip/hip_bf16.h>
#include <math.h>

#define BB 4
#define CC 512
#define HH 32
#define WW 32
#define HW 1024
#define NH 8
#define HC 64
#define NPT 1024
#define RPE_W 63

// ---------------------------------------------------------------------------
// C[b][o][p] = sum_c A[o][c] * B[b][c][p] + bias[o];  O=K=512, P=1024
// grid (P/64, O/64, B), block 256, 64x64 tile, 4x4 micro
// ---------------------------------------------------------------------------
__global__ __launch_bounds__(256) void gemm_proj(
    const float* __restrict__ A, const float* __restrict__ bias,
    const float* __restrict__ Bm, float* __restrict__ Cm)
{
    __shared__ float As[16][68];
    __shared__ float Bs[16][64];
    int b = blockIdx.z;
    int p0 = blockIdx.x * 64, o0 = blockIdx.y * 64;
    int t = threadIdx.x;
    int to = t >> 4, tp = t & 15;
    const float* Bb = Bm + (size_t)b * (CC * 1024);
    float acc[4][4] = {};
    for (int kt = 0; kt < 32; ++kt) {
        int c0 = kt * 16;
        #pragma unroll
        for (int i = 0; i < 4; ++i) {
            int e = t + i * 256;
            int ol = e >> 4, cl = e & 15;
            As[cl][ol] = A[(o0 + ol) * 512 + c0 + cl];
            int cb = e >> 6, pb = e & 63;
            Bs[cb][pb] = Bb[(c0 + cb) * 1024 + p0 + pb];
        }
        __syncthreads();
        #pragma unroll
        for (int c = 0; c < 16; ++c) {
            const float4 av = *(const float4*)&As[c][to * 4];
            const float4 bv = *(const float4*)&Bs[c][tp * 4];
            float a4[4] = {av.x, av.y, av.z, av.w};
            float b4[4] = {bv.x, bv.y, bv.z, bv.w};
            #pragma unroll
            for (int i = 0; i < 4; ++i)
                #pragma unroll
                for (int j = 0; j < 4; ++j)
                    acc[i][j] += a4[i] * b4[j];
        }
        __syncthreads();
    }
    #pragma unroll
    for (int i = 0; i < 4; ++i) {
        int o = o0 + to * 4 + i;
        float bs = bias[o];
        #pragma unroll
        for (int j = 0; j < 4; ++j)
            Cm[(size_t)b * (CC * 1024) + (size_t)o * 1024 + p0 + tp * 4 + j] = acc[i][j] + bs;
    }
}

// ---------------------------------------------------------------------------
// offset network: dwconv3x3 -> channel LN -> exact GELU -> 1x1 to 2ch
// -> tanh * 0.0625 + reference points -> pos[b][p][2] (y,x)
// one block (256 thr) per (b, p); each thread handles 2 channels
// ---------------------------------------------------------------------------
__global__ __launch_bounds__(256) void offset_kernel(
    const float* __restrict__ q, const float* __restrict__ dw_w,
    const float* __restrict__ dw_b, const float* __restrict__ ln_w,
    const float* __restrict__ ln_b, const float* __restrict__ pw_w,
    float* __restrict__ pos)
{
    __shared__ float red[8];
    int bid = blockIdx.x;
    int b = bid >> 10, p = bid & 1023;
    int y = p >> 5, x = p & 31;
    const float* qb = q + (size_t)b * (CC * HW);
    int t = threadIdx.x;
    float h[2];
    #pragma unroll
    for (int j = 0; j < 2; ++j) {
        int c = t + j * 256;
        const float* qc = qb + (size_t)c * HW;
        const float* wc = dw_w + c * 9;
        float s = 0.f;
        #pragma unroll
        for (int ky = 0; ky < 3; ++ky) {
            int yy = y + ky - 1;
            if (yy < 0 || yy > 31) continue;
            #pragma unroll
            for (int kx = 0; kx < 3; ++kx) {
                int xx = x + kx - 1;
                if (xx < 0 || xx > 31) continue;
                s += qc[yy * 32 + xx] * wc[ky * 3 + kx];
            }
        }
        h[j] = s + dw_b[c];
    }
    float ls = h[0] + h[1];
    float lq = h[0] * h[0] + h[1] * h[1];
    #pragma unroll
    for (int s = 32; s >= 1; s >>= 1) {
        ls += __shfl_xor(ls, s);
        lq += __shfl_xor(lq, s);
    }
    int wid = t >> 6, lane = t & 63;
    if (lane == 0) { red[wid] = ls; red[4 + wid] = lq; }
    __syncthreads();
    float mu  = (red[0] + red[1] + red[2] + red[3]) * (1.f / 512.f);
    float var = (red[4] + red[5] + red[6] + red[7]) * (1.f / 512.f) - mu * mu;
    float rstd = rsqrtf(var + 1e-5f);
    float o0 = 0.f, o1 = 0.f;
    #pragma unroll
    for (int j = 0; j < 2; ++j) {
        int c = t + j * 256;
        float hn = (h[j] - mu) * rstd * ln_w[c] + ln_b[c];
        float g = 0.5f * hn * (1.f + erff(hn * 0.70710678118f));
        o0 += g * pw_w[c];
        o1 += g * pw_w[512 + c];
    }
    #pragma unroll
    for (int s = 32; s >= 1; s >>= 1) {
        o0 += __shfl_xor(o0, s);
        o1 += __shfl_xor(o1, s);
    }
    __syncthreads();
    if (lane == 0) { red[wid] = o0; red[4 + wid] = o1; }
    __syncthreads();
    if (t == 0) {
        float oy = tanhf(red[0] + red[1] + red[2] + red[3]) * 0.0625f;
        float ox = tanhf(red[4] + red[5] + red[6] + red[7]) * 0.0625f;
        float ry = ((y + 0.5f) * (1.f / 32.f)) * 2.f - 1.f;
        float rx = ((x + 0.5f) * (1.f / 32.f)) * 2.f - 1.f;
        pos[bid * 2]     = oy + ry;
        pos[bid * 2 + 1] = ox + rx;
    }
}

// ---------------------------------------------------------------------------
// bilinear grid sample of x at pos -> x_sampled[b][c][p]
// grid (NPT/256, B*C), block 256, thread = one (b,c,p)
// ---------------------------------------------------------------------------
__global__ __launch_bounds__(256) void sample_kernel(
    const float* __restrict__ x, const float* __restrict__ pos,
    float* __restrict__ xs)
{
    int p = blockIdx.x * 256 + threadIdx.x;
    int bc = blockIdx.y;
    int b = bc >> 9, c = bc & 511;
    float py = pos[(b * 1024 + p) * 2];
    float px = pos[(b * 1024 + p) * 2 + 1];
    float gx = (px + 1.f) * 15.5f;
    float gy = (py + 1.f) * 15.5f;
    float x0f = floorf(gx), y0f = floorf(gy);
    int ix0 = (int)x0f, iy0 = (int)y0f;
    float wx1 = gx - x0f, wx0 = 1.f - wx1;
    float wy1 = gy - y0f, wy0 = 1.f - wy1;
    const float* xb = x + (size_t)(b * 512 + c) * 1024;
    auto tap = [&](int ix, int iy) -> float {
        return (ix >= 0 && ix < 32 && iy >= 0 && iy < 32) ? xb[iy * 32 + ix] : 0.f;
    };
    float acc = tap(ix0, iy0) * wx0 * wy0
              + tap(ix0 + 1, iy0) * wx1 * wy0
              + tap(ix0, iy0 + 1) * wx0 * wy1
              + tap(ix0 + 1, iy0 + 1) * wx1 * wy1;
    xs[(size_t)(b * 512 + c) * 1024 + p] = acc;
}

// ---------------------------------------------------------------------------
// attention logits + RPE bias + softmax; writes attn (post-softmax) to d_out
// block = (b, h, 16-row m-tile); thread owns 4 columns (nn); K=64 (hc)
// ---------------------------------------------------------------------------
__global__ __launch_bounds__(256) void attn_kernel(
    const float* __restrict__ q, const float* __restrict__ k,
    const float* __restrict__ pos, const float* __restrict__ rpe,
    float* __restrict__ attn_out)
{
    __shared__ float q_s[64][16];
    __shared__ float a_s[16][1024];
    int bid = blockIdx.x;
    int mt = bid & 63;
    int h  = (bid >> 6) & 7;
    int b  = bid >> 9;
    int m0 = mt * 16;
    int t = threadIdx.x;
    #pragma unroll
    for (int i = 0; i < 4; ++i) {
        int e = t + i * 256;
        int ch = e >> 4, m = e & 15;
        q_s[ch][m] = q[(size_t)(b * 512 + h * 64 + ch) * 1024 + m0 + m];
    }
    __syncthreads();
    int nn0 = t * 4;
    float posy[4], posx[4];
    #pragma unroll
    for (int j = 0; j < 4; ++j) {
        posy[j] = pos[(b * 1024 + nn0 + j) * 2];
        posx[j] = pos[(b * 1024 + nn0 + j) * 2 + 1];
    }
    float acc[16][4] = {};
    const float* kb = k + (size_t)(b * 512 + h * 64) * 1024;
    for (int ch = 0; ch < 64; ++ch) {
        const float4 kv4 = *(const float4*)&kb[ch * 1024 + nn0];
        float kv[4] = {kv4.x, kv4.y, kv4.z, kv4.w};
        #pragma unroll
        for (int mg = 0; mg < 4; ++mg) {
            const float4 qv = *(const float4*)&q_s[ch][mg * 4];
            float q4[4] = {qv.x, qv.y, qv.z, qv.w};
            #pragma unroll
            for (int mi = 0; mi < 4; ++mi)
                #pragma unroll
                for (int j = 0; j < 4; ++j)
                    acc[mg * 4 + mi][j] += q4[mi] * kv[j];
        }
    }
    const float* rh = rpe + h * (RPE_W * RPE_W);
    auto rtap = [&](int ix, int iy) -> float {
        return (ix >= 0 && ix < RPE_W && iy >= 0 && iy < RPE_W) ? rh[iy * RPE_W + ix] : 0.f;
    };
    #pragma unroll
    for (int m = 0; m < 16; ++m) {
        int mg = m0 + m;
        float qy = ((mg >> 5) + 0.5f) * (2.f / 32.f) - 1.f;
        float qx = ((mg & 31) + 0.5f) * (2.f / 32.f) - 1.f;
        #pragma unroll
        for (int j = 0; j < 4; ++j) {
            float dy = (qy - posy[j]) * 0.5f;
            float dx = (qx - posx[j]) * 0.5f;
            float gx = (dx + 1.f) * 31.f;
            float gy = (dy + 1.f) * 31.f;
            float x0f = floorf(gx), y0f = floorf(gy);
            int ix0 = (int)x0f, iy0 = (int)y0f;
            float wx1 = gx - x0f, wx0 = 1.f - wx1;
            float wy1 = gy - y0f, wy0 = 1.f - wy1;
            float bias = rtap(ix0, iy0) * wx0 * wy0
                       + rtap(ix0 + 1, iy0) * wx1 * wy0
                       + rtap(ix0, iy0 + 1) * wx0 * wy1
                       + rtap(ix0 + 1, iy0 + 1) * wx1 * wy1;
            a_s[m][nn0 + j] = acc[m][j] * 0.125f + bias;
        }
    }
    __syncthreads();
    int wid = t >> 6, lane = t & 63;
    int bh = b * 8 + h;
    #pragma unroll
    for (int r = 0; r < 4; ++r) {
        int m = wid * 4 + r;
        float v[16];
        float mx = -1e30f;
        #pragma unroll
        for (int j = 0; j < 16; ++j) {
            v[j] = a_s[m][lane + 64 * j];
            mx = fmaxf(mx, v[j]);
        }
        #pragma unroll
        for (int s = 32; s >= 1; s >>= 1) mx = fmaxf(mx, __shfl_xor(mx, s));
        float sum = 0.f;
        #pragma unroll
        for (int j = 0; j < 16; ++j) { v[j] = expf(v[j] - mx); sum += v[j]; }
        #pragma unroll
        for (int s = 32; s >= 1; s >>= 1) sum += __shfl_xor(sum, s);
        float inv = 1.f / sum;
        float* po = attn_out + ((size_t)bh * 1024 + m0 + m) * 1024;
        #pragma unroll
        for (int j = 0; j < 16; ++j) po[lane + 64 * j] = v[j] * inv;
    }
}

// ---------------------------------------------------------------------------
// out[b, h*64+ch, m] = gamma * sum_nn attn[bh, m, nn] * v[b, h*64+ch, nn] + x
// grid (16 m-tiles, 32 bh), block 256, 64x64 tile (m x ch), 4x4 micro
// ---------------------------------------------------------------------------
__global__ __launch_bounds__(256) void pv_kernel(
    const float* __restrict__ attn, const float* __restrict__ v,
    const float* __restrict__ x, const float* __restrict__ gamma,
    float* __restrict__ out0)
{
    __shared__ float As[16][68];
    __shared__ float Bs[16][68];
    int bh = blockIdx.y;
    int b = bh >> 3, h = bh & 7;
    int m0 = blockIdx.x * 64;
    int t = threadIdx.x;
    int tm = t >> 4, tc = t & 15;
    const float* Ab = attn + (size_t)bh * 1024 * 1024;
    const float* Vb = v + (size_t)(b * 512 + h * 64) * 1024;
    float acc[4][4] = {};
    for (int kt = 0; kt < 64; ++kt) {
        int n0 = kt * 16;
        #pragma unroll
        for (int i = 0; i < 4; ++i) {
            int e = t + i * 256;
            int ml = e >> 4, nl = e & 15;
            As[nl][ml] = Ab[(size_t)(m0 + ml) * 1024 + n0 + nl];
            Bs[nl][ml] = Vb[(size_t)ml * 1024 + n0 + nl];
        }
        __syncthreads();
        #pragma unroll
        for (int n = 0; n < 16; ++n) {
            const float4 av = *(const float4*)&As[n][tm * 4];
            const float4 bv = *(const float4*)&Bs[n][tc * 4];
            float a4[4] = {av.x, av.y, av.z, av.w};
            float b4[4] = {bv.x, bv.y, bv.z, bv.w};
            #pragma unroll
            for (int i = 0; i < 4; ++i)
                #pragma unroll
                for (int j = 0; j < 4; ++j)
                    acc[i][j] += a4[i] * b4[j];
        }
        __syncthreads();
    }
    float g = gamma[0];
    #pragma unroll
    for (int j = 0; j < 4; ++j) {
        int o = h * 64 + tc * 4 + j;
        size_t idx = (size_t)(b * 512 + o) * 1024 + m0 + tm * 4;
        const float4 xv = *(const float4*)&x[idx];
        float4 ov;
        ov.x = g * acc[0][j] + xv.x;
        ov.y = g * acc[1][j] + xv.y;
        ov.z = g * acc[2][j] + xv.z;
        ov.w = g * acc[3][j] + xv.w;
        *(float4*)&out0[idx] = ov;
    }
}

extern "C" void kernel_launch(void* const* d_in, const int* in_sizes, int n_in,
                              void* d_out, int out_size, void* d_ws, size_t ws_size,
                              hipStream_t stream) {
    const float* x     = (const float*)d_in[0];
    const float* dw_w  = (const float*)d_in[1];
    const float* dw_b  = (const float*)d_in[2];
    const float* ln_w  = (const float*)d_in[3];
    const float* ln_b  = (const float*)d_in[4];
    const float* pw_w  = (const float*)d_in[5];
    const float* q_w   = (const float*)d_in[6];
    const float* q_b   = (const float*)d_in[7];
    const float* k_w   = (const float*)d_in[8];
    const float* k_b   = (const float*)d_in[9];
    const float* v_w   = (const float*)d_in[10];
    const float* v_b   = (const float*)d_in[11];
    const float* rpe   = (const float*)d_in[12];
    const float* gamma = (const float*)d_in[13];

    float* out0 = (float*)d_out;
    float* attn = out0 + (size_t)BB * CC * HW;   // 2,097,152 floats

    float* ws  = (float*)d_ws;
    float* qb  = ws;                       // [4,512,1024]
    float* xs  = qb  + 2097152;            // x_sampled
    float* kb  = xs  + 2097152;
    float* vb  = kb  + 2097152;
    float* pos = vb  + 2097152;            // [4,1024,2]

    gemm_proj<<<dim3(16, 8, 4), 256, 0, stream>>>(q_w, q_b, x, qb);
    offset_kernel<<<4096, 256, 0, stream>>>(qb, dw_w, dw_b, ln_w, ln_b, pw_w, pos);
    sample_kernel<<<dim3(4, 2048), 256, 0, stream>>>(x, pos, xs);
    gemm_proj<<<dim3(16, 8, 4), 256, 0, stream>>>(k_w, k_b, xs, kb);
    gemm_proj<<<dim3(16, 8, 4), 256, 0, stream>>>(v_w, v_b, xs, vb);
    attn_kernel<<<2048, 256, 0, stream>>>(qb, kb, pos, rpe, attn);
    pv_kernel<<<dim3(16, 32), 256, 0, stream>>>(attn, vb, x, gamma, out0);
}

// Round 2
// 226.671 us; speedup vs baseline: 1.9464x; 1.9464x over previous
//
#include <hip/hip_runtime.h>
#include <hip/hip_bf16.h>
#include <math.h>

typedef short bf16x8 __attribute__((ext_vector_type(8)));
typedef float f32x4 __attribute__((ext_vector_type(4)));
typedef _Float16 h2 __attribute__((ext_vector_type(2)));

__device__ inline short f2bf(float f) {
    union { float f; unsigned u; } v; v.f = f;
    unsigned r = v.u + 0x7FFFu + ((v.u >> 16) & 1u);
    return (short)(r >> 16);
}
__device__ inline float bf2f(short s) {
    union { unsigned u; float f; } v; v.u = ((unsigned)(unsigned short)s) << 16;
    return v.f;
}

// ---------------------------------------------------------------------------
// transpose-cast: x [b][c][p] f32 -> xt [b][p][c] bf16
// ---------------------------------------------------------------------------
__global__ __launch_bounds__(256) void prep_x(const float* __restrict__ x,
                                              short* __restrict__ xt)
{
    __shared__ float ts[64][65];
    int p0 = blockIdx.x * 64, c0 = blockIdx.y * 64, b = blockIdx.z;
    int t = threadIdx.x;
    #pragma unroll
    for (int i = 0; i < 16; ++i) {
        int idx = i * 256 + t;
        int cl = idx >> 6, pl = idx & 63;
        ts[cl][pl] = x[((size_t)(b * 512 + c0 + cl)) * 1024 + p0 + pl];
    }
    __syncthreads();
    #pragma unroll
    for (int i = 0; i < 16; ++i) {
        int idx = i * 256 + t;
        int pl = idx >> 6, cl = idx & 63;
        xt[((size_t)(b * 1024 + p0 + pl)) * 512 + c0 + cl] = f2bf(ts[cl][pl]);
    }
}

// cast 3 weight matrices [512][512] f32 -> bf16
__global__ __launch_bounds__(256) void wcast(
    const float* __restrict__ qw, const float* __restrict__ kw,
    const float* __restrict__ vw, short* __restrict__ qwb,
    short* __restrict__ kwb, short* __restrict__ vwb)
{
    int idx = (blockIdx.x * 256 + threadIdx.x) * 8;
    int w = idx >> 18;
    int off = idx & 262143;
    const float* src = (w == 0) ? qw : (w == 1) ? kw : vw;
    short* dst = (w == 0) ? qwb : (w == 1) ? kwb : vwb;
    float4 f0 = *(const float4*)(src + off);
    float4 f1 = *(const float4*)(src + off + 4);
    bf16x8 o;
    o[0] = f2bf(f0.x); o[1] = f2bf(f0.y); o[2] = f2bf(f0.z); o[3] = f2bf(f0.w);
    o[4] = f2bf(f1.x); o[5] = f2bf(f1.y); o[6] = f2bf(f1.z); o[7] = f2bf(f1.w);
    *(bf16x8*)(dst + off) = o;
}

// ---------------------------------------------------------------------------
// NT MFMA GEMM: D[m][n] = sum_k A[m][k]*B[n][k] + bias; K=512
// MODE 0: q (M=4096,N=512, bias[n], out f32 + bf16 at [m*512+n])
// MODE 1: k (M=4096,N=512, bias[n], out bf16 [m*512+n])
// MODE 2: v (M=512,N=1024, z-batched B, bias[m], out bf16 [(z*512+m)*1024+n])
// ---------------------------------------------------------------------------
template<int MODE>
__global__ __launch_bounds__(256) void gemm_nt(
    const short* __restrict__ A, const short* __restrict__ B,
    const float* __restrict__ bias, float* __restrict__ Of,
    short* __restrict__ Ob)
{
    constexpr int K = 512;
    __shared__ short As[128][32];
    __shared__ short Bs[128][32];
    int m0 = blockIdx.x * 128, n0 = blockIdx.y * 128;
    const short* Bp = (MODE == 2) ? (B + (size_t)blockIdx.z * 524288) : B;
    int t = threadIdx.x, wid = t >> 6, l = t & 63;
    int wm = wid >> 1, wn = wid & 1;
    f32x4 acc[4][4] = {};
    int srow = t >> 1, half = t & 1;
    int sw = (srow >> 1) & 3;
    int s0 = (half * 2) ^ sw, s1 = (half * 2 + 1) ^ sw;
    for (int k0 = 0; k0 < K; k0 += 32) {
        const int4 a0 = *(const int4*)(A + (size_t)(m0 + srow) * K + k0 + half * 16);
        const int4 a1 = *(const int4*)(A + (size_t)(m0 + srow) * K + k0 + half * 16 + 8);
        const int4 b0 = *(const int4*)(Bp + (size_t)(n0 + srow) * K + k0 + half * 16);
        const int4 b1 = *(const int4*)(Bp + (size_t)(n0 + srow) * K + k0 + half * 16 + 8);
        __syncthreads();
        *(int4*)&As[srow][s0 * 8] = a0;
        *(int4*)&As[srow][s1 * 8] = a1;
        *(int4*)&Bs[srow][s0 * 8] = b0;
        *(int4*)&Bs[srow][s1 * 8] = b1;
        __syncthreads();
        bf16x8 af[4], bfr[4];
        #pragma unroll
        for (int mt = 0; mt < 4; ++mt) {
            int r = wm * 64 + mt * 16 + (l & 15);
            af[mt] = *(const bf16x8*)&As[r][(((l >> 4)) ^ ((r >> 1) & 3)) * 8];
        }
        #pragma unroll
        for (int nt = 0; nt < 4; ++nt) {
            int r = wn * 64 + nt * 16 + (l & 15);
            bfr[nt] = *(const bf16x8*)&Bs[r][(((l >> 4)) ^ ((r >> 1) & 3)) * 8];
        }
        #pragma unroll
        for (int mt = 0; mt < 4; ++mt)
            #pragma unroll
            for (int nt = 0; nt < 4; ++nt)
                acc[mt][nt] = __builtin_amdgcn_mfma_f32_16x16x32_bf16(
                    af[mt], bfr[nt], acc[mt][nt], 0, 0, 0);
    }
    #pragma unroll
    for (int mt = 0; mt < 4; ++mt)
        #pragma unroll
        for (int nt = 0; nt < 4; ++nt)
            #pragma unroll
            for (int r = 0; r < 4; ++r) {
                int m = m0 + wm * 64 + mt * 16 + (l >> 4) * 4 + r;
                int n = n0 + wn * 64 + nt * 16 + (l & 15);
                float val = acc[mt][nt][r] + ((MODE == 2) ? bias[m] : bias[n]);
                if (MODE == 0) {
                    Of[(size_t)m * 512 + n] = val;
                    Ob[(size_t)m * 512 + n] = f2bf(val);
                } else if (MODE == 1) {
                    Ob[(size_t)m * 512 + n] = f2bf(val);
                } else {
                    Ob[((size_t)blockIdx.z * 512 + m) * 1024 + n] = f2bf(val);
                }
            }
}

// ---------------------------------------------------------------------------
// offset network (reads q fp32 in [b][p][c] layout) -> pos[b][p][2] (y,x)
// ---------------------------------------------------------------------------
__global__ __launch_bounds__(256) void offset_kernel(
    const float* __restrict__ qf, const float* __restrict__ dw_w,
    const float* __restrict__ dw_b, const float* __restrict__ ln_w,
    const float* __restrict__ ln_b, const float* __restrict__ pw_w,
    float* __restrict__ pos)
{
    __shared__ float red[8];
    int bid = blockIdx.x;
    int b = bid >> 10, p = bid & 1023;
    int y = p >> 5, x = p & 31;
    int t = threadIdx.x;
    float h[2];
    #pragma unroll
    for (int j = 0; j < 2; ++j) {
        int c = t + j * 256;
        const float* wc = dw_w + c * 9;
        float s = 0.f;
        #pragma unroll
        for (int ky = 0; ky < 3; ++ky) {
            int yy = y + ky - 1;
            if (yy < 0 || yy > 31) continue;
            #pragma unroll
            for (int kx = 0; kx < 3; ++kx) {
                int xx = x + kx - 1;
                if (xx < 0 || xx > 31) continue;
                s += qf[((size_t)(b * 1024 + yy * 32 + xx)) * 512 + c] * wc[ky * 3 + kx];
            }
        }
        h[j] = s + dw_b[c];
    }
    float ls = h[0] + h[1];
    float lq = h[0] * h[0] + h[1] * h[1];
    #pragma unroll
    for (int s = 32; s >= 1; s >>= 1) {
        ls += __shfl_xor(ls, s);
        lq += __shfl_xor(lq, s);
    }
    int wid = t >> 6, lane = t & 63;
    if (lane == 0) { red[wid] = ls; red[4 + wid] = lq; }
    __syncthreads();
    float mu  = (red[0] + red[1] + red[2] + red[3]) * (1.f / 512.f);
    float var = (red[4] + red[5] + red[6] + red[7]) * (1.f / 512.f) - mu * mu;
    float rstd = rsqrtf(var + 1e-5f);
    float o0 = 0.f, o1 = 0.f;
    #pragma unroll
    for (int j = 0; j < 2; ++j) {
        int c = t + j * 256;
        float hn = (h[j] - mu) * rstd * ln_w[c] + ln_b[c];
        float g = 0.5f * hn * (1.f + erff(hn * 0.70710678118f));
        o0 += g * pw_w[c];
        o1 += g * pw_w[512 + c];
    }
    #pragma unroll
    for (int s = 32; s >= 1; s >>= 1) {
        o0 += __shfl_xor(o0, s);
        o1 += __shfl_xor(o1, s);
    }
    __syncthreads();
    if (lane == 0) { red[wid] = o0; red[4 + wid] = o1; }
    __syncthreads();
    if (t == 0) {
        float oy = tanhf(red[0] + red[1] + red[2] + red[3]) * 0.0625f;
        float ox = tanhf(red[4] + red[5] + red[6] + red[7]) * 0.0625f;
        float ry = ((y + 0.5f) * (1.f / 32.f)) * 2.f - 1.f;
        float rx = ((x + 0.5f) * (1.f / 32.f)) * 2.f - 1.f;
        pos[bid * 2]     = oy + ry;
        pos[bid * 2 + 1] = ox + rx;
    }
}

// ---------------------------------------------------------------------------
// bilinear sample of xt (bf16 [b][p][c]) at pos -> xs bf16 [b][p][c]
// one block per (b,p); thread t handles channels 2t, 2t+1
// ---------------------------------------------------------------------------
__global__ __launch_bounds__(256) void sample_k(
    const short* __restrict__ xt, const float* __restrict__ pos,
    short* __restrict__ xs)
{
    int bid = blockIdx.x;
    int b = bid >> 10;
    float py = pos[bid * 2], px = pos[bid * 2 + 1];
    float gx = (px + 1.f) * 15.5f;
    float gy = (py + 1.f) * 15.5f;
    float x0f = floorf(gx), y0f = floorf(gy);
    int ix0 = (int)x0f, iy0 = (int)y0f;
    float wx1 = gx - x0f, wx0 = 1.f - wx1;
    float wy1 = gy - y0f, wy0 = 1.f - wy1;
    const short* base = xt + (size_t)b * 524288;
    int t = threadIdx.x;
    float a0 = 0.f, a1 = 0.f;
    #pragma unroll
    for (int tap = 0; tap < 4; ++tap) {
        int ix = ix0 + (tap & 1), iy = iy0 + (tap >> 1);
        float w = ((tap & 1) ? wx1 : wx0) * ((tap >> 1) ? wy1 : wy0);
        if (ix >= 0 && ix < 32 && iy >= 0 && iy < 32) {
            unsigned u = *(const unsigned*)(base + (size_t)(iy * 32 + ix) * 512 + 2 * t);
            a0 += bf2f((short)(u & 0xFFFF)) * w;
            a1 += bf2f((short)(u >> 16)) * w;
        }
    }
    unsigned o = ((unsigned)(unsigned short)f2bf(a0)) |
                 (((unsigned)(unsigned short)f2bf(a1)) << 16);
    *(unsigned*)(xs + (size_t)bid * 512 + 2 * t) = o;
}

// ---------------------------------------------------------------------------
// attention: QK^T (MFMA) + RPE bias + softmax -> attn fp32 [bh][m][n]
// grid (32 m-tiles, 8 h, 4 b); block 256 (4 waves: 2 m16-rows x 2 n-halves)
// pass A: logits -> LDS f16, accumulate sum(exp); pass B: normalize + write
// ---------------------------------------------------------------------------
__global__ __launch_bounds__(256) void attn_mfma(
    const short* __restrict__ qbf, const short* __restrict__ kbf,
    const float* __restrict__ pos, const float* __restrict__ rpe,
    float* __restrict__ attn_out)
{
    __shared__ _Float16 l_s[32][1024];
    __shared__ h2 pos_s[1024];
    __shared__ _Float16 rpe_s[3972];
    __shared__ float S_part[32][2];
    int mt_b = blockIdx.x, h = blockIdx.y, b = blockIdx.z;
    int m0 = mt_b * 32;
    int t = threadIdx.x, wid = t >> 6, l = t & 63;
    int wm = wid >> 1, wn = wid & 1;
    // stage pos (f16) and rpe head slice (f16)
    #pragma unroll
    for (int i = 0; i < 8; ++i) {
        int idx = i * 256 + t;
        ((_Float16*)pos_s)[idx] = (_Float16)pos[b * 2048 + idx];
    }
    const float* rh = rpe + h * 3969;
    for (int i = 0; i < 16; ++i) {
        int idx = i * 256 + t;
        if (idx < 3969) rpe_s[idx] = (_Float16)rh[idx];
    }
    // q fragments (reused across all n)
    int rowm = m0 + wm * 16 + (l & 15);
    const short* qrow = qbf + ((size_t)(b * 1024 + rowm) * 512 + h * 64 + (l >> 4) * 8);
    bf16x8 aq0 = *(const bf16x8*)qrow;
    bf16x8 aq1 = *(const bf16x8*)(qrow + 32);
    float qy[4], qx[4];
    #pragma unroll
    for (int r = 0; r < 4; ++r) {
        int rm = m0 + wm * 16 + (l >> 4) * 4 + r;
        qy[r] = ((rm >> 5) + 0.5f) * (1.f / 16.f) - 1.f;
        qx[r] = ((rm & 31) + 0.5f) * (1.f / 16.f) - 1.f;
    }
    __syncthreads();
    float Ssum[4] = {0.f, 0.f, 0.f, 0.f};
    for (int nt = 0; nt < 32; ++nt) {
        int n0 = wn * 512 + nt * 16;
        int col = n0 + (l & 15);
        const short* krow = kbf + ((size_t)(b * 1024 + col) * 512 + h * 64 + (l >> 4) * 8);
        bf16x8 bk0 = *(const bf16x8*)krow;
        bf16x8 bk1 = *(const bf16x8*)(krow + 32);
        f32x4 acc = {0.f, 0.f, 0.f, 0.f};
        acc = __builtin_amdgcn_mfma_f32_16x16x32_bf16(aq0, bk0, acc, 0, 0, 0);
        acc = __builtin_amdgcn_mfma_f32_16x16x32_bf16(aq1, bk1, acc, 0, 0, 0);
        h2 pp = pos_s[col];
        float py = (float)pp[0], px = (float)pp[1];
        #pragma unroll
        for (int r = 0; r < 4; ++r) {
            float dy = (qy[r] - py) * 0.5f;
            float dx = (qx[r] - px) * 0.5f;
            float gx = (dx + 1.f) * 31.f;
            float gy = (dy + 1.f) * 31.f;
            float x0f = floorf(gx), y0f = floorf(gy);
            int ix0 = (int)x0f, iy0 = (int)y0f;
            float wx1 = gx - x0f, wx0 = 1.f - wx1;
            float wy1 = gy - y0f, wy0 = 1.f - wy1;
            float b00 = (ix0 >= 0 && ix0 < 63 && iy0 >= 0 && iy0 < 63) ? (float)rpe_s[iy0 * 63 + ix0] : 0.f;
            float b10 = (ix0 + 1 >= 0 && ix0 + 1 < 63 && iy0 >= 0 && iy0 < 63) ? (float)rpe_s[iy0 * 63 + ix0 + 1] : 0.f;
            float b01 = (ix0 >= 0 && ix0 < 63 && iy0 + 1 >= 0 && iy0 + 1 < 63) ? (float)rpe_s[(iy0 + 1) * 63 + ix0] : 0.f;
            float b11 = (ix0 + 1 >= 0 && ix0 + 1 < 63 && iy0 + 1 >= 0 && iy0 + 1 < 63) ? (float)rpe_s[(iy0 + 1) * 63 + ix0 + 1] : 0.f;
            float bias = b00 * wx0 * wy0 + b10 * wx1 * wy0 + b01 * wx0 * wy1 + b11 * wx1 * wy1;
            float logit = acc[r] * 0.125f + bias;
            Ssum[r] += expf(logit);
            l_s[wm * 16 + (l >> 4) * 4 + r][col] = (_Float16)logit;
        }
    }
    #pragma unroll
    for (int s = 1; s < 16; s <<= 1)
        #pragma unroll
        for (int r = 0; r < 4; ++r) Ssum[r] += __shfl_xor(Ssum[r], s);
    if ((l & 15) == 0)
        #pragma unroll
        for (int r = 0; r < 4; ++r) S_part[wm * 16 + (l >> 4) * 4 + r][wn] = Ssum[r];
    __syncthreads();
    // pass B: each wave handles 8 rows; coalesced fp32 writes
    int bh = b * 8 + h;
    for (int rr = 0; rr < 8; ++rr) {
        int row = wid * 8 + rr;
        float invS = 1.f / (S_part[row][0] + S_part[row][1]);
        float* po = attn_out + ((size_t)(bh * 1024 + m0 + row)) * 1024;
        #pragma unroll
        for (int j = 0; j < 8; ++j) {
            int col = j * 128 + l * 2;
            h2 v = *(const h2*)&l_s[row][col];
            float e0 = expf((float)v[0]) * invS;
            float e1 = expf((float)v[1]) * invS;
            *(float2*)&po[col] = make_float2(e0, e1);
        }
    }
}

// ---------------------------------------------------------------------------
// PV: out[b][h*64+ch][m] = gamma * sum_n attn[bh][m][n]*v[ch][n] + x
// D[ch][m] via MFMA; grid (8 m-blocks, 8 h, 4 b); block 256
// ---------------------------------------------------------------------------
__global__ __launch_bounds__(256) void pv_mfma(
    const float* __restrict__ attn, const short* __restrict__ vbf,
    const float* __restrict__ x, const float* __restrict__ gamma,
    float* __restrict__ out0)
{
    __shared__ short Ps[128][32];
    __shared__ short Vs[64][32];
    int mb = blockIdx.x * 128, h = blockIdx.y, b = blockIdx.z;
    int t = threadIdx.x, wid = t >> 6, l = t & 63;
    int wc = wid >> 1, wm2 = wid & 1;
    const float* Ab = attn + (size_t)(b * 8 + h) * 1024 * 1024;
    const short* Vb = vbf + (size_t)(b * 512 + h * 64) * 1024;
    f32x4 acc[2][4] = {};
    int prow = t >> 1, phalf = t & 1;
    int psw = (prow >> 1) & 3;
    int ps0 = (phalf * 2) ^ psw, ps1 = (phalf * 2 + 1) ^ psw;
    for (int ks = 0; ks < 32; ++ks) {
        int n0 = ks * 32;
        const float* src = Ab + (size_t)(mb + prow) * 1024 + n0 + phalf * 16;
        float4 f0 = *(const float4*)src;
        float4 f1 = *(const float4*)(src + 4);
        float4 f2 = *(const float4*)(src + 8);
        float4 f3 = *(const float4*)(src + 12);
        bf16x8 p0, p1;
        p0[0] = f2bf(f0.x); p0[1] = f2bf(f0.y); p0[2] = f2bf(f0.z); p0[3] = f2bf(f0.w);
        p0[4] = f2bf(f1.x); p0[5] = f2bf(f1.y); p0[6] = f2bf(f1.z); p0[7] = f2bf(f1.w);
        p1[0] = f2bf(f2.x); p1[1] = f2bf(f2.y); p1[2] = f2bf(f2.z); p1[3] = f2bf(f2.w);
        p1[4] = f2bf(f3.x); p1[5] = f2bf(f3.y); p1[6] = f2bf(f3.z); p1[7] = f2bf(f3.w);
        int4 v0, v1;
        if (t < 128) {
            v0 = *(const int4*)(Vb + (size_t)prow * 1024 + n0 + phalf * 16);
            v1 = *(const int4*)(Vb + (size_t)prow * 1024 + n0 + phalf * 16 + 8);
        }
        __syncthreads();
        *(bf16x8*)&Ps[prow][ps0 * 8] = p0;
        *(bf16x8*)&Ps[prow][ps1 * 8] = p1;
        if (t < 128) {
            *(int4*)&Vs[prow][ps0 * 8] = v0;
            *(int4*)&Vs[prow][ps1 * 8] = v1;
        }
        __syncthreads();
        bf16x8 pb[4], va[2];
        #pragma unroll
        for (int mt = 0; mt < 4; ++mt) {
            int r = wm2 * 64 + mt * 16 + (l & 15);
            pb[mt] = *(const bf16x8*)&Ps[r][(((l >> 4)) ^ ((r >> 1) & 3)) * 8];
        }
        #pragma unroll
        for (int ct = 0; ct < 2; ++ct) {
            int r = wc * 32 + ct * 16 + (l & 15);
            va[ct] = *(const bf16x8*)&Vs[r][(((l >> 4)) ^ ((r >> 1) & 3)) * 8];
        }
        #pragma unroll
        for (int ct = 0; ct < 2; ++ct)
            #pragma unroll
            for (int mt = 0; mt < 4; ++mt)
                acc[ct][mt] = __builtin_amdgcn_mfma_f32_16x16x32_bf16(
                    va[ct], pb[mt], acc[ct][mt], 0, 0, 0);
        __syncthreads();
    }
    float g = gamma[0];
    #pragma unroll
    for (int ct = 0; ct < 2; ++ct)
        #pragma unroll
        for (int mt = 0; mt < 4; ++mt)
            #pragma unroll
            for (int r = 0; r < 4; ++r) {
                int ch = wc * 32 + ct * 16 + (l >> 4) * 4 + r;
                int m = mb + wm2 * 64 + mt * 16 + (l & 15);
                size_t idx = (size_t)(b * 512 + h * 64 + ch) * 1024 + m;
                out0[idx] = g * acc[ct][mt][r] + x[idx];
            }
}

extern "C" void kernel_launch(void* const* d_in, const int* in_sizes, int n_in,
                              void* d_out, int out_size, void* d_ws, size_t ws_size,
                              hipStream_t stream) {
    const float* x     = (const float*)d_in[0];
    const float* dw_w  = (const float*)d_in[1];
    const float* dw_b  = (const float*)d_in[2];
    const float* ln_w  = (const float*)d_in[3];
    const float* ln_b  = (const float*)d_in[4];
    const float* pw_w  = (const float*)d_in[5];
    const float* q_w   = (const float*)d_in[6];
    const float* q_b   = (const float*)d_in[7];
    const float* k_w   = (const float*)d_in[8];
    const float* k_b   = (const float*)d_in[9];
    const float* v_w   = (const float*)d_in[10];
    const float* v_b   = (const float*)d_in[11];
    const float* rpe   = (const float*)d_in[12];
    const float* gamma = (const float*)d_in[13];

    float* out0 = (float*)d_out;
    float* attn = out0 + (size_t)4 * 512 * 1024;

    char* w = (char*)d_ws;
    short* xt   = (short*)w;                      // 4 MB
    short* qwb  = (short*)(w + 4194304);          // 512 KB
    short* kwb  = (short*)(w + 4718592);          // 512 KB
    short* vwb  = (short*)(w + 5242880);          // 512 KB
    short* qbf  = (short*)(w + 5767168);          // 4 MB
    float* qf32 = (float*)(w + 9961472);          // 8 MB
    short* xsb  = (short*)(w + 18350080);         // 4 MB
    short* kbf  = (short*)(w + 22544384);         // 4 MB
    short* vbf  = (short*)(w + 26738688);         // 4 MB
    float* pos  = (float*)(w + 30932992);         // 32 KB

    prep_x<<<dim3(16, 8, 4), 256, 0, stream>>>(x, xt);
    wcast<<<384, 256, 0, stream>>>(q_w, k_w, v_w, qwb, kwb, vwb);
    gemm_nt<0><<<dim3(32, 4, 1), 256, 0, stream>>>(xt, qwb, q_b, qf32, qbf);
    offset_kernel<<<4096, 256, 0, stream>>>(qf32, dw_w, dw_b, ln_w, ln_b, pw_w, pos);
    sample_k<<<4096, 256, 0, stream>>>(xt, pos, xsb);
    gemm_nt<1><<<dim3(32, 4, 1), 256, 0, stream>>>(xsb, kwb, k_b, nullptr, kbf);
    gemm_nt<2><<<dim3(4, 8, 4), 256, 0, stream>>>(vwb, xsb, v_b, nullptr, vbf);
    attn_mfma<<<dim3(32, 8, 4), 256, 0, stream>>>(qbf, kbf, pos, rpe, attn);
    pv_mfma<<<dim3(8, 8, 4), 256, 0, stream>>>(attn, vbf, x, gamma, out0);
}

// Round 4
// 198.141 us; speedup vs baseline: 2.2266x; 1.1440x over previous
//
#include <hip/hip_runtime.h>
#include <hip/hip_bf16.h>
#include <math.h>

typedef short bf16x8 __attribute__((ext_vector_type(8)));
typedef float f32x4 __attribute__((ext_vector_type(4)));
typedef _Float16 h2 __attribute__((ext_vector_type(2)));

__device__ inline short f2bf(float f) {
    union { float f; unsigned u; } v; v.f = f;
    unsigned r = v.u + 0x7FFFu + ((v.u >> 16) & 1u);
    return (short)(r >> 16);
}
__device__ inline float bf2f(short s) {
    union { unsigned u; float f; } v; v.u = ((unsigned)(unsigned short)s) << 16;
    return v.f;
}
__device__ inline h2 pkrtz(float a, float b) {
    return __builtin_bit_cast(h2, __builtin_amdgcn_cvt_pkrtz(a, b));
}
__device__ inline float dot2(h2 a, h2 b) {
#if __has_builtin(__builtin_amdgcn_fdot2)
    return __builtin_amdgcn_fdot2(a, b, 0.f, false);
#else
    return (float)a[0] * (float)b[0] + (float)a[1] * (float)b[1];
#endif
}

// ---------------------------------------------------------------------------
// transpose-cast: x [b][c][p] f32 -> xt [b][p][c] bf16
// ---------------------------------------------------------------------------
__global__ __launch_bounds__(256) void prep_x(const float* __restrict__ x,
                                              short* __restrict__ xt)
{
    __shared__ float ts[64][65];
    int p0 = blockIdx.x * 64, c0 = blockIdx.y * 64, b = blockIdx.z;
    int t = threadIdx.x;
    #pragma unroll
    for (int i = 0; i < 16; ++i) {
        int idx = i * 256 + t;
        int cl = idx >> 6, pl = idx & 63;
        ts[cl][pl] = x[((size_t)(b * 512 + c0 + cl)) * 1024 + p0 + pl];
    }
    __syncthreads();
    #pragma unroll
    for (int i = 0; i < 16; ++i) {
        int idx = i * 256 + t;
        int pl = idx >> 6, cl = idx & 63;
        xt[((size_t)(b * 1024 + p0 + pl)) * 512 + c0 + cl] = f2bf(ts[cl][pl]);
    }
}

// cast 3 weight matrices [512][512] f32 -> bf16
__global__ __launch_bounds__(256) void wcast(
    const float* __restrict__ qw, const float* __restrict__ kw,
    const float* __restrict__ vw, short* __restrict__ qwb,
    short* __restrict__ kwb, short* __restrict__ vwb)
{
    int idx = (blockIdx.x * 256 + threadIdx.x) * 8;
    int w = idx >> 18;
    int off = idx & 262143;
    const float* src = (w == 0) ? qw : (w == 1) ? kw : vw;
    short* dst = (w == 0) ? qwb : (w == 1) ? kwb : vwb;
    float4 f0 = *(const float4*)(src + off);
    float4 f1 = *(const float4*)(src + off + 4);
    bf16x8 o;
    o[0] = f2bf(f0.x); o[1] = f2bf(f0.y); o[2] = f2bf(f0.z); o[3] = f2bf(f0.w);
    o[4] = f2bf(f1.x); o[5] = f2bf(f1.y); o[6] = f2bf(f1.z); o[7] = f2bf(f1.w);
    *(bf16x8*)(dst + off) = o;
}

// ---------------------------------------------------------------------------
// NT MFMA GEMM: D[m][n] = sum_k A[m][k]*B[n][k] + bias; K=512
// MODE 1: q/k (M=4096,N=512, bias[n], out bf16 [m*512+n])
// MODE 2: v (M=512,N=1024, z-batched B, bias[m], out bf16 [(z*512+m)*1024+n])
// ---------------------------------------------------------------------------
template<int MODE>
__global__ __launch_bounds__(256) void gemm_nt(
    const short* __restrict__ A, const short* __restrict__ B,
    const float* __restrict__ bias, short* __restrict__ Ob)
{
    constexpr int K = 512;
    __shared__ short As[128][32];
    __shared__ short Bs[128][32];
    int m0 = blockIdx.x * 128, n0 = blockIdx.y * 128;
    const short* Bp = (MODE == 2) ? (B + (size_t)blockIdx.z * 524288) : B;
    int t = threadIdx.x, wid = t >> 6, l = t & 63;
    int wm = wid >> 1, wn = wid & 1;
    f32x4 acc[4][4] = {};
    int srow = t >> 1, half = t & 1;
    int sw = (srow >> 1) & 3;
    int s0 = (half * 2) ^ sw, s1 = (half * 2 + 1) ^ sw;
    for (int k0 = 0; k0 < K; k0 += 32) {
        const int4 a0 = *(const int4*)(A + (size_t)(m0 + srow) * K + k0 + half * 16);
        const int4 a1 = *(const int4*)(A + (size_t)(m0 + srow) * K + k0 + half * 16 + 8);
        const int4 b0 = *(const int4*)(Bp + (size_t)(n0 + srow) * K + k0 + half * 16);
        const int4 b1 = *(const int4*)(Bp + (size_t)(n0 + srow) * K + k0 + half * 16 + 8);
        __syncthreads();
        *(int4*)&As[srow][s0 * 8] = a0;
        *(int4*)&As[srow][s1 * 8] = a1;
        *(int4*)&Bs[srow][s0 * 8] = b0;
        *(int4*)&Bs[srow][s1 * 8] = b1;
        __syncthreads();
        bf16x8 af[4], bfr[4];
        #pragma unroll
        for (int mt = 0; mt < 4; ++mt) {
            int r = wm * 64 + mt * 16 + (l & 15);
            af[mt] = *(const bf16x8*)&As[r][(((l >> 4)) ^ ((r >> 1) & 3)) * 8];
        }
        #pragma unroll
        for (int nt = 0; nt < 4; ++nt) {
            int r = wn * 64 + nt * 16 + (l & 15);
            bfr[nt] = *(const bf16x8*)&Bs[r][(((l >> 4)) ^ ((r >> 1) & 3)) * 8];
        }
        #pragma unroll
        for (int mt = 0; mt < 4; ++mt)
            #pragma unroll
            for (int nt = 0; nt < 4; ++nt)
                acc[mt][nt] = __builtin_amdgcn_mfma_f32_16x16x32_bf16(
                    af[mt], bfr[nt], acc[mt][nt], 0, 0, 0);
    }
    #pragma unroll
    for (int mt = 0; mt < 4; ++mt)
        #pragma unroll
        for (int nt = 0; nt < 4; ++nt)
            #pragma unroll
            for (int r = 0; r < 4; ++r) {
                int m = m0 + wm * 64 + mt * 16 + (l >> 4) * 4 + r;
                int n = n0 + wn * 64 + nt * 16 + (l & 15);
                float val = acc[mt][nt][r] + ((MODE == 2) ? bias[m] : bias[n]);
                if (MODE == 1) {
                    Ob[(size_t)m * 512 + n] = f2bf(val);
                } else {
                    Ob[((size_t)blockIdx.z * 512 + m) * 1024 + n] = f2bf(val);
                }
            }
}

// ---------------------------------------------------------------------------
// offset network (reads q bf16 in [b][p][c] layout) -> pos[b][p][2] (y,x)
// one block per (b,p); thread t handles channels 2t, 2t+1
// ---------------------------------------------------------------------------
__global__ __launch_bounds__(256) void offset_kernel(
    const short* __restrict__ qbf, const float* __restrict__ dw_w,
    const float* __restrict__ dw_b, const float* __restrict__ ln_w,
    const float* __restrict__ ln_b, const float* __restrict__ pw_w,
    float* __restrict__ pos)
{
    __shared__ float red[8];
    int bid = blockIdx.x;
    int b = bid >> 10, p = bid & 1023;
    int y = p >> 5, x = p & 31;
    int t = threadIdx.x;
    int c0 = 2 * t;
    const short* qb = qbf + (size_t)b * 524288;
    float h0, h1;
    {
        const float* w0 = dw_w + c0 * 9;
        const float* w1 = w0 + 9;
        float s0 = 0.f, s1 = 0.f;
        #pragma unroll
        for (int ky = 0; ky < 3; ++ky) {
            int yy = y + ky - 1;
            if (yy < 0 || yy > 31) continue;
            #pragma unroll
            for (int kx = 0; kx < 3; ++kx) {
                int xx = x + kx - 1;
                if (xx < 0 || xx > 31) continue;
                unsigned u = *(const unsigned*)(qb + (size_t)(yy * 32 + xx) * 512 + c0);
                s0 += bf2f((short)(u & 0xFFFF)) * w0[ky * 3 + kx];
                s1 += bf2f((short)(u >> 16)) * w1[ky * 3 + kx];
            }
        }
        float2 db = *(const float2*)(dw_b + c0);
        h0 = s0 + db.x; h1 = s1 + db.y;
    }
    float ls = h0 + h1;
    float lq = h0 * h0 + h1 * h1;
    #pragma unroll
    for (int s = 32; s >= 1; s >>= 1) {
        ls += __shfl_xor(ls, s);
        lq += __shfl_xor(lq, s);
    }
    int wid = t >> 6, lane = t & 63;
    if (lane == 0) { red[wid] = ls; red[4 + wid] = lq; }
    __syncthreads();
    float mu  = (red[0] + red[1] + red[2] + red[3]) * (1.f / 512.f);
    float var = (red[4] + red[5] + red[6] + red[7]) * (1.f / 512.f) - mu * mu;
    float rstd = rsqrtf(var + 1e-5f);
    float o0, o1;
    {
        float2 lw = *(const float2*)(ln_w + c0);
        float2 lb = *(const float2*)(ln_b + c0);
        float2 p0 = *(const float2*)(pw_w + c0);
        float2 p1 = *(const float2*)(pw_w + 512 + c0);
        float hn0 = (h0 - mu) * rstd * lw.x + lb.x;
        float hn1 = (h1 - mu) * rstd * lw.y + lb.y;
        float g0 = 0.5f * hn0 * (1.f + erff(hn0 * 0.70710678118f));
        float g1 = 0.5f * hn1 * (1.f + erff(hn1 * 0.70710678118f));
        o0 = g0 * p0.x + g1 * p0.y;
        o1 = g0 * p1.x + g1 * p1.y;
    }
    #pragma unroll
    for (int s = 32; s >= 1; s >>= 1) {
        o0 += __shfl_xor(o0, s);
        o1 += __shfl_xor(o1, s);
    }
    __syncthreads();
    if (lane == 0) { red[wid] = o0; red[4 + wid] = o1; }
    __syncthreads();
    if (t == 0) {
        float oy = tanhf(red[0] + red[1] + red[2] + red[3]) * 0.0625f;
        float ox = tanhf(red[4] + red[5] + red[6] + red[7]) * 0.0625f;
        float ry = ((y + 0.5f) * (1.f / 32.f)) * 2.f - 1.f;
        float rx = ((x + 0.5f) * (1.f / 32.f)) * 2.f - 1.f;
        pos[bid * 2]     = oy + ry;
        pos[bid * 2 + 1] = ox + rx;
    }
}

// ---------------------------------------------------------------------------
// bilinear sample of xt (bf16 [b][p][c]) at pos -> xs bf16 [b][p][c]
// ---------------------------------------------------------------------------
__global__ __launch_bounds__(256) void sample_k(
    const short* __restrict__ xt, const float* __restrict__ pos,
    short* __restrict__ xs)
{
    int bid = blockIdx.x;
    int b = bid >> 10;
    float py = pos[bid * 2], px = pos[bid * 2 + 1];
    float gx = (px + 1.f) * 15.5f;
    float gy = (py + 1.f) * 15.5f;
    float x0f = floorf(gx), y0f = floorf(gy);
    int ix0 = (int)x0f, iy0 = (int)y0f;
    float wx1 = gx - x0f, wx0 = 1.f - wx1;
    float wy1 = gy - y0f, wy0 = 1.f - wy1;
    const short* base = xt + (size_t)b * 524288;
    int t = threadIdx.x;
    float a0 = 0.f, a1 = 0.f;
    #pragma unroll
    for (int tap = 0; tap < 4; ++tap) {
        int ix = ix0 + (tap & 1), iy = iy0 + (tap >> 1);
        float w = ((tap & 1) ? wx1 : wx0) * ((tap >> 1) ? wy1 : wy0);
        if (ix >= 0 && ix < 32 && iy >= 0 && iy < 32) {
            unsigned u = *(const unsigned*)(base + (size_t)(iy * 32 + ix) * 512 + 2 * t);
            a0 += bf2f((short)(u & 0xFFFF)) * w;
            a1 += bf2f((short)(u >> 16)) * w;
        }
    }
    unsigned o = ((unsigned)(unsigned short)f2bf(a0)) |
                 (((unsigned)(unsigned short)f2bf(a1)) << 16);
    *(unsigned*)(xs + (size_t)bid * 512 + 2 * t) = o;
}

// ---------------------------------------------------------------------------
// attention: QK^T (MFMA) + RPE bias (padded pair-table, fdot2) + softmax.
// exp values kept in VGPRs (packed f16); pass B stages 8-row chunks in LDS
// (reusing the rpe/pos region) for coalesced float4 writes.
// grid (32 m-tiles, 8 h, 4 b); block 256 = 4 waves (2 m16 x 2 col-halves)
// ---------------------------------------------------------------------------
__global__ __launch_bounds__(256, 4) void attn_mfma(
    const short* __restrict__ qbf, const short* __restrict__ kbf,
    const float* __restrict__ pos, const float* __restrict__ rpe,
    float* __restrict__ attn_out)
{
    __shared__ __align__(16) char smem_raw[32768];   // passA: rpe2p+pos | passB: stage
    __shared__ float S_part[32][2];
    h2*     rpe_s = (h2*)smem_raw;                    // [65*65] padded pair table
    float2* pos_s = (float2*)(smem_raw + 16960);      // [1024]
    float*  stage = (float*)smem_raw;                 // [8][1024]

    int m0 = blockIdx.x * 32, h = blockIdx.y, b = blockIdx.z;
    int t = threadIdx.x, wid = t >> 6, l = t & 63;
    int wm = wid >> 1, wn = wid & 1;

    // ---- build padded pair table: entry (iy+1, ix+1) = (v[iy][ix], v[iy][ix+1])
    #pragma unroll
    for (int i = 0; i < 17; ++i) {
        int e = i * 256 + t;
        if (e < 4225) rpe_s[e] = (h2)((_Float16)0.f);
    }
    __syncthreads();
    const float* rh = rpe + h * 3969;
    for (int i = 0; i < 16; ++i) {
        int e = i * 256 + t;
        if (e < 3969) {
            int iy = (int)(((unsigned)e * 16645u) >> 20);   // e/63 exact for e<3969
            int ix = e - iy * 63;
            float v0 = rh[e];
            float v1 = (ix < 62) ? rh[e + 1] : 0.f;
            h2 pr; pr[0] = (_Float16)v0; pr[1] = (_Float16)v1;
            rpe_s[(iy + 1) * 65 + ix + 1] = pr;
        }
    }
    if (t < 63) {  // left border column: (0, v[iy][0])
        h2 pr; pr[0] = (_Float16)0.f; pr[1] = (_Float16)rh[t * 63];
        rpe_s[(t + 1) * 65] = pr;
    }
    #pragma unroll
    for (int i = 0; i < 4; ++i) {
        int idx = i * 256 + t;
        pos_s[idx] = *(const float2*)(pos + b * 2048 + idx * 2);
    }
    // q fragments
    int rowm = m0 + wm * 16 + (l & 15);
    const short* qrow = qbf + ((size_t)(b * 1024 + rowm) * 512 + h * 64 + (l >> 4) * 8);
    bf16x8 aq0 = *(const bf16x8*)qrow;
    bf16x8 aq1 = *(const bf16x8*)(qrow + 32);
    float qy15[4], qx15[4];
    #pragma unroll
    for (int r = 0; r < 4; ++r) {
        int rm = m0 + wm * 16 + (l >> 4) * 4 + r;
        qy15[r] = (((rm >> 5) + 0.5f) * (1.f / 16.f) - 1.f) * 15.5f;
        qx15[r] = (((rm & 31) + 0.5f) * (1.f / 16.f) - 1.f) * 15.5f;
    }
    __syncthreads();

    // ---- pass A: logits -> exp kept in regs (packed f16 across nt pairs)
    float Ssum[4] = {0.f, 0.f, 0.f, 0.f};
    float eprev[4];
    unsigned ep[4][16];
    for (int nt = 0; nt < 32; ++nt) {
        int n0 = wn * 512 + nt * 16;
        int col = n0 + (l & 15);
        const short* krow = kbf + ((size_t)(b * 1024 + col) * 512 + h * 64 + (l >> 4) * 8);
        bf16x8 bk0 = *(const bf16x8*)krow;
        bf16x8 bk1 = *(const bf16x8*)(krow + 32);
        f32x4 acc = {0.f, 0.f, 0.f, 0.f};
        acc = __builtin_amdgcn_mfma_f32_16x16x32_bf16(aq0, bk0, acc, 0, 0, 0);
        acc = __builtin_amdgcn_mfma_f32_16x16x32_bf16(aq1, bk1, acc, 0, 0, 0);
        float2 pp = pos_s[col];
        float cyn = 32.f - pp.x * 15.5f;
        float cxn = 32.f - pp.y * 15.5f;
        #pragma unroll
        for (int r = 0; r < 4; ++r) {
            float gyp = qy15[r] + cyn;
            float gxp = qx15[r] + cxn;
            float fy = floorf(gyp), fx = floorf(gxp);
            float wy1 = gyp - fy, wx1 = gxp - fx;
            int ad = (int)fy * 65 + (int)fx;
            h2 r0 = rpe_s[ad];
            h2 r1 = rpe_s[ad + 65];
            h2 wp = pkrtz(1.f - wx1, wx1);
            float t0 = dot2(r0, wp);
            float t1 = dot2(r1, wp);
            float bias = t0 + wy1 * (t1 - t0);
            float logit = fmaf(acc[r], 0.125f, bias);
            float e = __expf(logit);
            Ssum[r] += e;
            if (nt & 1) {
                h2 pk = pkrtz(eprev[r], e);
                ep[r][nt >> 1] = __builtin_bit_cast(unsigned, pk);
            } else {
                eprev[r] = e;
            }
        }
    }
    #pragma unroll
    for (int s = 1; s < 16; s <<= 1)
        #pragma unroll
        for (int r = 0; r < 4; ++r) Ssum[r] += __shfl_xor(Ssum[r], s);
    if ((l & 15) == 0)
        #pragma unroll
        for (int r = 0; r < 4; ++r) S_part[wm * 16 + (l >> 4) * 4 + r][wn] = Ssum[r];
    __syncthreads();
    float invS[4];
    #pragma unroll
    for (int r = 0; r < 4; ++r) {
        int row = wm * 16 + (l >> 4) * 4 + r;
        invS[r] = 1.f / (S_part[row][0] + S_part[row][1]);
    }
    size_t obase = ((size_t)((b * 8 + h) * 1024 + m0)) * 1024;

    // ---- pass B: 4 chunks of 8 rows; stage in LDS, coalesced float4 writes
    for (int cc = 0; cc < 4; ++cc) {
        __syncthreads();  // stage region free (first iter: pass A LDS reads done)
        if (wm == (cc >> 1) && ((l >> 4) >> 1) == (cc & 1)) {
            int base_col = wn * 512 + (l & 15);
            #pragma unroll
            for (int r = 0; r < 4; ++r) {
                int rc = ((l >> 4) & 1) * 4 + r;
                float* srow = stage + rc * 1024 + base_col;
                #pragma unroll
                for (int j = 0; j < 16; ++j) {
                    h2 pk = __builtin_bit_cast(h2, ep[r][j]);
                    srow[j * 32]      = (float)pk[0] * invS[r];
                    srow[j * 32 + 16] = (float)pk[1] * invS[r];
                }
            }
        }
        __syncthreads();
        #pragma unroll
        for (int i = 0; i < 8; ++i) {
            float4 vv = *(const float4*)(stage + i * 1024 + t * 4);
            *(float4*)(attn_out + obase + (size_t)(cc * 8 + i) * 1024 + t * 4) = vv;
        }
    }
}

// ---------------------------------------------------------------------------
// PV: out[b][h*64+ch][m] = gamma * sum_n attn[bh][m][n]*v[ch][n] + x
// ---------------------------------------------------------------------------
__global__ __launch_bounds__(256) void pv_mfma(
    const float* __restrict__ attn, const short* __restrict__ vbf,
    const float* __restrict__ x, const float* __restrict__ gamma,
    float* __restrict__ out0)
{
    __shared__ short Ps[128][32];
    __shared__ short Vs[64][32];
    int mb = blockIdx.x * 128, h = blockIdx.y, b = blockIdx.z;
    int t = threadIdx.x, wid = t >> 6, l = t & 63;
    int wc = wid >> 1, wm2 = wid & 1;
    const float* Ab = attn + (size_t)(b * 8 + h) * 1024 * 1024;
    const short* Vb = vbf + (size_t)(b * 512 + h * 64) * 1024;
    f32x4 acc[2][4] = {};
    int prow = t >> 1, phalf = t & 1;
    int psw = (prow >> 1) & 3;
    int ps0 = (phalf * 2) ^ psw, ps1 = (phalf * 2 + 1) ^ psw;
    for (int ks = 0; ks < 32; ++ks) {
        int n0 = ks * 32;
        const float* src = Ab + (size_t)(mb + prow) * 1024 + n0 + phalf * 16;
        float4 f0 = *(const float4*)src;
        float4 f1 = *(const float4*)(src + 4);
        float4 f2 = *(const float4*)(src + 8);
        float4 f3 = *(const float4*)(src + 12);
        bf16x8 p0, p1;
        p0[0] = f2bf(f0.x); p0[1] = f2bf(f0.y); p0[2] = f2bf(f0.z); p0[3] = f2bf(f0.w);
        p0[4] = f2bf(f1.x); p0[5] = f2bf(f1.y); p0[6] = f2bf(f1.z); p0[7] = f2bf(f1.w);
        p1[0] = f2bf(f2.x); p1[1] = f2bf(f2.y); p1[2] = f2bf(f2.z); p1[3] = f2bf(f2.w);
        p1[4] = f2bf(f3.x); p1[5] = f2bf(f3.y); p1[6] = f2bf(f3.z); p1[7] = f2bf(f3.w);
        int4 v0, v1;
        if (t < 128) {
            v0 = *(const int4*)(Vb + (size_t)prow * 1024 + n0 + phalf * 16);
            v1 = *(const int4*)(Vb + (size_t)prow * 1024 + n0 + phalf * 16 + 8);
        }
        __syncthreads();
        *(bf16x8*)&Ps[prow][ps0 * 8] = p0;
        *(bf16x8*)&Ps[prow][ps1 * 8] = p1;
        if (t < 128) {
            *(int4*)&Vs[prow][ps0 * 8] = v0;
            *(int4*)&Vs[prow][ps1 * 8] = v1;
        }
        __syncthreads();
        bf16x8 pb[4], va[2];
        #pragma unroll
        for (int mt = 0; mt < 4; ++mt) {
            int r = wm2 * 64 + mt * 16 + (l & 15);
            pb[mt] = *(const bf16x8*)&Ps[r][(((l >> 4)) ^ ((r >> 1) & 3)) * 8];
        }
        #pragma unroll
        for (int ct = 0; ct < 2; ++ct) {
            int r = wc * 32 + ct * 16 + (l & 15);
            va[ct] = *(const bf16x8*)&Vs[r][(((l >> 4)) ^ ((r >> 1) & 3)) * 8];
        }
        #pragma unroll
        for (int ct = 0; ct < 2; ++ct)
            #pragma unroll
            for (int mt = 0; mt < 4; ++mt)
                acc[ct][mt] = __builtin_amdgcn_mfma_f32_16x16x32_bf16(
                    va[ct], pb[mt], acc[ct][mt], 0, 0, 0);
        __syncthreads();
    }
    float g = gamma[0];
    #pragma unroll
    for (int ct = 0; ct < 2; ++ct)
        #pragma unroll
        for (int mt = 0; mt < 4; ++mt)
            #pragma unroll
            for (int r = 0; r < 4; ++r) {
                int ch = wc * 32 + ct * 16 + (l >> 4) * 4 + r;
                int m = mb + wm2 * 64 + mt * 16 + (l & 15);
                size_t idx = (size_t)(b * 512 + h * 64 + ch) * 1024 + m;
                out0[idx] = g * acc[ct][mt][r] + x[idx];
            }
}

extern "C" void kernel_launch(void* const* d_in, const int* in_sizes, int n_in,
                              void* d_out, int out_size, void* d_ws, size_t ws_size,
                              hipStream_t stream) {
    const float* x     = (const float*)d_in[0];
    const float* dw_w  = (const float*)d_in[1];
    const float* dw_b  = (const float*)d_in[2];
    const float* ln_w  = (const float*)d_in[3];
    const float* ln_b  = (const float*)d_in[4];
    const float* pw_w  = (const float*)d_in[5];
    const float* q_w   = (const float*)d_in[6];
    const float* q_b   = (const float*)d_in[7];
    const float* k_w   = (const float*)d_in[8];
    const float* k_b   = (const float*)d_in[9];
    const float* v_w   = (const float*)d_in[10];
    const float* v_b   = (const float*)d_in[11];
    const float* rpe   = (const float*)d_in[12];
    const float* gamma = (const float*)d_in[13];

    float* out0 = (float*)d_out;
    float* attn = out0 + (size_t)4 * 512 * 1024;

    char* w = (char*)d_ws;
    short* xt   = (short*)w;                      // 4 MB
    short* qwb  = (short*)(w + 4194304);
    short* kwb  = (short*)(w + 4718592);
    short* vwb  = (short*)(w + 5242880);
    short* qbf  = (short*)(w + 5767168);          // 4 MB
    short* xsb  = (short*)(w + 9961472);          // 4 MB
    short* kbf  = (short*)(w + 14155776);         // 4 MB
    short* vbf  = (short*)(w + 18350080);         // 4 MB
    float* pos  = (float*)(w + 22544384);         // 32 KB

    prep_x<<<dim3(16, 8, 4), 256, 0, stream>>>(x, xt);
    wcast<<<384, 256, 0, stream>>>(q_w, k_w, v_w, qwb, kwb, vwb);
    gemm_nt<1><<<dim3(32, 4, 1), 256, 0, stream>>>(xt, qwb, q_b, qbf);
    offset_kernel<<<4096, 256, 0, stream>>>(qbf, dw_w, dw_b, ln_w, ln_b, pw_w, pos);
    sample_k<<<4096, 256, 0, stream>>>(xt, pos, xsb);
    gemm_nt<1><<<dim3(32, 4, 1), 256, 0, stream>>>(xsb, kwb, k_b, kbf);
    gemm_nt<2><<<dim3(4, 8, 4), 256, 0, stream>>>(vwb, xsb, v_b, vbf);
    attn_mfma<<<dim3(32, 8, 4), 256, 0, stream>>>(qbf, kbf, pos, rpe, attn);
    pv_mfma<<<dim3(8, 8, 4), 256, 0, stream>>>(attn, vbf, x, gamma, out0);
}

// Round 5
// 173.824 us; speedup vs baseline: 2.5381x; 1.1399x over previous
//
#include <hip/hip_runtime.h>
#include <hip/hip_bf16.h>
#include <math.h>

typedef short bf16x8 __attribute__((ext_vector_type(8)));
typedef float f32x4 __attribute__((ext_vector_type(4)));
typedef _Float16 h2 __attribute__((ext_vector_type(2)));

__device__ inline short f2bf(float f) {
    union { float f; unsigned u; } v; v.f = f;
    unsigned r = v.u + 0x7FFFu + ((v.u >> 16) & 1u);
    return (short)(r >> 16);
}
__device__ inline float bf2f(short s) {
    union { unsigned u; float f; } v; v.u = ((unsigned)(unsigned short)s) << 16;
    return v.f;
}
__device__ inline h2 pkrtz(float a, float b) {
    return __builtin_bit_cast(h2, __builtin_amdgcn_cvt_pkrtz(a, b));
}
__device__ inline unsigned cvtpk_bf16(float a, float b) {
    unsigned r;
    asm("v_cvt_pk_bf16_f32 %0, %1, %2" : "=v"(r) : "v"(a), "v"(b));
    return r;
}
__device__ inline float bflo(unsigned u) {
    return __builtin_bit_cast(float, u << 16);
}
__device__ inline float bfhi(unsigned u) {
    return __builtin_bit_cast(float, u & 0xFFFF0000u);
}
__device__ inline float dot2(h2 a, h2 b) {
#if __has_builtin(__builtin_amdgcn_fdot2)
    return __builtin_amdgcn_fdot2(a, b, 0.f, false);
#else
    return (float)a[0] * (float)b[0] + (float)a[1] * (float)b[1];
#endif
}

// ---------------------------------------------------------------------------
// transpose-cast: x [b][c][p] f32 -> xt [b][p][c] bf16
// ---------------------------------------------------------------------------
__global__ __launch_bounds__(256) void prep_x(const float* __restrict__ x,
                                              short* __restrict__ xt)
{
    __shared__ float ts[64][65];
    int p0 = blockIdx.x * 64, c0 = blockIdx.y * 64, b = blockIdx.z;
    int t = threadIdx.x;
    #pragma unroll
    for (int i = 0; i < 16; ++i) {
        int idx = i * 256 + t;
        int cl = idx >> 6, pl = idx & 63;
        ts[cl][pl] = x[((size_t)(b * 512 + c0 + cl)) * 1024 + p0 + pl];
    }
    __syncthreads();
    #pragma unroll
    for (int i = 0; i < 16; ++i) {
        int idx = i * 256 + t;
        int pl = idx >> 6, cl = idx & 63;
        xt[((size_t)(b * 1024 + p0 + pl)) * 512 + c0 + cl] = f2bf(ts[cl][pl]);
    }
}

// cast 3 weight matrices [512][512] f32 -> bf16
__global__ __launch_bounds__(256) void wcast(
    const float* __restrict__ qw, const float* __restrict__ kw,
    const float* __restrict__ vw, short* __restrict__ qwb,
    short* __restrict__ kwb, short* __restrict__ vwb)
{
    int idx = (blockIdx.x * 256 + threadIdx.x) * 8;
    int w = idx >> 18;
    int off = idx & 262143;
    const float* src = (w == 0) ? qw : (w == 1) ? kw : vw;
    short* dst = (w == 0) ? qwb : (w == 1) ? kwb : vwb;
    float4 f0 = *(const float4*)(src + off);
    float4 f1 = *(const float4*)(src + off + 4);
    bf16x8 o;
    o[0] = f2bf(f0.x); o[1] = f2bf(f0.y); o[2] = f2bf(f0.z); o[3] = f2bf(f0.w);
    o[4] = f2bf(f1.x); o[5] = f2bf(f1.y); o[6] = f2bf(f1.z); o[7] = f2bf(f1.w);
    *(bf16x8*)(dst + off) = o;
}

// ---------------------------------------------------------------------------
// NT MFMA GEMM: D[m][n] = sum_k A[m][k]*B[n][k] + bias; K=512
// MODE 1: q/k (M=4096,N=512, bias[n], out bf16 [m*512+n])
// MODE 2: v (M=512,N=1024, z-batched B, bias[m], out bf16 [(z*512+m)*1024+n])
// ---------------------------------------------------------------------------
template<int MODE>
__global__ __launch_bounds__(256) void gemm_nt(
    const short* __restrict__ A, const short* __restrict__ B,
    const float* __restrict__ bias, short* __restrict__ Ob)
{
    constexpr int K = 512;
    __shared__ short As[128][32];
    __shared__ short Bs[128][32];
    int m0 = blockIdx.x * 128, n0 = blockIdx.y * 128;
    const short* Bp = (MODE == 2) ? (B + (size_t)blockIdx.z * 524288) : B;
    int t = threadIdx.x, wid = t >> 6, l = t & 63;
    int wm = wid >> 1, wn = wid & 1;
    f32x4 acc[4][4] = {};
    int srow = t >> 1, half = t & 1;
    int sw = (srow >> 1) & 3;
    int s0 = (half * 2) ^ sw, s1 = (half * 2 + 1) ^ sw;
    for (int k0 = 0; k0 < K; k0 += 32) {
        const int4 a0 = *(const int4*)(A + (size_t)(m0 + srow) * K + k0 + half * 16);
        const int4 a1 = *(const int4*)(A + (size_t)(m0 + srow) * K + k0 + half * 16 + 8);
        const int4 b0 = *(const int4*)(Bp + (size_t)(n0 + srow) * K + k0 + half * 16);
        const int4 b1 = *(const int4*)(Bp + (size_t)(n0 + srow) * K + k0 + half * 16 + 8);
        __syncthreads();
        *(int4*)&As[srow][s0 * 8] = a0;
        *(int4*)&As[srow][s1 * 8] = a1;
        *(int4*)&Bs[srow][s0 * 8] = b0;
        *(int4*)&Bs[srow][s1 * 8] = b1;
        __syncthreads();
        bf16x8 af[4], bfr[4];
        #pragma unroll
        for (int mt = 0; mt < 4; ++mt) {
            int r = wm * 64 + mt * 16 + (l & 15);
            af[mt] = *(const bf16x8*)&As[r][(((l >> 4)) ^ ((r >> 1) & 3)) * 8];
        }
        #pragma unroll
        for (int nt = 0; nt < 4; ++nt) {
            int r = wn * 64 + nt * 16 + (l & 15);
            bfr[nt] = *(const bf16x8*)&Bs[r][(((l >> 4)) ^ ((r >> 1) & 3)) * 8];
        }
        #pragma unroll
        for (int mt = 0; mt < 4; ++mt)
            #pragma unroll
            for (int nt = 0; nt < 4; ++nt)
                acc[mt][nt] = __builtin_amdgcn_mfma_f32_16x16x32_bf16(
                    af[mt], bfr[nt], acc[mt][nt], 0, 0, 0);
    }
    #pragma unroll
    for (int mt = 0; mt < 4; ++mt)
        #pragma unroll
        for (int nt = 0; nt < 4; ++nt)
            #pragma unroll
            for (int r = 0; r < 4; ++r) {
                int m = m0 + wm * 64 + mt * 16 + (l >> 4) * 4 + r;
                int n = n0 + wn * 64 + nt * 16 + (l & 15);
                float val = acc[mt][nt][r] + ((MODE == 2) ? bias[m] : bias[n]);
                if (MODE == 1) {
                    Ob[(size_t)m * 512 + n] = f2bf(val);
                } else {
                    Ob[((size_t)blockIdx.z * 512 + m) * 1024 + n] = f2bf(val);
                }
            }
}

// ---------------------------------------------------------------------------
// offset network (reads q bf16 in [b][p][c] layout) -> pos[b][p][2] (y,x)
// ---------------------------------------------------------------------------
__global__ __launch_bounds__(256) void offset_kernel(
    const short* __restrict__ qbf, const float* __restrict__ dw_w,
    const float* __restrict__ dw_b, const float* __restrict__ ln_w,
    const float* __restrict__ ln_b, const float* __restrict__ pw_w,
    float* __restrict__ pos)
{
    __shared__ float red[8];
    int bid = blockIdx.x;
    int b = bid >> 10, p = bid & 1023;
    int y = p >> 5, x = p & 31;
    int t = threadIdx.x;
    int c0 = 2 * t;
    const short* qb = qbf + (size_t)b * 524288;
    float h0, h1;
    {
        const float* w0 = dw_w + c0 * 9;
        const float* w1 = w0 + 9;
        float s0 = 0.f, s1 = 0.f;
        #pragma unroll
        for (int ky = 0; ky < 3; ++ky) {
            int yy = y + ky - 1;
            if (yy < 0 || yy > 31) continue;
            #pragma unroll
            for (int kx = 0; kx < 3; ++kx) {
                int xx = x + kx - 1;
                if (xx < 0 || xx > 31) continue;
                unsigned u = *(const unsigned*)(qb + (size_t)(yy * 32 + xx) * 512 + c0);
                s0 += bf2f((short)(u & 0xFFFF)) * w0[ky * 3 + kx];
                s1 += bf2f((short)(u >> 16)) * w1[ky * 3 + kx];
            }
        }
        float2 db = *(const float2*)(dw_b + c0);
        h0 = s0 + db.x; h1 = s1 + db.y;
    }
    float ls = h0 + h1;
    float lq = h0 * h0 + h1 * h1;
    #pragma unroll
    for (int s = 32; s >= 1; s >>= 1) {
        ls += __shfl_xor(ls, s);
        lq += __shfl_xor(lq, s);
    }
    int wid = t >> 6, lane = t & 63;
    if (lane == 0) { red[wid] = ls; red[4 + wid] = lq; }
    __syncthreads();
    float mu  = (red[0] + red[1] + red[2] + red[3]) * (1.f / 512.f);
    float var = (red[4] + red[5] + red[6] + red[7]) * (1.f / 512.f) - mu * mu;
    float rstd = rsqrtf(var + 1e-5f);
    float o0, o1;
    {
        float2 lw = *(const float2*)(ln_w + c0);
        float2 lb = *(const float2*)(ln_b + c0);
        float2 p0 = *(const float2*)(pw_w + c0);
        float2 p1 = *(const float2*)(pw_w + 512 + c0);
        float hn0 = (h0 - mu) * rstd * lw.x + lb.x;
        float hn1 = (h1 - mu) * rstd * lw.y + lb.y;
        float g0 = 0.5f * hn0 * (1.f + erff(hn0 * 0.70710678118f));
        float g1 = 0.5f * hn1 * (1.f + erff(hn1 * 0.70710678118f));
        o0 = g0 * p0.x + g1 * p0.y;
        o1 = g0 * p1.x + g1 * p1.y;
    }
    #pragma unroll
    for (int s = 32; s >= 1; s >>= 1) {
        o0 += __shfl_xor(o0, s);
        o1 += __shfl_xor(o1, s);
    }
    __syncthreads();
    if (lane == 0) { red[wid] = o0; red[4 + wid] = o1; }
    __syncthreads();
    if (t == 0) {
        float oy = tanhf(red[0] + red[1] + red[2] + red[3]) * 0.0625f;
        float ox = tanhf(red[4] + red[5] + red[6] + red[7]) * 0.0625f;
        float ry = ((y + 0.5f) * (1.f / 32.f)) * 2.f - 1.f;
        float rx = ((x + 0.5f) * (1.f / 32.f)) * 2.f - 1.f;
        pos[bid * 2]     = oy + ry;
        pos[bid * 2 + 1] = ox + rx;
    }
}

// ---------------------------------------------------------------------------
// bilinear sample of xt (bf16 [b][p][c]) at pos -> xs bf16 [b][p][c]
// ---------------------------------------------------------------------------
__global__ __launch_bounds__(256) void sample_k(
    const short* __restrict__ xt, const float* __restrict__ pos,
    short* __restrict__ xs)
{
    int bid = blockIdx.x;
    int b = bid >> 10;
    float py = pos[bid * 2], px = pos[bid * 2 + 1];
    float gx = (px + 1.f) * 15.5f;
    float gy = (py + 1.f) * 15.5f;
    float x0f = floorf(gx), y0f = floorf(gy);
    int ix0 = (int)x0f, iy0 = (int)y0f;
    float wx1 = gx - x0f, wx0 = 1.f - wx1;
    float wy1 = gy - y0f, wy0 = 1.f - wy1;
    const short* base = xt + (size_t)b * 524288;
    int t = threadIdx.x;
    float a0 = 0.f, a1 = 0.f;
    #pragma unroll
    for (int tap = 0; tap < 4; ++tap) {
        int ix = ix0 + (tap & 1), iy = iy0 + (tap >> 1);
        float w = ((tap & 1) ? wx1 : wx0) * ((tap >> 1) ? wy1 : wy0);
        if (ix >= 0 && ix < 32 && iy >= 0 && iy < 32) {
            unsigned u = *(const unsigned*)(base + (size_t)(iy * 32 + ix) * 512 + 2 * t);
            a0 += bf2f((short)(u & 0xFFFF)) * w;
            a1 += bf2f((short)(u >> 16)) * w;
        }
    }
    unsigned o = ((unsigned)(unsigned short)f2bf(a0)) |
                 (((unsigned)(unsigned short)f2bf(a1)) << 16);
    *(unsigned*)(xs + (size_t)bid * 512 + 2 * t) = o;
}

// ---------------------------------------------------------------------------
// attention: QK^T (MFMA) + RPE bias (padded pair-table, fdot2) + softmax.
// m-tile = 16 rows; 4 waves each own a 256-col quarter. exp kept in VGPRs as
// PACKED BF16 pairs (ep[4][8], static-indexed via full unroll -> no scratch).
// pass B: 4-row chunks staged in LDS (reusing rpe region), float4 writes.
// grid (64 m-tiles, 8 h, 4 b)
// ---------------------------------------------------------------------------
__global__ __launch_bounds__(256, 5) void attn_mfma(
    const short* __restrict__ qbf, const short* __restrict__ kbf,
    const float* __restrict__ pos, const float* __restrict__ rpe,
    float* __restrict__ attn_out)
{
    __shared__ __align__(16) char smem_raw[21504];   // passA: rpe2p+pos | passB: stage
    __shared__ float S_part[16][4];
    h2*     rpe_s = (h2*)smem_raw;                    // [65*65] padded pair table
    h2*     pos_s = (h2*)(smem_raw + 16960);          // [1024] (y,x) f16
    float*  stage = (float*)smem_raw;                 // [4][1024]

    int m0 = blockIdx.x * 16, h = blockIdx.y, b = blockIdx.z;
    int t = threadIdx.x, wn = t >> 6, l = t & 63;
    int g = l >> 4, c16 = l & 15;

    // ---- build padded pair table: entry (iy+1, ix+1) = (v[iy][ix], v[iy][ix+1])
    #pragma unroll
    for (int i = 0; i < 17; ++i) {
        int e = i * 256 + t;
        if (e < 4225) rpe_s[e] = (h2)((_Float16)0.f);
    }
    __syncthreads();
    const float* rh = rpe + h * 3969;
    for (int i = 0; i < 16; ++i) {
        int e = i * 256 + t;
        if (e < 3969) {
            int iy = (int)(((unsigned)e * 16645u) >> 20);   // e/63 exact for e<3969
            int ix = e - iy * 63;
            float v0 = rh[e];
            float v1 = (ix < 62) ? rh[e + 1] : 0.f;
            h2 pr; pr[0] = (_Float16)v0; pr[1] = (_Float16)v1;
            rpe_s[(iy + 1) * 65 + ix + 1] = pr;
        }
    }
    if (t < 63) {  // left border column: (0, v[iy][0])
        h2 pr; pr[0] = (_Float16)0.f; pr[1] = (_Float16)rh[t * 63];
        rpe_s[(t + 1) * 65] = pr;
    }
    #pragma unroll
    for (int i = 0; i < 4; ++i) {
        int idx = i * 256 + t;
        float2 pf = *(const float2*)(pos + b * 2048 + idx * 2);
        pos_s[idx] = pkrtz(pf.x, pf.y);
    }
    // q fragments (16 rows shared by all 4 waves)
    int rowm = m0 + c16;
    const short* qrow = qbf + ((size_t)(b * 1024 + rowm) * 512 + h * 64 + g * 8);
    bf16x8 aq0 = *(const bf16x8*)qrow;
    bf16x8 aq1 = *(const bf16x8*)(qrow + 32);
    float qy15[4], qx15[4];
    #pragma unroll
    for (int r = 0; r < 4; ++r) {
        int rm = m0 + g * 4 + r;
        qy15[r] = (((rm >> 5) + 0.5f) * (1.f / 16.f) - 1.f) * 15.5f;
        qx15[r] = (((rm & 31) + 0.5f) * (1.f / 16.f) - 1.f) * 15.5f;
    }
    __syncthreads();

    // ---- pass A: 16 col-tiles of 16; exp -> packed bf16 pairs in VGPRs
    float Ssum[4] = {0.f, 0.f, 0.f, 0.f};
    float eprev[4];
    unsigned ep[4][8];
    #pragma unroll
    for (int nt = 0; nt < 16; ++nt) {
        int col = wn * 256 + nt * 16 + c16;
        const short* krow = kbf + ((size_t)(b * 1024 + col) * 512 + h * 64 + g * 8);
        bf16x8 bk0 = *(const bf16x8*)krow;
        bf16x8 bk1 = *(const bf16x8*)(krow + 32);
        f32x4 acc = {0.f, 0.f, 0.f, 0.f};
        acc = __builtin_amdgcn_mfma_f32_16x16x32_bf16(aq0, bk0, acc, 0, 0, 0);
        acc = __builtin_amdgcn_mfma_f32_16x16x32_bf16(aq1, bk1, acc, 0, 0, 0);
        h2 pp = pos_s[col];
        float cyn = 32.f - (float)pp[0] * 15.5f;
        float cxn = 32.f - (float)pp[1] * 15.5f;
        #pragma unroll
        for (int r = 0; r < 4; ++r) {
            float gyp = qy15[r] + cyn;
            float gxp = qx15[r] + cxn;
            float fy = floorf(gyp), fx = floorf(gxp);
            float wy1 = gyp - fy, wx1 = gxp - fx;
            int ad = (int)fy * 65 + (int)fx;
            h2 r0 = rpe_s[ad];
            h2 r1 = rpe_s[ad + 65];
            h2 wp = pkrtz(1.f - wx1, wx1);
            float t0 = dot2(r0, wp);
            float t1 = dot2(r1, wp);
            float bias = t0 + wy1 * (t1 - t0);
            float logit = fmaf(acc[r], 0.125f, bias);
            float e = __expf(logit);
            Ssum[r] += e;
            if (nt & 1) {
                ep[r][nt >> 1] = cvtpk_bf16(eprev[r], e);
            } else {
                eprev[r] = e;
            }
        }
    }
    #pragma unroll
    for (int s = 1; s < 16; s <<= 1)
        #pragma unroll
        for (int r = 0; r < 4; ++r) Ssum[r] += __shfl_xor(Ssum[r], s);
    if (c16 == 0)
        #pragma unroll
        for (int r = 0; r < 4; ++r) S_part[g * 4 + r][wn] = Ssum[r];
    __syncthreads();
    float invS[4];
    #pragma unroll
    for (int r = 0; r < 4; ++r) {
        int row = g * 4 + r;
        invS[r] = 1.f / (S_part[row][0] + S_part[row][1] + S_part[row][2] + S_part[row][3]);
    }
    size_t obase = ((size_t)((b * 8 + h) * 1024 + m0)) * 1024;

    // ---- pass B: 4 chunks of 4 rows; stage in LDS, coalesced float4 writes
    for (int cc = 0; cc < 4; ++cc) {
        __syncthreads();
        if (g == cc) {
            int base_col = wn * 256 + c16;
            #pragma unroll
            for (int r = 0; r < 4; ++r) {
                float* srow = stage + r * 1024 + base_col;
                #pragma unroll
                for (int j = 0; j < 8; ++j) {
                    unsigned u = ep[r][j];
                    srow[j * 32]      = bflo(u) * invS[r];
                    srow[j * 32 + 16] = bfhi(u) * invS[r];
                }
            }
        }
        __syncthreads();
        #pragma unroll
        for (int i = 0; i < 4; ++i) {
            float4 vv = *(const float4*)(stage + i * 1024 + t * 4);
            *(float4*)(attn_out + obase + (size_t)(cc * 4 + i) * 1024 + t * 4) = vv;
        }
    }
}

// ---------------------------------------------------------------------------
// PV: out[b][h*64+ch][m] = gamma * sum_n attn[bh][m][n]*v[ch][n] + x
// ---------------------------------------------------------------------------
__global__ __launch_bounds__(256) void pv_mfma(
    const float* __restrict__ attn, const short* __restrict__ vbf,
    const float* __restrict__ x, const float* __restrict__ gamma,
    float* __restrict__ out0)
{
    __shared__ short Ps[128][32];
    __shared__ short Vs[64][32];
    int mb = blockIdx.x * 128, h = blockIdx.y, b = blockIdx.z;
    int t = threadIdx.x, wid = t >> 6, l = t & 63;
    int wc = wid >> 1, wm2 = wid & 1;
    const float* Ab = attn + (size_t)(b * 8 + h) * 1024 * 1024;
    const short* Vb = vbf + (size_t)(b * 512 + h * 64) * 1024;
    f32x4 acc[2][4] = {};
    int prow = t >> 1, phalf = t & 1;
    int psw = (prow >> 1) & 3;
    int ps0 = (phalf * 2) ^ psw, ps1 = (phalf * 2 + 1) ^ psw;
    for (int ks = 0; ks < 32; ++ks) {
        int n0 = ks * 32;
        const float* src = Ab + (size_t)(mb + prow) * 1024 + n0 + phalf * 16;
        float4 f0 = *(const float4*)src;
        float4 f1 = *(const float4*)(src + 4);
        float4 f2 = *(const float4*)(src + 8);
        float4 f3 = *(const float4*)(src + 12);
        int4 w0, w1;
        w0.x = (int)cvtpk_bf16(f0.x, f0.y);
        w0.y = (int)cvtpk_bf16(f0.z, f0.w);
        w0.z = (int)cvtpk_bf16(f1.x, f1.y);
        w0.w = (int)cvtpk_bf16(f1.z, f1.w);
        w1.x = (int)cvtpk_bf16(f2.x, f2.y);
        w1.y = (int)cvtpk_bf16(f2.z, f2.w);
        w1.z = (int)cvtpk_bf16(f3.x, f3.y);
        w1.w = (int)cvtpk_bf16(f3.z, f3.w);
        int4 v0, v1;
        if (t < 128) {
            v0 = *(const int4*)(Vb + (size_t)prow * 1024 + n0 + phalf * 16);
            v1 = *(const int4*)(Vb + (size_t)prow * 1024 + n0 + phalf * 16 + 8);
        }
        __syncthreads();
        *(int4*)&Ps[prow][ps0 * 8] = w0;
        *(int4*)&Ps[prow][ps1 * 8] = w1;
        if (t < 128) {
            *(int4*)&Vs[prow][ps0 * 8] = v0;
            *(int4*)&Vs[prow][ps1 * 8] = v1;
        }
        __syncthreads();
        bf16x8 pb[4], va[2];
        #pragma unroll
        for (int mt = 0; mt < 4; ++mt) {
            int r = wm2 * 64 + mt * 16 + (l & 15);
            pb[mt] = *(const bf16x8*)&Ps[r][(((l >> 4)) ^ ((r >> 1) & 3)) * 8];
        }
        #pragma unroll
        for (int ct = 0; ct < 2; ++ct) {
            int r = wc * 32 + ct * 16 + (l & 15);
            va[ct] = *(const bf16x8*)&Vs[r][(((l >> 4)) ^ ((r >> 1) & 3)) * 8];
        }
        #pragma unroll
        for (int ct = 0; ct < 2; ++ct)
            #pragma unroll
            for (int mt = 0; mt < 4; ++mt)
                acc[ct][mt] = __builtin_amdgcn_mfma_f32_16x16x32_bf16(
                    va[ct], pb[mt], acc[ct][mt], 0, 0, 0);
        __syncthreads();
    }
    float g = gamma[0];
    #pragma unroll
    for (int ct = 0; ct < 2; ++ct)
        #pragma unroll
        for (int mt = 0; mt < 4; ++mt)
            #pragma unroll
            for (int r = 0; r < 4; ++r) {
                int ch = wc * 32 + ct * 16 + (l >> 4) * 4 + r;
                int m = mb + wm2 * 64 + mt * 16 + (l & 15);
                size_t idx = (size_t)(b * 512 + h * 64 + ch) * 1024 + m;
                out0[idx] = g * acc[ct][mt][r] + x[idx];
            }
}

extern "C" void kernel_launch(void* const* d_in, const int* in_sizes, int n_in,
                              void* d_out, int out_size, void* d_ws, size_t ws_size,
                              hipStream_t stream) {
    const float* x     = (const float*)d_in[0];
    const float* dw_w  = (const float*)d_in[1];
    const float* dw_b  = (const float*)d_in[2];
    const float* ln_w  = (const float*)d_in[3];
    const float* ln_b  = (const float*)d_in[4];
    const float* pw_w  = (const float*)d_in[5];
    const float* q_w   = (const float*)d_in[6];
    const float* q_b   = (const float*)d_in[7];
    const float* k_w   = (const float*)d_in[8];
    const float* k_b   = (const float*)d_in[9];
    const float* v_w   = (const float*)d_in[10];
    const float* v_b   = (const float*)d_in[11];
    const float* rpe   = (const float*)d_in[12];
    const float* gamma = (const float*)d_in[13];

    float* out0 = (float*)d_out;
    float* attn = out0 + (size_t)4 * 512 * 1024;

    char* w = (char*)d_ws;
    short* xt   = (short*)w;                      // 4 MB
    short* qwb  = (short*)(w + 4194304);
    short* kwb  = (short*)(w + 4718592);
    short* vwb  = (short*)(w + 5242880);
    short* qbf  = (short*)(w + 5767168);          // 4 MB
    short* xsb  = (short*)(w + 9961472);          // 4 MB
    short* kbf  = (short*)(w + 14155776);         // 4 MB
    short* vbf  = (short*)(w + 18350080);         // 4 MB
    float* pos  = (float*)(w + 22544384);         // 32 KB

    prep_x<<<dim3(16, 8, 4), 256, 0, stream>>>(x, xt);
    wcast<<<384, 256, 0, stream>>>(q_w, k_w, v_w, qwb, kwb, vwb);
    gemm_nt<1><<<dim3(32, 4, 1), 256, 0, stream>>>(xt, qwb, q_b, qbf);
    offset_kernel<<<4096, 256, 0, stream>>>(qbf, dw_w, dw_b, ln_w, ln_b, pw_w, pos);
    sample_k<<<4096, 256, 0, stream>>>(xt, pos, xsb);
    gemm_nt<1><<<dim3(32, 4, 1), 256, 0, stream>>>(xsb, kwb, k_b, kbf);
    gemm_nt<2><<<dim3(4, 8, 4), 256, 0, stream>>>(vwb, xsb, v_b, vbf);
    attn_mfma<<<dim3(64, 8, 4), 256, 0, stream>>>(qbf, kbf, pos, rpe, attn);
    pv_mfma<<<dim3(8, 8, 4), 256, 0, stream>>>(attn, vbf, x, gamma, out0);
}

// Round 6
// 160.799 us; speedup vs baseline: 2.7437x; 1.0810x over previous
//
#include <hip/hip_runtime.h>
#include <hip/hip_bf16.h>
#include <math.h>

typedef short bf16x8 __attribute__((ext_vector_type(8)));
typedef float f32x4 __attribute__((ext_vector_type(4)));
typedef _Float16 h2 __attribute__((ext_vector_type(2)));

__device__ inline short f2bf(float f) {
    union { float f; unsigned u; } v; v.f = f;
    unsigned r = v.u + 0x7FFFu + ((v.u >> 16) & 1u);
    return (short)(r >> 16);
}
__device__ inline float bf2f(short s) {
    union { unsigned u; float f; } v; v.u = ((unsigned)(unsigned short)s) << 16;
    return v.f;
}
__device__ inline h2 pkrtz(float a, float b) {
    return __builtin_bit_cast(h2, __builtin_amdgcn_cvt_pkrtz(a, b));
}
__device__ inline unsigned cvtpk_bf16(float a, float b) {
    unsigned r;
    asm("v_cvt_pk_bf16_f32 %0, %1, %2" : "=v"(r) : "v"(a), "v"(b));
    return r;
}
__device__ inline float bflo(unsigned u) {
    return __builtin_bit_cast(float, u << 16);
}
__device__ inline float bfhi(unsigned u) {
    return __builtin_bit_cast(float, u & 0xFFFF0000u);
}
__device__ inline float dot2(h2 a, h2 b) {
#if __has_builtin(__builtin_amdgcn_fdot2)
    return __builtin_amdgcn_fdot2(a, b, 0.f, false);
#else
    return (float)a[0] * (float)b[0] + (float)a[1] * (float)b[1];
#endif
}

// ---------------------------------------------------------------------------
// transpose-cast: x [b][c][p] f32 -> xt [b][p][c] bf16
// ---------------------------------------------------------------------------
__global__ __launch_bounds__(256) void prep_x(const float* __restrict__ x,
                                              short* __restrict__ xt)
{
    __shared__ float ts[64][65];
    int p0 = blockIdx.x * 64, c0 = blockIdx.y * 64, b = blockIdx.z;
    int t = threadIdx.x;
    #pragma unroll
    for (int i = 0; i < 16; ++i) {
        int idx = i * 256 + t;
        int cl = idx >> 6, pl = idx & 63;
        ts[cl][pl] = x[((size_t)(b * 512 + c0 + cl)) * 1024 + p0 + pl];
    }
    __syncthreads();
    #pragma unroll
    for (int i = 0; i < 16; ++i) {
        int idx = i * 256 + t;
        int pl = idx >> 6, cl = idx & 63;
        xt[((size_t)(b * 1024 + p0 + pl)) * 512 + c0 + cl] = f2bf(ts[cl][pl]);
    }
}

// cast 3 weight matrices [512][512] f32 -> bf16
__global__ __launch_bounds__(256) void wcast(
    const float* __restrict__ qw, const float* __restrict__ kw,
    const float* __restrict__ vw, short* __restrict__ qwb,
    short* __restrict__ kwb, short* __restrict__ vwb)
{
    int idx = (blockIdx.x * 256 + threadIdx.x) * 8;
    int w = idx >> 18;
    int off = idx & 262143;
    const float* src = (w == 0) ? qw : (w == 1) ? kw : vw;
    short* dst = (w == 0) ? qwb : (w == 1) ? kwb : vwb;
    float4 f0 = *(const float4*)(src + off);
    float4 f1 = *(const float4*)(src + off + 4);
    bf16x8 o;
    o[0] = f2bf(f0.x); o[1] = f2bf(f0.y); o[2] = f2bf(f0.z); o[3] = f2bf(f0.w);
    o[4] = f2bf(f1.x); o[5] = f2bf(f1.y); o[6] = f2bf(f1.z); o[7] = f2bf(f1.w);
    *(bf16x8*)(dst + off) = o;
}

// ---------------------------------------------------------------------------
// NT MFMA GEMM: D[m][n] = sum_k A[m][k]*B[n][k] + bias; K=512
// MODE 1: q/k (M=4096,N=512, bias[n], out bf16 [m*512+n])
// MODE 2: v (M=512,N=1024, z-batched B, bias[m], out bf16 [(z*512+m)*1024+n])
// ---------------------------------------------------------------------------
template<int MODE>
__global__ __launch_bounds__(256) void gemm_nt(
    const short* __restrict__ A, const short* __restrict__ B,
    const float* __restrict__ bias, short* __restrict__ Ob)
{
    constexpr int K = 512;
    __shared__ short As[128][32];
    __shared__ short Bs[128][32];
    int m0 = blockIdx.x * 128, n0 = blockIdx.y * 128;
    const short* Bp = (MODE == 2) ? (B + (size_t)blockIdx.z * 524288) : B;
    int t = threadIdx.x, wid = t >> 6, l = t & 63;
    int wm = wid >> 1, wn = wid & 1;
    f32x4 acc[4][4] = {};
    int srow = t >> 1, half = t & 1;
    int sw = (srow >> 1) & 3;
    int s0 = (half * 2) ^ sw, s1 = (half * 2 + 1) ^ sw;
    for (int k0 = 0; k0 < K; k0 += 32) {
        const int4 a0 = *(const int4*)(A + (size_t)(m0 + srow) * K + k0 + half * 16);
        const int4 a1 = *(const int4*)(A + (size_t)(m0 + srow) * K + k0 + half * 16 + 8);
        const int4 b0 = *(const int4*)(Bp + (size_t)(n0 + srow) * K + k0 + half * 16);
        const int4 b1 = *(const int4*)(Bp + (size_t)(n0 + srow) * K + k0 + half * 16 + 8);
        __syncthreads();
        *(int4*)&As[srow][s0 * 8] = a0;
        *(int4*)&As[srow][s1 * 8] = a1;
        *(int4*)&Bs[srow][s0 * 8] = b0;
        *(int4*)&Bs[srow][s1 * 8] = b1;
        __syncthreads();
        bf16x8 af[4], bfr[4];
        #pragma unroll
        for (int mt = 0; mt < 4; ++mt) {
            int r = wm * 64 + mt * 16 + (l & 15);
            af[mt] = *(const bf16x8*)&As[r][(((l >> 4)) ^ ((r >> 1) & 3)) * 8];
        }
        #pragma unroll
        for (int nt = 0; nt < 4; ++nt) {
            int r = wn * 64 + nt * 16 + (l & 15);
            bfr[nt] = *(const bf16x8*)&Bs[r][(((l >> 4)) ^ ((r >> 1) & 3)) * 8];
        }
        #pragma unroll
        for (int mt = 0; mt < 4; ++mt)
            #pragma unroll
            for (int nt = 0; nt < 4; ++nt)
                acc[mt][nt] = __builtin_amdgcn_mfma_f32_16x16x32_bf16(
                    af[mt], bfr[nt], acc[mt][nt], 0, 0, 0);
    }
    #pragma unroll
    for (int mt = 0; mt < 4; ++mt)
        #pragma unroll
        for (int nt = 0; nt < 4; ++nt)
            #pragma unroll
            for (int r = 0; r < 4; ++r) {
                int m = m0 + wm * 64 + mt * 16 + (l >> 4) * 4 + r;
                int n = n0 + wn * 64 + nt * 16 + (l & 15);
                float val = acc[mt][nt][r] + ((MODE == 2) ? bias[m] : bias[n]);
                if (MODE == 1) {
                    Ob[(size_t)m * 512 + n] = f2bf(val);
                } else {
                    Ob[((size_t)blockIdx.z * 512 + m) * 1024 + n] = f2bf(val);
                }
            }
}

// ---------------------------------------------------------------------------
// offset network (reads q bf16 in [b][p][c] layout) -> pos[b][p][2] (y,x)
// ---------------------------------------------------------------------------
__global__ __launch_bounds__(256) void offset_kernel(
    const short* __restrict__ qbf, const float* __restrict__ dw_w,
    const float* __restrict__ dw_b, const float* __restrict__ ln_w,
    const float* __restrict__ ln_b, const float* __restrict__ pw_w,
    float* __restrict__ pos)
{
    __shared__ float red[8];
    int bid = blockIdx.x;
    int b = bid >> 10, p = bid & 1023;
    int y = p >> 5, x = p & 31;
    int t = threadIdx.x;
    int c0 = 2 * t;
    const short* qb = qbf + (size_t)b * 524288;
    float h0, h1;
    {
        const float* w0 = dw_w + c0 * 9;
        const float* w1 = w0 + 9;
        float s0 = 0.f, s1 = 0.f;
        #pragma unroll
        for (int ky = 0; ky < 3; ++ky) {
            int yy = y + ky - 1;
            if (yy < 0 || yy > 31) continue;
            #pragma unroll
            for (int kx = 0; kx < 3; ++kx) {
                int xx = x + kx - 1;
                if (xx < 0 || xx > 31) continue;
                unsigned u = *(const unsigned*)(qb + (size_t)(yy * 32 + xx) * 512 + c0);
                s0 += bf2f((short)(u & 0xFFFF)) * w0[ky * 3 + kx];
                s1 += bf2f((short)(u >> 16)) * w1[ky * 3 + kx];
            }
        }
        float2 db = *(const float2*)(dw_b + c0);
        h0 = s0 + db.x; h1 = s1 + db.y;
    }
    float ls = h0 + h1;
    float lq = h0 * h0 + h1 * h1;
    #pragma unroll
    for (int s = 32; s >= 1; s >>= 1) {
        ls += __shfl_xor(ls, s);
        lq += __shfl_xor(lq, s);
    }
    int wid = t >> 6, lane = t & 63;
    if (lane == 0) { red[wid] = ls; red[4 + wid] = lq; }
    __syncthreads();
    float mu  = (red[0] + red[1] + red[2] + red[3]) * (1.f / 512.f);
    float var = (red[4] + red[5] + red[6] + red[7]) * (1.f / 512.f) - mu * mu;
    float rstd = rsqrtf(var + 1e-5f);
    float o0, o1;
    {
        float2 lw = *(const float2*)(ln_w + c0);
        float2 lb = *(const float2*)(ln_b + c0);
        float2 p0 = *(const float2*)(pw_w + c0);
        float2 p1 = *(const float2*)(pw_w + 512 + c0);
        float hn0 = (h0 - mu) * rstd * lw.x + lb.x;
        float hn1 = (h1 - mu) * rstd * lw.y + lb.y;
        float g0 = 0.5f * hn0 * (1.f + erff(hn0 * 0.70710678118f));
        float g1 = 0.5f * hn1 * (1.f + erff(hn1 * 0.70710678118f));
        o0 = g0 * p0.x + g1 * p0.y;
        o1 = g0 * p1.x + g1 * p1.y;
    }
    #pragma unroll
    for (int s = 32; s >= 1; s >>= 1) {
        o0 += __shfl_xor(o0, s);
        o1 += __shfl_xor(o1, s);
    }
    __syncthreads();
    if (lane == 0) { red[wid] = o0; red[4 + wid] = o1; }
    __syncthreads();
    if (t == 0) {
        float oy = tanhf(red[0] + red[1] + red[2] + red[3]) * 0.0625f;
        float ox = tanhf(red[4] + red[5] + red[6] + red[7]) * 0.0625f;
        float ry = ((y + 0.5f) * (1.f / 32.f)) * 2.f - 1.f;
        float rx = ((x + 0.5f) * (1.f / 32.f)) * 2.f - 1.f;
        pos[bid * 2]     = oy + ry;
        pos[bid * 2 + 1] = ox + rx;
    }
}

// ---------------------------------------------------------------------------
// bilinear sample of xt (bf16 [b][p][c]) at pos -> xs bf16 [b][p][c]
// ---------------------------------------------------------------------------
__global__ __launch_bounds__(256) void sample_k(
    const short* __restrict__ xt, const float* __restrict__ pos,
    short* __restrict__ xs)
{
    int bid = blockIdx.x;
    int b = bid >> 10;
    float py = pos[bid * 2], px = pos[bid * 2 + 1];
    float gx = (px + 1.f) * 15.5f;
    float gy = (py + 1.f) * 15.5f;
    float x0f = floorf(gx), y0f = floorf(gy);
    int ix0 = (int)x0f, iy0 = (int)y0f;
    float wx1 = gx - x0f, wx0 = 1.f - wx1;
    float wy1 = gy - y0f, wy0 = 1.f - wy1;
    const short* base = xt + (size_t)b * 524288;
    int t = threadIdx.x;
    float a0 = 0.f, a1 = 0.f;
    #pragma unroll
    for (int tap = 0; tap < 4; ++tap) {
        int ix = ix0 + (tap & 1), iy = iy0 + (tap >> 1);
        float w = ((tap & 1) ? wx1 : wx0) * ((tap >> 1) ? wy1 : wy0);
        if (ix >= 0 && ix < 32 && iy >= 0 && iy < 32) {
            unsigned u = *(const unsigned*)(base + (size_t)(iy * 32 + ix) * 512 + 2 * t);
            a0 += bf2f((short)(u & 0xFFFF)) * w;
            a1 += bf2f((short)(u >> 16)) * w;
        }
    }
    unsigned o = ((unsigned)(unsigned short)f2bf(a0)) |
                 (((unsigned)(unsigned short)f2bf(a1)) << 16);
    *(unsigned*)(xs + (size_t)bid * 512 + 2 * t) = o;
}

// ---------------------------------------------------------------------------
// FUSED attention: QK^T (MFMA) + RPE bias + softmax + attn write + PV + out.
// m-tile = 16 rows; 4 waves each own a 256-col quarter in pass A.
// P normalized -> bf16 in LDS Pn[16][1032]; attn fp32 written from LDS
// (coalesced float4); PV: wave wn owns 16 output channels, A-frags from Pn,
// V-frags direct global bf16x8; epilogue fuses gamma*D + x.
// grid (64 m-tiles, 8 h, 4 b)
// ---------------------------------------------------------------------------
__global__ __launch_bounds__(256, 4) void attn_fused(
    const short* __restrict__ qbf, const short* __restrict__ kbf,
    const short* __restrict__ vbf, const float* __restrict__ pos,
    const float* __restrict__ rpe, const float* __restrict__ x,
    const float* __restrict__ gamma, float* __restrict__ attn_out,
    float* __restrict__ out0)
{
    __shared__ __align__(16) char smem_raw[33024];   // passA: rpe2p+pos | then: Pn
    __shared__ float S_part[16][4];
    h2*    rpe_s = (h2*)smem_raw;                     // [65*65] padded pair table
    h2*    pos_s = (h2*)(smem_raw + 16960);           // [1024] (y,x) f16
    short* Pn    = (short*)smem_raw;                  // [16][1032] bf16 probs

    int m0 = blockIdx.x * 16, h = blockIdx.y, b = blockIdx.z;
    int t = threadIdx.x, wn = t >> 6, l = t & 63;
    int g = l >> 4, c16 = l & 15;

    // ---- build padded pair table: entry (iy+1, ix+1) = (v[iy][ix], v[iy][ix+1])
    #pragma unroll
    for (int i = 0; i < 17; ++i) {
        int e = i * 256 + t;
        if (e < 4225) rpe_s[e] = (h2)((_Float16)0.f);
    }
    __syncthreads();
    const float* rh = rpe + h * 3969;
    for (int i = 0; i < 16; ++i) {
        int e = i * 256 + t;
        if (e < 3969) {
            int iy = (int)(((unsigned)e * 16645u) >> 20);   // e/63 exact for e<3969
            int ix = e - iy * 63;
            float v0 = rh[e];
            float v1 = (ix < 62) ? rh[e + 1] : 0.f;
            h2 pr; pr[0] = (_Float16)v0; pr[1] = (_Float16)v1;
            rpe_s[(iy + 1) * 65 + ix + 1] = pr;
        }
    }
    if (t < 63) {  // left border column: (0, v[iy][0])
        h2 pr; pr[0] = (_Float16)0.f; pr[1] = (_Float16)rh[t * 63];
        rpe_s[(t + 1) * 65] = pr;
    }
    #pragma unroll
    for (int i = 0; i < 4; ++i) {
        int idx = i * 256 + t;
        float2 pf = *(const float2*)(pos + b * 2048 + idx * 2);
        pos_s[idx] = pkrtz(pf.x, pf.y);
    }
    // q fragments (16 rows shared by all 4 waves)
    int rowm = m0 + c16;
    const short* qrow = qbf + ((size_t)(b * 1024 + rowm) * 512 + h * 64 + g * 8);
    bf16x8 aq0 = *(const bf16x8*)qrow;
    bf16x8 aq1 = *(const bf16x8*)(qrow + 32);
    float qy15[4], qx15[4];
    #pragma unroll
    for (int r = 0; r < 4; ++r) {
        int rm = m0 + g * 4 + r;
        qy15[r] = (((rm >> 5) + 0.5f) * (1.f / 16.f) - 1.f) * 15.5f;
        qx15[r] = (((rm & 31) + 0.5f) * (1.f / 16.f) - 1.f) * 15.5f;
    }
    __syncthreads();

    // ---- pass A: 16 col-tiles of 16; exp -> packed bf16 pairs in VGPRs
    float Ssum[4] = {0.f, 0.f, 0.f, 0.f};
    float eprev[4];
    unsigned ep[4][8];
    #pragma unroll
    for (int nt = 0; nt < 16; ++nt) {
        int col = wn * 256 + nt * 16 + c16;
        const short* krow = kbf + ((size_t)(b * 1024 + col) * 512 + h * 64 + g * 8);
        bf16x8 bk0 = *(const bf16x8*)krow;
        bf16x8 bk1 = *(const bf16x8*)(krow + 32);
        f32x4 acc = {0.f, 0.f, 0.f, 0.f};
        acc = __builtin_amdgcn_mfma_f32_16x16x32_bf16(aq0, bk0, acc, 0, 0, 0);
        acc = __builtin_amdgcn_mfma_f32_16x16x32_bf16(aq1, bk1, acc, 0, 0, 0);
        h2 pp = pos_s[col];
        float cyn = 32.f - (float)pp[0] * 15.5f;
        float cxn = 32.f - (float)pp[1] * 15.5f;
        #pragma unroll
        for (int r = 0; r < 4; ++r) {
            float gyp = qy15[r] + cyn;
            float gxp = qx15[r] + cxn;
            float fy = floorf(gyp), fx = floorf(gxp);
            float wy1 = gyp - fy, wx1 = gxp - fx;
            int ad = (int)fy * 65 + (int)fx;
            h2 r0 = rpe_s[ad];
            h2 r1 = rpe_s[ad + 65];
            h2 wp = pkrtz(1.f - wx1, wx1);
            float t0 = dot2(r0, wp);
            float t1 = dot2(r1, wp);
            float bias = t0 + wy1 * (t1 - t0);
            float logit = fmaf(acc[r], 0.125f, bias);
            float e = __expf(logit);
            Ssum[r] += e;
            if (nt & 1) {
                ep[r][nt >> 1] = cvtpk_bf16(eprev[r], e);
            } else {
                eprev[r] = e;
            }
        }
    }
    #pragma unroll
    for (int s = 1; s < 16; s <<= 1)
        #pragma unroll
        for (int r = 0; r < 4; ++r) Ssum[r] += __shfl_xor(Ssum[r], s);
    if (c16 == 0)
        #pragma unroll
        for (int r = 0; r < 4; ++r) S_part[g * 4 + r][wn] = Ssum[r];
    __syncthreads();   // all pass-A LDS reads done; rpe/pos region now dead
    float invS[4];
    #pragma unroll
    for (int r = 0; r < 4; ++r) {
        int row = g * 4 + r;
        invS[r] = 1.f / (S_part[row][0] + S_part[row][1] + S_part[row][2] + S_part[row][3]);
    }

    // ---- normalize -> bf16 into Pn[16][1032]
    #pragma unroll
    for (int r = 0; r < 4; ++r) {
        short* prow = Pn + (g * 4 + r) * 1032 + wn * 256 + c16;
        #pragma unroll
        for (int j = 0; j < 8; ++j) {
            unsigned u = ep[r][j];
            unsigned pk = cvtpk_bf16(bflo(u) * invS[r], bfhi(u) * invS[r]);
            prow[j * 32]      = (short)(pk & 0xFFFF);
            prow[j * 32 + 16] = (short)(pk >> 16);
        }
    }
    __syncthreads();

    // ---- attn fp32 write from LDS (coalesced float4; thread t -> cols 4t..4t+3)
    size_t obase = ((size_t)((b * 8 + h) * 1024 + m0)) * 1024;
    #pragma unroll
    for (int row = 0; row < 16; ++row) {
        const unsigned* pr = (const unsigned*)(Pn + row * 1032 + t * 4);
        unsigned u0 = pr[0], u1 = pr[1];
        float4 vv = make_float4(bflo(u0), bfhi(u0), bflo(u1), bfhi(u1));
        *(float4*)(attn_out + obase + (size_t)row * 1024 + t * 4) = vv;
    }

    // ---- PV: wave wn owns channels wn*16..wn*16+15; loop n in 32-chunks
    const short* Vb = vbf + ((size_t)(b * 512 + h * 64 + wn * 16 + c16)) * 1024;
    const short* Prow = Pn + c16 * 1032 + g * 8;
    f32x4 dacc = {0.f, 0.f, 0.f, 0.f};
    #pragma unroll
    for (int cc = 0; cc < 32; ++cc) {
        int n0 = cc * 32;
        bf16x8 pa  = *(const bf16x8*)(Prow + n0);
        bf16x8 vb8 = *(const bf16x8*)(Vb + n0 + g * 8);
        dacc = __builtin_amdgcn_mfma_f32_16x16x32_bf16(pa, vb8, dacc, 0, 0, 0);
    }
    float gm = gamma[0];
    #pragma unroll
    for (int r = 0; r < 4; ++r) {
        int ch = h * 64 + wn * 16 + c16;
        int m = m0 + g * 4 + r;
        size_t idx = ((size_t)(b * 512 + ch)) * 1024 + m;
        out0[idx] = gm * dacc[r] + x[idx];
    }
}

extern "C" void kernel_launch(void* const* d_in, const int* in_sizes, int n_in,
                              void* d_out, int out_size, void* d_ws, size_t ws_size,
                              hipStream_t stream) {
    const float* x     = (const float*)d_in[0];
    const float* dw_w  = (const float*)d_in[1];
    const float* dw_b  = (const float*)d_in[2];
    const float* ln_w  = (const float*)d_in[3];
    const float* ln_b  = (const float*)d_in[4];
    const float* pw_w  = (const float*)d_in[5];
    const float* q_w   = (const float*)d_in[6];
    const float* q_b   = (const float*)d_in[7];
    const float* k_w   = (const float*)d_in[8];
    const float* k_b   = (const float*)d_in[9];
    const float* v_w   = (const float*)d_in[10];
    const float* v_b   = (const float*)d_in[11];
    const float* rpe   = (const float*)d_in[12];
    const float* gamma = (const float*)d_in[13];

    float* out0 = (float*)d_out;
    float* attn = out0 + (size_t)4 * 512 * 1024;

    char* w = (char*)d_ws;
    short* xt   = (short*)w;                      // 4 MB
    short* qwb  = (short*)(w + 4194304);
    short* kwb  = (short*)(w + 4718592);
    short* vwb  = (short*)(w + 5242880);
    short* qbf  = (short*)(w + 5767168);          // 4 MB
    short* xsb  = (short*)(w + 9961472);          // 4 MB
    short* kbf  = (short*)(w + 14155776);         // 4 MB
    short* vbf  = (short*)(w + 18350080);         // 4 MB
    float* pos  = (float*)(w + 22544384);         // 32 KB

    prep_x<<<dim3(16, 8, 4), 256, 0, stream>>>(x, xt);
    wcast<<<384, 256, 0, stream>>>(q_w, k_w, v_w, qwb, kwb, vwb);
    gemm_nt<1><<<dim3(32, 4, 1), 256, 0, stream>>>(xt, qwb, q_b, qbf);
    offset_kernel<<<4096, 256, 0, stream>>>(qbf, dw_w, dw_b, ln_w, ln_b, pw_w, pos);
    sample_k<<<4096, 256, 0, stream>>>(xt, pos, xsb);
    gemm_nt<1><<<dim3(32, 4, 1), 256, 0, stream>>>(xsb, kwb, k_b, kbf);
    gemm_nt<2><<<dim3(4, 8, 4), 256, 0, stream>>>(vwb, xsb, v_b, vbf);
    attn_fused<<<dim3(64, 8, 4), 256, 0, stream>>>(qbf, kbf, vbf, pos, rpe, x,
                                                   gamma, attn, out0);
}

// Round 7
// 148.690 us; speedup vs baseline: 2.9672x; 1.0814x over previous
//
#include <hip/hip_runtime.h>
#include <hip/hip_bf16.h>
#include <math.h>

typedef short bf16x8 __attribute__((ext_vector_type(8)));
typedef _Float16 f16x8 __attribute__((ext_vector_type(8)));
typedef float f32x4 __attribute__((ext_vector_type(4)));
typedef _Float16 h2 __attribute__((ext_vector_type(2)));

__device__ inline short f2bf(float f) {
    union { float f; unsigned u; } v; v.f = f;
    unsigned r = v.u + 0x7FFFu + ((v.u >> 16) & 1u);
    return (short)(r >> 16);
}
__device__ inline float bf2f(short s) {
    union { unsigned u; float f; } v; v.u = ((unsigned)(unsigned short)s) << 16;
    return v.f;
}
__device__ inline h2 pkrtz(float a, float b) {
    return __builtin_bit_cast(h2, __builtin_amdgcn_cvt_pkrtz(a, b));
}
__device__ inline float dot2(h2 a, h2 b) {
#if __has_builtin(__builtin_amdgcn_fdot2)
    return __builtin_amdgcn_fdot2(a, b, 0.f, false);
#else
    return (float)a[0] * (float)b[0] + (float)a[1] * (float)b[1];
#endif
}

// ---------------------------------------------------------------------------
// transpose-cast: x [b][c][p] f32 -> xt [b][p][c] bf16
// ---------------------------------------------------------------------------
__global__ __launch_bounds__(256) void prep_x(const float* __restrict__ x,
                                              short* __restrict__ xt)
{
    __shared__ float ts[64][65];
    int p0 = blockIdx.x * 64, c0 = blockIdx.y * 64, b = blockIdx.z;
    int t = threadIdx.x;
    #pragma unroll
    for (int i = 0; i < 16; ++i) {
        int idx = i * 256 + t;
        int cl = idx >> 6, pl = idx & 63;
        ts[cl][pl] = x[((size_t)(b * 512 + c0 + cl)) * 1024 + p0 + pl];
    }
    __syncthreads();
    #pragma unroll
    for (int i = 0; i < 16; ++i) {
        int idx = i * 256 + t;
        int pl = idx >> 6, cl = idx & 63;
        xt[((size_t)(b * 1024 + p0 + pl)) * 512 + c0 + cl] = f2bf(ts[cl][pl]);
    }
}

// cast 3 weight matrices [512][512] f32 -> bf16
__global__ __launch_bounds__(256) void wcast(
    const float* __restrict__ qw, const float* __restrict__ kw,
    const float* __restrict__ vw, short* __restrict__ qwb,
    short* __restrict__ kwb, short* __restrict__ vwb)
{
    int idx = (blockIdx.x * 256 + threadIdx.x) * 8;
    int w = idx >> 18;
    int off = idx & 262143;
    const float* src = (w == 0) ? qw : (w == 1) ? kw : vw;
    short* dst = (w == 0) ? qwb : (w == 1) ? kwb : vwb;
    float4 f0 = *(const float4*)(src + off);
    float4 f1 = *(const float4*)(src + off + 4);
    bf16x8 o;
    o[0] = f2bf(f0.x); o[1] = f2bf(f0.y); o[2] = f2bf(f0.z); o[3] = f2bf(f0.w);
    o[4] = f2bf(f1.x); o[5] = f2bf(f1.y); o[6] = f2bf(f1.z); o[7] = f2bf(f1.w);
    *(bf16x8*)(dst + off) = o;
}

// ---------------------------------------------------------------------------
// 128x128 NT MFMA tile body (K=512): acc[4][4] per thread.
// ---------------------------------------------------------------------------
__device__ inline void nt_tile_128(const short* __restrict__ A,
                                   const short* __restrict__ B,
                                   int m0, int n0, int t,
                                   short (*As)[32], short (*Bs)[32],
                                   f32x4 (&acc)[4][4])
{
    int wid = t >> 6, l = t & 63;
    int wm = wid >> 1, wn = wid & 1;
    int srow = t >> 1, half = t & 1;
    int sw = (srow >> 1) & 3;
    int s0 = (half * 2) ^ sw, s1 = (half * 2 + 1) ^ sw;
    for (int k0 = 0; k0 < 512; k0 += 32) {
        const int4 a0 = *(const int4*)(A + (size_t)(m0 + srow) * 512 + k0 + half * 16);
        const int4 a1 = *(const int4*)(A + (size_t)(m0 + srow) * 512 + k0 + half * 16 + 8);
        const int4 b0 = *(const int4*)(B + (size_t)(n0 + srow) * 512 + k0 + half * 16);
        const int4 b1 = *(const int4*)(B + (size_t)(n0 + srow) * 512 + k0 + half * 16 + 8);
        __syncthreads();
        *(int4*)&As[srow][s0 * 8] = a0;
        *(int4*)&As[srow][s1 * 8] = a1;
        *(int4*)&Bs[srow][s0 * 8] = b0;
        *(int4*)&Bs[srow][s1 * 8] = b1;
        __syncthreads();
        bf16x8 af[4], bfr[4];
        #pragma unroll
        for (int mt = 0; mt < 4; ++mt) {
            int r = wm * 64 + mt * 16 + (l & 15);
            af[mt] = *(const bf16x8*)&As[r][(((l >> 4)) ^ ((r >> 1) & 3)) * 8];
        }
        #pragma unroll
        for (int nt = 0; nt < 4; ++nt) {
            int r = wn * 64 + nt * 16 + (l & 15);
            bfr[nt] = *(const bf16x8*)&Bs[r][(((l >> 4)) ^ ((r >> 1) & 3)) * 8];
        }
        #pragma unroll
        for (int mt = 0; mt < 4; ++mt)
            #pragma unroll
            for (int nt = 0; nt < 4; ++nt)
                acc[mt][nt] = __builtin_amdgcn_mfma_f32_16x16x32_bf16(
                    af[mt], bfr[nt], acc[mt][nt], 0, 0, 0);
    }
}

// q projection: D[m][n] = xt[m][:]·qwb[n][:] + q_b[n] -> bf16 [m*512+n]
__global__ __launch_bounds__(256) void gemm_q(
    const short* __restrict__ A, const short* __restrict__ B,
    const float* __restrict__ bias, short* __restrict__ Ob)
{
    __shared__ short As[128][32];
    __shared__ short Bs[128][32];
    int m0 = blockIdx.x * 128, n0 = blockIdx.y * 128;
    int t = threadIdx.x, wid = t >> 6, l = t & 63;
    int wm = wid >> 1, wn = wid & 1;
    f32x4 acc[4][4] = {};
    nt_tile_128(A, B, m0, n0, t, As, Bs, acc);
    #pragma unroll
    for (int mt = 0; mt < 4; ++mt)
        #pragma unroll
        for (int nt = 0; nt < 4; ++nt)
            #pragma unroll
            for (int r = 0; r < 4; ++r) {
                int m = m0 + wm * 64 + mt * 16 + (l >> 4) * 4 + r;
                int n = n0 + wn * 64 + nt * 16 + (l & 15);
                Ob[(size_t)m * 512 + n] = f2bf(acc[mt][nt][r] + bias[n]);
            }
}

// k-gemm (bid<128, bf16 out) + v-gemm (bid>=128, f16 out) in ONE launch
__global__ __launch_bounds__(256) void gemm_kv(
    const short* __restrict__ xsb, const short* __restrict__ kwb,
    const float* __restrict__ k_b, short* __restrict__ kbf,
    const short* __restrict__ vwb, const float* __restrict__ v_b,
    short* __restrict__ vhf)
{
    __shared__ short As[128][32];
    __shared__ short Bs[128][32];
    int bid = blockIdx.x;
    int t = threadIdx.x, wid = t >> 6, l = t & 63;
    int wm = wid >> 1, wn = wid & 1;
    f32x4 acc[4][4] = {};
    if (bid < 128) {
        int m0 = (bid >> 2) * 128, n0 = (bid & 3) * 128;
        nt_tile_128(xsb, kwb, m0, n0, t, As, Bs, acc);
        #pragma unroll
        for (int mt = 0; mt < 4; ++mt)
            #pragma unroll
            for (int nt = 0; nt < 4; ++nt)
                #pragma unroll
                for (int r = 0; r < 4; ++r) {
                    int m = m0 + wm * 64 + mt * 16 + (l >> 4) * 4 + r;
                    int n = n0 + wn * 64 + nt * 16 + (l & 15);
                    kbf[(size_t)m * 512 + n] = f2bf(acc[mt][nt][r] + k_b[n]);
                }
    } else {
        int id2 = bid - 128;
        int z = id2 >> 5, rr = id2 & 31;
        int m0 = (rr >> 3) * 128, n0 = (rr & 7) * 128;
        nt_tile_128(vwb, xsb + (size_t)z * 524288, m0, n0, t, As, Bs, acc);
        #pragma unroll
        for (int mt = 0; mt < 4; ++mt)
            #pragma unroll
            for (int nt = 0; nt < 4; ++nt)
                #pragma unroll
                for (int r = 0; r < 4; ++r) {
                    int m = m0 + wm * 64 + mt * 16 + (l >> 4) * 4 + r;
                    int n = n0 + wn * 64 + nt * 16 + (l & 15);
                    _Float16 hv = (_Float16)(acc[mt][nt][r] + v_b[m]);
                    vhf[((size_t)z * 512 + m) * 1024 + n] = __builtin_bit_cast(short, hv);
                }
    }
}

// ---------------------------------------------------------------------------
// offset network (reads q bf16 in [b][p][c] layout) -> pos[b][p][2] (y,x)
// ---------------------------------------------------------------------------
__global__ __launch_bounds__(256) void offset_kernel(
    const short* __restrict__ qbf, const float* __restrict__ dw_w,
    const float* __restrict__ dw_b, const float* __restrict__ ln_w,
    const float* __restrict__ ln_b, const float* __restrict__ pw_w,
    float* __restrict__ pos)
{
    __shared__ float red[8];
    int bid = blockIdx.x;
    int b = bid >> 10, p = bid & 1023;
    int y = p >> 5, x = p & 31;
    int t = threadIdx.x;
    int c0 = 2 * t;
    const short* qb = qbf + (size_t)b * 524288;
    float h0, h1;
    {
        const float* w0 = dw_w + c0 * 9;
        const float* w1 = w0 + 9;
        float s0 = 0.f, s1 = 0.f;
        #pragma unroll
        for (int ky = 0; ky < 3; ++ky) {
            int yy = y + ky - 1;
            if (yy < 0 || yy > 31) continue;
            #pragma unroll
            for (int kx = 0; kx < 3; ++kx) {
                int xx = x + kx - 1;
                if (xx < 0 || xx > 31) continue;
                unsigned u = *(const unsigned*)(qb + (size_t)(yy * 32 + xx) * 512 + c0);
                s0 += bf2f((short)(u & 0xFFFF)) * w0[ky * 3 + kx];
                s1 += bf2f((short)(u >> 16)) * w1[ky * 3 + kx];
            }
        }
        float2 db = *(const float2*)(dw_b + c0);
        h0 = s0 + db.x; h1 = s1 + db.y;
    }
    float ls = h0 + h1;
    float lq = h0 * h0 + h1 * h1;
    #pragma unroll
    for (int s = 32; s >= 1; s >>= 1) {
        ls += __shfl_xor(ls, s);
        lq += __shfl_xor(lq, s);
    }
    int wid = t >> 6, lane = t & 63;
    if (lane == 0) { red[wid] = ls; red[4 + wid] = lq; }
    __syncthreads();
    float mu  = (red[0] + red[1] + red[2] + red[3]) * (1.f / 512.f);
    float var = (red[4] + red[5] + red[6] + red[7]) * (1.f / 512.f) - mu * mu;
    float rstd = rsqrtf(var + 1e-5f);
    float o0, o1;
    {
        float2 lw = *(const float2*)(ln_w + c0);
        float2 lb = *(const float2*)(ln_b + c0);
        float2 p0 = *(const float2*)(pw_w + c0);
        float2 p1 = *(const float2*)(pw_w + 512 + c0);
        float hn0 = (h0 - mu) * rstd * lw.x + lb.x;
        float hn1 = (h1 - mu) * rstd * lw.y + lb.y;
        float g0 = 0.5f * hn0 * (1.f + erff(hn0 * 0.70710678118f));
        float g1 = 0.5f * hn1 * (1.f + erff(hn1 * 0.70710678118f));
        o0 = g0 * p0.x + g1 * p0.y;
        o1 = g0 * p1.x + g1 * p1.y;
    }
    #pragma unroll
    for (int s = 32; s >= 1; s >>= 1) {
        o0 += __shfl_xor(o0, s);
        o1 += __shfl_xor(o1, s);
    }
    __syncthreads();
    if (lane == 0) { red[wid] = o0; red[4 + wid] = o1; }
    __syncthreads();
    if (t == 0) {
        float oy = tanhf(red[0] + red[1] + red[2] + red[3]) * 0.0625f;
        float ox = tanhf(red[4] + red[5] + red[6] + red[7]) * 0.0625f;
        float ry = ((y + 0.5f) * (1.f / 32.f)) * 2.f - 1.f;
        float rx = ((x + 0.5f) * (1.f / 32.f)) * 2.f - 1.f;
        pos[bid * 2]     = oy + ry;
        pos[bid * 2 + 1] = ox + rx;
    }
}

// ---------------------------------------------------------------------------
// bilinear sample of xt (bf16 [b][p][c]) at pos -> xs bf16 [b][p][c]
// ---------------------------------------------------------------------------
__global__ __launch_bounds__(256) void sample_k(
    const short* __restrict__ xt, const float* __restrict__ pos,
    short* __restrict__ xs)
{
    int bid = blockIdx.x;
    int b = bid >> 10;
    float py = pos[bid * 2], px = pos[bid * 2 + 1];
    float gx = (px + 1.f) * 15.5f;
    float gy = (py + 1.f) * 15.5f;
    float x0f = floorf(gx), y0f = floorf(gy);
    int ix0 = (int)x0f, iy0 = (int)y0f;
    float wx1 = gx - x0f, wx0 = 1.f - wx1;
    float wy1 = gy - y0f, wy0 = 1.f - wy1;
    const short* base = xt + (size_t)b * 524288;
    int t = threadIdx.x;
    float a0 = 0.f, a1 = 0.f;
    #pragma unroll
    for (int tap = 0; tap < 4; ++tap) {
        int ix = ix0 + (tap & 1), iy = iy0 + (tap >> 1);
        float w = ((tap & 1) ? wx1 : wx0) * ((tap >> 1) ? wy1 : wy0);
        if (ix >= 0 && ix < 32 && iy >= 0 && iy < 32) {
            unsigned u = *(const unsigned*)(base + (size_t)(iy * 32 + ix) * 512 + 2 * t);
            a0 += bf2f((short)(u & 0xFFFF)) * w;
            a1 += bf2f((short)(u >> 16)) * w;
        }
    }
    unsigned o = ((unsigned)(unsigned short)f2bf(a0)) |
                 (((unsigned)(unsigned short)f2bf(a1)) << 16);
    *(unsigned*)(xs + (size_t)bid * 512 + 2 * t) = o;
}

// ---------------------------------------------------------------------------
// FUSED attention, 512 threads (8 waves): wave wn owns cols wn*128..+127 in
// pass A (QK^T MFMA + RPE bias + exp, ep[4][4] packed f16 in regs). After
// softmax-sum: P normalized -> f16 LDS Pn[16][1032] (overlays rpe region).
// Then wave split: waves 0-3 do PV (f16 MFMA, V f16 from global) + fused
// gamma*D+x epilogue; waves 4-7 stream attn fp32 from LDS (float4).
// grid (64 m-tiles, 8 h, 4 b)
// ---------------------------------------------------------------------------
__global__ __launch_bounds__(512, 4) void attn_fused(
    const short* __restrict__ qbf, const short* __restrict__ kbf,
    const short* __restrict__ vhf, const float* __restrict__ pos,
    const float* __restrict__ rpe, const float* __restrict__ x,
    const float* __restrict__ gamma, float* __restrict__ attn_out,
    float* __restrict__ out0)
{
    __shared__ __align__(16) char smem_raw[33024];   // rpe(16960)+pos(4096) | Pn 16*1032*2
    __shared__ float S_part[16][8];
    h2*    rpe_s = (h2*)smem_raw;                     // [65*65] padded pair table
    h2*    pos_s = (h2*)(smem_raw + 16960);           // [1024] (y,x) f16
    short* Pn    = (short*)smem_raw;                  // [16][1032] f16 normalized P

    int m0 = blockIdx.x * 16, h = blockIdx.y, b = blockIdx.z;
    int t = threadIdx.x, wn = t >> 6, l = t & 63;
    int g = l >> 4, c16 = l & 15;

    // ---- padded pair table: entry (iy+1, ix+1) = (v[iy][ix], v[iy][ix+1])
    #pragma unroll
    for (int i = 0; i < 9; ++i) {
        int e = i * 512 + t;
        if (e < 4225) rpe_s[e] = (h2)((_Float16)0.f);
    }
    __syncthreads();
    const float* rh = rpe + h * 3969;
    #pragma unroll
    for (int i = 0; i < 8; ++i) {
        int e = i * 512 + t;
        if (e < 3969) {
            int iy = (int)(((unsigned)e * 16645u) >> 20);   // e/63 exact for e<3969
            int ix = e - iy * 63;
            float v0 = rh[e];
            float v1 = (ix < 62) ? rh[e + 1] : 0.f;
            h2 pr; pr[0] = (_Float16)v0; pr[1] = (_Float16)v1;
            rpe_s[(iy + 1) * 65 + ix + 1] = pr;
        }
    }
    if (t < 63) {  // left border column: (0, v[iy][0])
        h2 pr; pr[0] = (_Float16)0.f; pr[1] = (_Float16)rh[t * 63];
        rpe_s[(t + 1) * 65] = pr;
    }
    #pragma unroll
    for (int i = 0; i < 2; ++i) {
        int idx = i * 512 + t;
        float2 pf = *(const float2*)(pos + b * 2048 + idx * 2);
        pos_s[idx] = pkrtz(pf.x, pf.y);
    }
    // q fragments (16 rows shared by all 8 waves)
    int rowm = m0 + c16;
    const short* qrow = qbf + ((size_t)(b * 1024 + rowm) * 512 + h * 64 + g * 8);
    bf16x8 aq0 = *(const bf16x8*)qrow;
    bf16x8 aq1 = *(const bf16x8*)(qrow + 32);
    float qy15[4], qx15[4];
    #pragma unroll
    for (int r = 0; r < 4; ++r) {
        int rm = m0 + g * 4 + r;
        qy15[r] = (((rm >> 5) + 0.5f) * (1.f / 16.f) - 1.f) * 15.5f;
        qx15[r] = (((rm & 31) + 0.5f) * (1.f / 16.f) - 1.f) * 15.5f;
    }
    __syncthreads();

    // ---- pass A: 8 col-tiles of 16; exp -> packed f16 pairs (ep[4][4] regs)
    float Ssum[4] = {0.f, 0.f, 0.f, 0.f};
    float eprev[4];
    unsigned ep[4][4];
    #pragma unroll
    for (int nt = 0; nt < 8; ++nt) {
        int col = wn * 128 + nt * 16 + c16;
        const short* krow = kbf + ((size_t)(b * 1024 + col) * 512 + h * 64 + g * 8);
        bf16x8 bk0 = *(const bf16x8*)krow;
        bf16x8 bk1 = *(const bf16x8*)(krow + 32);
        f32x4 acc = {0.f, 0.f, 0.f, 0.f};
        acc = __builtin_amdgcn_mfma_f32_16x16x32_bf16(aq0, bk0, acc, 0, 0, 0);
        acc = __builtin_amdgcn_mfma_f32_16x16x32_bf16(aq1, bk1, acc, 0, 0, 0);
        h2 pp = pos_s[col];
        float cyn = 32.f - (float)pp[0] * 15.5f;
        float cxn = 32.f - (float)pp[1] * 15.5f;
        #pragma unroll
        for (int r = 0; r < 4; ++r) {
            float gyp = qy15[r] + cyn;
            float gxp = qx15[r] + cxn;
            float fy = floorf(gyp), fx = floorf(gxp);
            float wy1 = gyp - fy, wx1 = gxp - fx;
            int ad = (int)fy * 65 + (int)fx;
            h2 r0 = rpe_s[ad];
            h2 r1 = rpe_s[ad + 65];
            h2 wp = pkrtz(1.f - wx1, wx1);
            float t0 = dot2(r0, wp);
            float t1 = dot2(r1, wp);
            float bias = t0 + wy1 * (t1 - t0);
            float logit = fmaf(acc[r], 0.125f, bias);
            float e = __expf(logit);
            Ssum[r] += e;
            if (nt & 1) {
                ep[r][nt >> 1] = __builtin_bit_cast(unsigned, pkrtz(eprev[r], e));
            } else {
                eprev[r] = e;
            }
        }
    }
    #pragma unroll
    for (int s = 1; s < 16; s <<= 1)
        #pragma unroll
        for (int r = 0; r < 4; ++r) Ssum[r] += __shfl_xor(Ssum[r], s);
    if (c16 == 0)
        #pragma unroll
        for (int r = 0; r < 4; ++r) S_part[g * 4 + r][wn] = Ssum[r];
    __syncthreads();   // pass-A LDS reads done; rpe/pos region dead
    float invS[4];
    #pragma unroll
    for (int r = 0; r < 4; ++r) {
        int row = g * 4 + r;
        float s = 0.f;
        #pragma unroll
        for (int w = 0; w < 8; ++w) s += S_part[row][w];
        invS[r] = 1.f / s;
    }

    // ---- normalize -> f16 into Pn[16][1032]
    #pragma unroll
    for (int r = 0; r < 4; ++r) {
        short* prow = Pn + (g * 4 + r) * 1032 + wn * 128 + c16;
        #pragma unroll
        for (int j = 0; j < 4; ++j) {
            h2 pk = __builtin_bit_cast(h2, ep[r][j]);
            h2 npk = pkrtz((float)pk[0] * invS[r], (float)pk[1] * invS[r]);
            prow[j * 32]      = __builtin_bit_cast(short, npk[0]);
            prow[j * 32 + 16] = __builtin_bit_cast(short, npk[1]);
        }
    }
    __syncthreads();

    size_t obase = ((size_t)((b * 8 + h) * 1024 + m0)) * 1024;
    if (wn >= 4) {
        // ---- attn fp32 stream from LDS: waves 4-7 = 256 threads
        int tw = t - 256;
        #pragma unroll
        for (int row = 0; row < 16; ++row) {
            const unsigned* pr = (const unsigned*)(Pn + row * 1032 + tw * 4);
            unsigned u0 = pr[0], u1 = pr[1];
            h2 a = __builtin_bit_cast(h2, u0);
            h2 bb = __builtin_bit_cast(h2, u1);
            float4 vv = make_float4((float)a[0], (float)a[1], (float)bb[0], (float)bb[1]);
            *(float4*)(attn_out + obase + (size_t)row * 1024 + tw * 4) = vv;
        }
    } else {
        // ---- PV: wave wn owns channels wn*16..+15; f16 MFMA, V from global
        const short* Vb = vhf + ((size_t)(b * 512 + h * 64 + wn * 16 + c16)) * 1024;
        const short* Prow = Pn + c16 * 1032 + g * 8;
        f32x4 dacc = {0.f, 0.f, 0.f, 0.f};
        #pragma unroll
        for (int cc = 0; cc < 32; ++cc) {
            int n0 = cc * 32;
            f16x8 pa  = *(const f16x8*)(Prow + n0);
            f16x8 vb8 = *(const f16x8*)(Vb + n0 + g * 8);
            dacc = __builtin_amdgcn_mfma_f32_16x16x32_f16(pa, vb8, dacc, 0, 0, 0);
        }
        float gm = gamma[0];
        int ch = h * 64 + wn * 16 + c16;
        int m = m0 + g * 4;
        size_t idx = ((size_t)(b * 512 + ch)) * 1024 + m;
        float4 xv = *(const float4*)(x + idx);
        float4 ov;
        ov.x = gm * dacc[0] + xv.x;
        ov.y = gm * dacc[1] + xv.y;
        ov.z = gm * dacc[2] + xv.z;
        ov.w = gm * dacc[3] + xv.w;
        *(float4*)(out0 + idx) = ov;
    }
}

extern "C" void kernel_launch(void* const* d_in, const int* in_sizes, int n_in,
                              void* d_out, int out_size, void* d_ws, size_t ws_size,
                              hipStream_t stream) {
    const float* x     = (const float*)d_in[0];
    const float* dw_w  = (const float*)d_in[1];
    const float* dw_b  = (const float*)d_in[2];
    const float* ln_w  = (const float*)d_in[3];
    const float* ln_b  = (const float*)d_in[4];
    const float* pw_w  = (const float*)d_in[5];
    const float* q_w   = (const float*)d_in[6];
    const float* q_b   = (const float*)d_in[7];
    const float* k_w   = (const float*)d_in[8];
    const float* k_b   = (const float*)d_in[9];
    const float* v_w   = (const float*)d_in[10];
    const float* v_b   = (const float*)d_in[11];
    const float* rpe   = (const float*)d_in[12];
    const float* gamma = (const float*)d_in[13];

    float* out0 = (float*)d_out;
    float* attn = out0 + (size_t)4 * 512 * 1024;

    char* w = (char*)d_ws;
    short* xt   = (short*)w;                      // 4 MB
    short* qwb  = (short*)(w + 4194304);
    short* kwb  = (short*)(w + 4718592);
    short* vwb  = (short*)(w + 5242880);
    short* qbf  = (short*)(w + 5767168);          // 4 MB
    short* xsb  = (short*)(w + 9961472);          // 4 MB
    short* kbf  = (short*)(w + 14155776);         // 4 MB
    short* vhf  = (short*)(w + 18350080);         // 4 MB (f16)
    float* pos  = (float*)(w + 22544384);         // 32 KB

    prep_x<<<dim3(16, 8, 4), 256, 0, stream>>>(x, xt);
    wcast<<<384, 256, 0, stream>>>(q_w, k_w, v_w, qwb, kwb, vwb);
    gemm_q<<<dim3(32, 4), 256, 0, stream>>>(xt, qwb, q_b, qbf);
    offset_kernel<<<4096, 256, 0, stream>>>(qbf, dw_w, dw_b, ln_w, ln_b, pw_w, pos);
    sample_k<<<4096, 256, 0, stream>>>(xt, pos, xsb);
    gemm_kv<<<256, 256, 0, stream>>>(xsb, kwb, k_b, kbf, vwb, v_b, vhf);
    attn_fused<<<dim3(64, 8, 4), 512, 0, stream>>>(qbf, kbf, vhf, pos, rpe, x,
                                                   gamma, attn, out0);
}

// Round 8
// 146.566 us; speedup vs baseline: 3.0102x; 1.0145x over previous
//
#include <hip/hip_runtime.h>
#include <hip/hip_bf16.h>
#include <math.h>

typedef short bf16x8 __attribute__((ext_vector_type(8)));
typedef _Float16 f16x8 __attribute__((ext_vector_type(8)));
typedef float f32x4 __attribute__((ext_vector_type(4)));
typedef _Float16 h2 __attribute__((ext_vector_type(2)));

__device__ inline short f2bf(float f) {
    union { float f; unsigned u; } v; v.f = f;
    unsigned r = v.u + 0x7FFFu + ((v.u >> 16) & 1u);
    return (short)(r >> 16);
}
__device__ inline float bf2f(short s) {
    union { unsigned u; float f; } v; v.u = ((unsigned)(unsigned short)s) << 16;
    return v.f;
}
__device__ inline h2 pkrtz(float a, float b) {
    return __builtin_bit_cast(h2, __builtin_amdgcn_cvt_pkrtz(a, b));
}
__device__ inline float dot2(h2 a, h2 b) {
#if __has_builtin(__builtin_amdgcn_fdot2)
    return __builtin_amdgcn_fdot2(a, b, 0.f, false);
#else
    return (float)a[0] * (float)b[0] + (float)a[1] * (float)b[1];
#endif
}

// ---------------------------------------------------------------------------
// transpose-cast: x [b][c][p] f32 -> xt [b][p][c] bf16
// ---------------------------------------------------------------------------
__global__ __launch_bounds__(256) void prep_x(const float* __restrict__ x,
                                              short* __restrict__ xt)
{
    __shared__ float ts[64][65];
    int p0 = blockIdx.x * 64, c0 = blockIdx.y * 64, b = blockIdx.z;
    int t = threadIdx.x;
    #pragma unroll
    for (int i = 0; i < 16; ++i) {
        int idx = i * 256 + t;
        int cl = idx >> 6, pl = idx & 63;
        ts[cl][pl] = x[((size_t)(b * 512 + c0 + cl)) * 1024 + p0 + pl];
    }
    __syncthreads();
    #pragma unroll
    for (int i = 0; i < 16; ++i) {
        int idx = i * 256 + t;
        int pl = idx >> 6, cl = idx & 63;
        xt[((size_t)(b * 1024 + p0 + pl)) * 512 + c0 + cl] = f2bf(ts[cl][pl]);
    }
}

// cast 3 weight matrices [512][512] f32 -> bf16
__global__ __launch_bounds__(256) void wcast(
    const float* __restrict__ qw, const float* __restrict__ kw,
    const float* __restrict__ vw, short* __restrict__ qwb,
    short* __restrict__ kwb, short* __restrict__ vwb)
{
    int idx = (blockIdx.x * 256 + threadIdx.x) * 8;
    int w = idx >> 18;
    int off = idx & 262143;
    const float* src = (w == 0) ? qw : (w == 1) ? kw : vw;
    short* dst = (w == 0) ? qwb : (w == 1) ? kwb : vwb;
    float4 f0 = *(const float4*)(src + off);
    float4 f1 = *(const float4*)(src + off + 4);
    bf16x8 o;
    o[0] = f2bf(f0.x); o[1] = f2bf(f0.y); o[2] = f2bf(f0.z); o[3] = f2bf(f0.w);
    o[4] = f2bf(f1.x); o[5] = f2bf(f1.y); o[6] = f2bf(f1.z); o[7] = f2bf(f1.w);
    *(bf16x8*)(dst + off) = o;
}

// ---------------------------------------------------------------------------
// 128x128 NT MFMA tile body (K=512): acc[4][4] per thread.
// ---------------------------------------------------------------------------
__device__ inline void nt_tile_128(const short* __restrict__ A,
                                   const short* __restrict__ B,
                                   int m0, int n0, int t,
                                   short (*As)[32], short (*Bs)[32],
                                   f32x4 (&acc)[4][4])
{
    int wid = t >> 6, l = t & 63;
    int wm = wid >> 1, wn = wid & 1;
    int srow = t >> 1, half = t & 1;
    int sw = (srow >> 1) & 3;
    int s0 = (half * 2) ^ sw, s1 = (half * 2 + 1) ^ sw;
    for (int k0 = 0; k0 < 512; k0 += 32) {
        const int4 a0 = *(const int4*)(A + (size_t)(m0 + srow) * 512 + k0 + half * 16);
        const int4 a1 = *(const int4*)(A + (size_t)(m0 + srow) * 512 + k0 + half * 16 + 8);
        const int4 b0 = *(const int4*)(B + (size_t)(n0 + srow) * 512 + k0 + half * 16);
        const int4 b1 = *(const int4*)(B + (size_t)(n0 + srow) * 512 + k0 + half * 16 + 8);
        __syncthreads();
        *(int4*)&As[srow][s0 * 8] = a0;
        *(int4*)&As[srow][s1 * 8] = a1;
        *(int4*)&Bs[srow][s0 * 8] = b0;
        *(int4*)&Bs[srow][s1 * 8] = b1;
        __syncthreads();
        bf16x8 af[4], bfr[4];
        #pragma unroll
        for (int mt = 0; mt < 4; ++mt) {
            int r = wm * 64 + mt * 16 + (l & 15);
            af[mt] = *(const bf16x8*)&As[r][(((l >> 4)) ^ ((r >> 1) & 3)) * 8];
        }
        #pragma unroll
        for (int nt = 0; nt < 4; ++nt) {
            int r = wn * 64 + nt * 16 + (l & 15);
            bfr[nt] = *(const bf16x8*)&Bs[r][(((l >> 4)) ^ ((r >> 1) & 3)) * 8];
        }
        #pragma unroll
        for (int mt = 0; mt < 4; ++mt)
            #pragma unroll
            for (int nt = 0; nt < 4; ++nt)
                acc[mt][nt] = __builtin_amdgcn_mfma_f32_16x16x32_bf16(
                    af[mt], bfr[nt], acc[mt][nt], 0, 0, 0);
    }
}

// q projection: D[m][n] = xt[m][:]·qwb[n][:] + q_b[n] -> bf16 [m*512+n]
__global__ __launch_bounds__(256) void gemm_q(
    const short* __restrict__ A, const short* __restrict__ B,
    const float* __restrict__ bias, short* __restrict__ Ob)
{
    __shared__ short As[128][32];
    __shared__ short Bs[128][32];
    int m0 = blockIdx.x * 128, n0 = blockIdx.y * 128;
    int t = threadIdx.x, wid = t >> 6, l = t & 63;
    int wm = wid >> 1, wn = wid & 1;
    f32x4 acc[4][4] = {};
    nt_tile_128(A, B, m0, n0, t, As, Bs, acc);
    #pragma unroll
    for (int mt = 0; mt < 4; ++mt)
        #pragma unroll
        for (int nt = 0; nt < 4; ++nt)
            #pragma unroll
            for (int r = 0; r < 4; ++r) {
                int m = m0 + wm * 64 + mt * 16 + (l >> 4) * 4 + r;
                int n = n0 + wn * 64 + nt * 16 + (l & 15);
                Ob[(size_t)m * 512 + n] = f2bf(acc[mt][nt][r] + bias[n]);
            }
}

// k-gemm (bid<128, bf16 out) + v-gemm (bid>=128, f16 out) in ONE launch
__global__ __launch_bounds__(256) void gemm_kv(
    const short* __restrict__ xsb, const short* __restrict__ kwb,
    const float* __restrict__ k_b, short* __restrict__ kbf,
    const short* __restrict__ vwb, const float* __restrict__ v_b,
    short* __restrict__ vhf)
{
    __shared__ short As[128][32];
    __shared__ short Bs[128][32];
    int bid = blockIdx.x;
    int t = threadIdx.x, wid = t >> 6, l = t & 63;
    int wm = wid >> 1, wn = wid & 1;
    f32x4 acc[4][4] = {};
    if (bid < 128) {
        int m0 = (bid >> 2) * 128, n0 = (bid & 3) * 128;
        nt_tile_128(xsb, kwb, m0, n0, t, As, Bs, acc);
        #pragma unroll
        for (int mt = 0; mt < 4; ++mt)
            #pragma unroll
            for (int nt = 0; nt < 4; ++nt)
                #pragma unroll
                for (int r = 0; r < 4; ++r) {
                    int m = m0 + wm * 64 + mt * 16 + (l >> 4) * 4 + r;
                    int n = n0 + wn * 64 + nt * 16 + (l & 15);
                    kbf[(size_t)m * 512 + n] = f2bf(acc[mt][nt][r] + k_b[n]);
                }
    } else {
        int id2 = bid - 128;
        int z = id2 >> 5, rr = id2 & 31;
        int m0 = (rr >> 3) * 128, n0 = (rr & 7) * 128;
        nt_tile_128(vwb, xsb + (size_t)z * 524288, m0, n0, t, As, Bs, acc);
        #pragma unroll
        for (int mt = 0; mt < 4; ++mt)
            #pragma unroll
            for (int nt = 0; nt < 4; ++nt)
                #pragma unroll
                for (int r = 0; r < 4; ++r) {
                    int m = m0 + wm * 64 + mt * 16 + (l >> 4) * 4 + r;
                    int n = n0 + wn * 64 + nt * 16 + (l & 15);
                    _Float16 hv = (_Float16)(acc[mt][nt][r] + v_b[m]);
                    vhf[((size_t)z * 512 + m) * 1024 + n] = __builtin_bit_cast(short, hv);
                }
    }
}

// ---------------------------------------------------------------------------
// offset network (reads q bf16 in [b][p][c] layout) -> pos[b][p][2] (y,x)
// ---------------------------------------------------------------------------
__global__ __launch_bounds__(256) void offset_kernel(
    const short* __restrict__ qbf, const float* __restrict__ dw_w,
    const float* __restrict__ dw_b, const float* __restrict__ ln_w,
    const float* __restrict__ ln_b, const float* __restrict__ pw_w,
    float* __restrict__ pos)
{
    __shared__ float red[8];
    int bid = blockIdx.x;
    int b = bid >> 10, p = bid & 1023;
    int y = p >> 5, x = p & 31;
    int t = threadIdx.x;
    int c0 = 2 * t;
    const short* qb = qbf + (size_t)b * 524288;
    float h0, h1;
    {
        const float* w0 = dw_w + c0 * 9;
        const float* w1 = w0 + 9;
        float s0 = 0.f, s1 = 0.f;
        #pragma unroll
        for (int ky = 0; ky < 3; ++ky) {
            int yy = y + ky - 1;
            if (yy < 0 || yy > 31) continue;
            #pragma unroll
            for (int kx = 0; kx < 3; ++kx) {
                int xx = x + kx - 1;
                if (xx < 0 || xx > 31) continue;
                unsigned u = *(const unsigned*)(qb + (size_t)(yy * 32 + xx) * 512 + c0);
                s0 += bf2f((short)(u & 0xFFFF)) * w0[ky * 3 + kx];
                s1 += bf2f((short)(u >> 16)) * w1[ky * 3 + kx];
            }
        }
        float2 db = *(const float2*)(dw_b + c0);
        h0 = s0 + db.x; h1 = s1 + db.y;
    }
    float ls = h0 + h1;
    float lq = h0 * h0 + h1 * h1;
    #pragma unroll
    for (int s = 32; s >= 1; s >>= 1) {
        ls += __shfl_xor(ls, s);
        lq += __shfl_xor(lq, s);
    }
    int wid = t >> 6, lane = t & 63;
    if (lane == 0) { red[wid] = ls; red[4 + wid] = lq; }
    __syncthreads();
    float mu  = (red[0] + red[1] + red[2] + red[3]) * (1.f / 512.f);
    float var = (red[4] + red[5] + red[6] + red[7]) * (1.f / 512.f) - mu * mu;
    float rstd = rsqrtf(var + 1e-5f);
    float o0, o1;
    {
        float2 lw = *(const float2*)(ln_w + c0);
        float2 lb = *(const float2*)(ln_b + c0);
        float2 p0 = *(const float2*)(pw_w + c0);
        float2 p1 = *(const float2*)(pw_w + 512 + c0);
        float hn0 = (h0 - mu) * rstd * lw.x + lb.x;
        float hn1 = (h1 - mu) * rstd * lw.y + lb.y;
        float g0 = 0.5f * hn0 * (1.f + erff(hn0 * 0.70710678118f));
        float g1 = 0.5f * hn1 * (1.f + erff(hn1 * 0.70710678118f));
        o0 = g0 * p0.x + g1 * p0.y;
        o1 = g0 * p1.x + g1 * p1.y;
    }
    #pragma unroll
    for (int s = 32; s >= 1; s >>= 1) {
        o0 += __shfl_xor(o0, s);
        o1 += __shfl_xor(o1, s);
    }
    __syncthreads();
    if (lane == 0) { red[wid] = o0; red[4 + wid] = o1; }
    __syncthreads();
    if (t == 0) {
        float oy = tanhf(red[0] + red[1] + red[2] + red[3]) * 0.0625f;
        float ox = tanhf(red[4] + red[5] + red[6] + red[7]) * 0.0625f;
        float ry = ((y + 0.5f) * (1.f / 32.f)) * 2.f - 1.f;
        float rx = ((x + 0.5f) * (1.f / 32.f)) * 2.f - 1.f;
        pos[bid * 2]     = oy + ry;
        pos[bid * 2 + 1] = ox + rx;
    }
}

// ---------------------------------------------------------------------------
// bilinear sample of xt (bf16 [b][p][c]) at pos -> xs bf16 [b][p][c]
// ---------------------------------------------------------------------------
__global__ __launch_bounds__(256) void sample_k(
    const short* __restrict__ xt, const float* __restrict__ pos,
    short* __restrict__ xs)
{
    int bid = blockIdx.x;
    int b = bid >> 10;
    float py = pos[bid * 2], px = pos[bid * 2 + 1];
    float gx = (px + 1.f) * 15.5f;
    float gy = (py + 1.f) * 15.5f;
    float x0f = floorf(gx), y0f = floorf(gy);
    int ix0 = (int)x0f, iy0 = (int)y0f;
    float wx1 = gx - x0f, wx0 = 1.f - wx1;
    float wy1 = gy - y0f, wy0 = 1.f - wy1;
    const short* base = xt + (size_t)b * 524288;
    int t = threadIdx.x;
    float a0 = 0.f, a1 = 0.f;
    #pragma unroll
    for (int tap = 0; tap < 4; ++tap) {
        int ix = ix0 + (tap & 1), iy = iy0 + (tap >> 1);
        float w = ((tap & 1) ? wx1 : wx0) * ((tap >> 1) ? wy1 : wy0);
        if (ix >= 0 && ix < 32 && iy >= 0 && iy < 32) {
            unsigned u = *(const unsigned*)(base + (size_t)(iy * 32 + ix) * 512 + 2 * t);
            a0 += bf2f((short)(u & 0xFFFF)) * w;
            a1 += bf2f((short)(u >> 16)) * w;
        }
    }
    unsigned o = ((unsigned)(unsigned short)f2bf(a0)) |
                 (((unsigned)(unsigned short)f2bf(a1)) << 16);
    *(unsigned*)(xs + (size_t)bid * 512 + 2 * t) = o;
}

// ---------------------------------------------------------------------------
// FUSED attention, 512 threads (8 waves), SWAPPED QK^T:
// mfma(K_frag, Q_frag) -> D[row=n][col=m]: lane owns ONE m (=c16), 4 n per
// tile. RPE gathers are lane-coherent (consecutive table addresses, fy
// constant per group) -> conflict-free; pos reads broadcast; softmax reduce
// = 2 shfl_xor; Pn written as packed b64. pos staged f32 (precision).
// After softmax: waves 0-3 PV (f16 MFMA) + gamma*D+x; waves 4-7 stream attn.
// grid (64 m-tiles, 8 h, 4 b)
// ---------------------------------------------------------------------------
__global__ __launch_bounds__(512, 4) void attn_fused(
    const short* __restrict__ qbf, const short* __restrict__ kbf,
    const short* __restrict__ vhf, const float* __restrict__ pos,
    const float* __restrict__ rpe, const float* __restrict__ x,
    const float* __restrict__ gamma, float* __restrict__ attn_out,
    float* __restrict__ out0)
{
    __shared__ __align__(16) char smem_raw[33024];   // rpe(16900)+posf32(8192) | Pn 16*1032*2
    __shared__ float S_part[16][8];
    h2*     rpe_s  = (h2*)smem_raw;                   // [65*65] padded pair table
    float2* pos_sf = (float2*)(smem_raw + 16960);     // [1024] (y,x) f32
    short*  Pn     = (short*)smem_raw;                // [16][1032] f16 normalized P

    int m0 = blockIdx.x * 16, h = blockIdx.y, b = blockIdx.z;
    int t = threadIdx.x, wn = t >> 6, l = t & 63;
    int g = l >> 4, c16 = l & 15;

    // ---- padded pair table: entry (iy+1, ix+1) = (v[iy][ix], v[iy][ix+1])
    #pragma unroll
    for (int i = 0; i < 9; ++i) {
        int e = i * 512 + t;
        if (e < 4225) rpe_s[e] = (h2)((_Float16)0.f);
    }
    __syncthreads();
    const float* rh = rpe + h * 3969;
    #pragma unroll
    for (int i = 0; i < 8; ++i) {
        int e = i * 512 + t;
        if (e < 3969) {
            int iy = (int)(((unsigned)e * 16645u) >> 20);   // e/63 exact for e<3969
            int ix = e - iy * 63;
            float v0 = rh[e];
            float v1 = (ix < 62) ? rh[e + 1] : 0.f;
            h2 pr; pr[0] = (_Float16)v0; pr[1] = (_Float16)v1;
            rpe_s[(iy + 1) * 65 + ix + 1] = pr;
        }
    }
    if (t < 63) {  // left border column: (0, v[iy][0])
        h2 pr; pr[0] = (_Float16)0.f; pr[1] = (_Float16)rh[t * 63];
        rpe_s[(t + 1) * 65] = pr;
    }
    #pragma unroll
    for (int i = 0; i < 2; ++i) {
        int idx = i * 512 + t;
        pos_sf[idx] = *(const float2*)(pos + b * 2048 + idx * 2);
    }
    // q fragments: B-operand of swapped mfma; lane's m = m0 + c16
    int rowm = m0 + c16;
    const short* qrow = qbf + ((size_t)(b * 1024 + rowm) * 512 + h * 64 + g * 8);
    bf16x8 aq0 = *(const bf16x8*)qrow;
    bf16x8 aq1 = *(const bf16x8*)(qrow + 32);
    float qy = (((rowm >> 5) + 0.5f) * (1.f / 16.f) - 1.f) * 15.5f;
    float qx = (((rowm & 31) + 0.5f) * (1.f / 16.f) - 1.f) * 15.5f;
    __syncthreads();

    // ---- pass A: 8 n-tiles of 16; lane computes 4 n's for its m
    float Ssum = 0.f;
    float e0, e1;
    unsigned ep[16];
    #pragma unroll
    for (int nt = 0; nt < 8; ++nt) {
        int nb = wn * 128 + nt * 16;
        const short* krow = kbf + ((size_t)(b * 1024 + nb + c16) * 512 + h * 64 + g * 8);
        bf16x8 bk0 = *(const bf16x8*)krow;
        bf16x8 bk1 = *(const bf16x8*)(krow + 32);
        f32x4 acc = {0.f, 0.f, 0.f, 0.f};
        acc = __builtin_amdgcn_mfma_f32_16x16x32_bf16(bk0, aq0, acc, 0, 0, 0);
        acc = __builtin_amdgcn_mfma_f32_16x16x32_bf16(bk1, aq1, acc, 0, 0, 0);
        #pragma unroll
        for (int r = 0; r < 4; ++r) {
            float2 pp = pos_sf[nb + g * 4 + r];        // broadcast across c16
            float gyp = qy + (32.f - pp.x * 15.5f);
            float gxp = qx + (32.f - pp.y * 15.5f);
            float fy = floorf(gyp), fx = floorf(gxp);
            float wy1 = gyp - fy, wx1 = gxp - fx;
            int ad = (int)(fy * 65.f + fx);
            h2 r0 = rpe_s[ad];                          // lane-coherent: consecutive
            h2 r1 = rpe_s[ad + 65];
            h2 wp = pkrtz(1.f - wx1, wx1);
            float t0 = dot2(r0, wp);
            float t1 = dot2(r1, wp);
            float bias = t0 + wy1 * (t1 - t0);
            float logit = fmaf(acc[r], 0.125f, bias);
            float e = __expf(logit);
            Ssum += e;
            if (r == 0) e0 = e;
            else if (r == 1) ep[nt * 2] = __builtin_bit_cast(unsigned, pkrtz(e0, e));
            else if (r == 2) e1 = e;
            else ep[nt * 2 + 1] = __builtin_bit_cast(unsigned, pkrtz(e1, e));
        }
    }
    // reduce over g (lanes sharing m=c16), then across waves
    Ssum += __shfl_xor(Ssum, 16);
    Ssum += __shfl_xor(Ssum, 32);
    if (l < 16) S_part[c16][wn] = Ssum;
    __syncthreads();   // pass-A LDS reads done; rpe/pos region dead
    float4 sa = *(const float4*)&S_part[c16][0];
    float4 sb = *(const float4*)&S_part[c16][4];
    float invS = 1.f / (sa.x + sa.y + sa.z + sa.w + sb.x + sb.y + sb.z + sb.w);

    // ---- normalize -> f16, packed b64 writes into Pn[m=c16][n]
    short* prow = Pn + c16 * 1032 + wn * 128;
    #pragma unroll
    for (int nt = 0; nt < 8; ++nt) {
        h2 a  = __builtin_bit_cast(h2, ep[nt * 2]);
        h2 b2 = __builtin_bit_cast(h2, ep[nt * 2 + 1]);
        h2 na  = pkrtz((float)a[0] * invS, (float)a[1] * invS);
        h2 nb2 = pkrtz((float)b2[0] * invS, (float)b2[1] * invS);
        uint2 w;
        w.x = __builtin_bit_cast(unsigned, na);
        w.y = __builtin_bit_cast(unsigned, nb2);
        *(uint2*)(prow + nt * 16 + g * 4) = w;
    }
    __syncthreads();

    size_t obase = ((size_t)((b * 8 + h) * 1024 + m0)) * 1024;
    if (wn >= 4) {
        // ---- attn fp32 stream from LDS: waves 4-7 = 256 threads
        int tw = t - 256;
        #pragma unroll
        for (int row = 0; row < 16; ++row) {
            const unsigned* pr = (const unsigned*)(Pn + row * 1032 + tw * 4);
            unsigned u0 = pr[0], u1 = pr[1];
            h2 a = __builtin_bit_cast(h2, u0);
            h2 bb = __builtin_bit_cast(h2, u1);
            float4 vv = make_float4((float)a[0], (float)a[1], (float)bb[0], (float)bb[1]);
            *(float4*)(attn_out + obase + (size_t)row * 1024 + tw * 4) = vv;
        }
    } else {
        // ---- PV: wave wn owns channels wn*16..+15; f16 MFMA, V from global
        const short* Vb = vhf + ((size_t)(b * 512 + h * 64 + wn * 16 + c16)) * 1024;
        const short* Prow = Pn + c16 * 1032 + g * 8;
        f32x4 dacc = {0.f, 0.f, 0.f, 0.f};
        #pragma unroll
        for (int cc = 0; cc < 32; ++cc) {
            int n0 = cc * 32;
            f16x8 pa  = *(const f16x8*)(Prow + n0);
            f16x8 vb8 = *(const f16x8*)(Vb + n0 + g * 8);
            dacc = __builtin_amdgcn_mfma_f32_16x16x32_f16(pa, vb8, dacc, 0, 0, 0);
        }
        float gm = gamma[0];
        int ch = h * 64 + wn * 16 + c16;
        int m = m0 + g * 4;
        size_t idx = ((size_t)(b * 512 + ch)) * 1024 + m;
        float4 xv = *(const float4*)(x + idx);
        float4 ov;
        ov.x = gm * dacc[0] + xv.x;
        ov.y = gm * dacc[1] + xv.y;
        ov.z = gm * dacc[2] + xv.z;
        ov.w = gm * dacc[3] + xv.w;
        *(float4*)(out0 + idx) = ov;
    }
}

extern "C" void kernel_launch(void* const* d_in, const int* in_sizes, int n_in,
                              void* d_out, int out_size, void* d_ws, size_t ws_size,
                              hipStream_t stream) {
    const float* x     = (const float*)d_in[0];
    const float* dw_w  = (const float*)d_in[1];
    const float* dw_b  = (const float*)d_in[2];
    const float* ln_w  = (const float*)d_in[3];
    const float* ln_b  = (const float*)d_in[4];
    const float* pw_w  = (const float*)d_in[5];
    const float* q_w   = (const float*)d_in[6];
    const float* q_b   = (const float*)d_in[7];
    const float* k_w   = (const float*)d_in[8];
    const float* k_b   = (const float*)d_in[9];
    const float* v_w   = (const float*)d_in[10];
    const float* v_b   = (const float*)d_in[11];
    const float* rpe   = (const float*)d_in[12];
    const float* gamma = (const float*)d_in[13];

    float* out0 = (float*)d_out;
    float* attn = out0 + (size_t)4 * 512 * 1024;

    char* w = (char*)d_ws;
    short* xt   = (short*)w;                      // 4 MB
    short* qwb  = (short*)(w + 4194304);
    short* kwb  = (short*)(w + 4718592);
    short* vwb  = (short*)(w + 5242880);
    short* qbf  = (short*)(w + 5767168);          // 4 MB
    short* xsb  = (short*)(w + 9961472);          // 4 MB
    short* kbf  = (short*)(w + 14155776);         // 4 MB
    short* vhf  = (short*)(w + 18350080);         // 4 MB (f16)
    float* pos  = (float*)(w + 22544384);         // 32 KB

    prep_x<<<dim3(16, 8, 4), 256, 0, stream>>>(x, xt);
    wcast<<<384, 256, 0, stream>>>(q_w, k_w, v_w, qwb, kwb, vwb);
    gemm_q<<<dim3(32, 4), 256, 0, stream>>>(xt, qwb, q_b, qbf);
    offset_kernel<<<4096, 256, 0, stream>>>(qbf, dw_w, dw_b, ln_w, ln_b, pw_w, pos);
    sample_k<<<4096, 256, 0, stream>>>(xt, pos, xsb);
    gemm_kv<<<256, 256, 0, stream>>>(xsb, kwb, k_b, kbf, vwb, v_b, vhf);
    attn_fused<<<dim3(64, 8, 4), 512, 0, stream>>>(qbf, kbf, vhf, pos, rpe, x,
                                                   gamma, attn, out0);
}

// Round 9
// 145.783 us; speedup vs baseline: 3.0263x; 1.0054x over previous
//
#include <hip/hip_runtime.h>
#include <hip/hip_bf16.h>
#include <math.h>

typedef short bf16x8 __attribute__((ext_vector_type(8)));
typedef _Float16 f16x8 __attribute__((ext_vector_type(8)));
typedef float f32x4 __attribute__((ext_vector_type(4)));
typedef _Float16 h2 __attribute__((ext_vector_type(2)));

__device__ inline short f2bf(float f) {
    union { float f; unsigned u; } v; v.f = f;
    unsigned r = v.u + 0x7FFFu + ((v.u >> 16) & 1u);
    return (short)(r >> 16);
}
__device__ inline float bf2f(short s) {
    union { unsigned u; float f; } v; v.u = ((unsigned)(unsigned short)s) << 16;
    return v.f;
}
__device__ inline h2 pkrtz(float a, float b) {
    return __builtin_bit_cast(h2, __builtin_amdgcn_cvt_pkrtz(a, b));
}
__device__ inline float fast_exp2(float x) {
    float r;
    asm("v_exp_f32 %0, %1" : "=v"(r) : "v"(x));
    return r;
}
__device__ inline float dot2(h2 a, h2 b) {
#if __has_builtin(__builtin_amdgcn_fdot2)
    return __builtin_amdgcn_fdot2(a, b, 0.f, false);
#else
    return (float)a[0] * (float)b[0] + (float)a[1] * (float)b[1];
#endif
}

// ---------------------------------------------------------------------------
// transpose-cast x [b][c][p] f32 -> xt [b][p][c] bf16 (z<4); z==4: wcast
// ---------------------------------------------------------------------------
__global__ __launch_bounds__(256) void prep_x(
    const float* __restrict__ x, short* __restrict__ xt,
    const float* __restrict__ qw, const float* __restrict__ kw,
    const float* __restrict__ vw, short* __restrict__ qwb,
    short* __restrict__ kwb, short* __restrict__ vwb)
{
    __shared__ float ts[64][65];
    int t = threadIdx.x;
    if (blockIdx.z == 4) {   // weight cast plane: 128 blocks x 3 matrices
        int f = blockIdx.y * 16 + blockIdx.x;
        int base = (f * 256 + t) * 8;
        #pragma unroll
        for (int w = 0; w < 3; ++w) {
            const float* src = (w == 0) ? qw : (w == 1) ? kw : vw;
            short* dst = (w == 0) ? qwb : (w == 1) ? kwb : vwb;
            float4 f0 = *(const float4*)(src + base);
            float4 f1 = *(const float4*)(src + base + 4);
            bf16x8 o;
            o[0] = f2bf(f0.x); o[1] = f2bf(f0.y); o[2] = f2bf(f0.z); o[3] = f2bf(f0.w);
            o[4] = f2bf(f1.x); o[5] = f2bf(f1.y); o[6] = f2bf(f1.z); o[7] = f2bf(f1.w);
            *(bf16x8*)(dst + base) = o;
        }
        return;
    }
    int p0 = blockIdx.x * 64, c0 = blockIdx.y * 64, b = blockIdx.z;
    #pragma unroll
    for (int i = 0; i < 16; ++i) {
        int idx = i * 256 + t;
        int cl = idx >> 6, pl = idx & 63;
        ts[cl][pl] = x[((size_t)(b * 512 + c0 + cl)) * 1024 + p0 + pl];
    }
    __syncthreads();
    #pragma unroll
    for (int i = 0; i < 16; ++i) {
        int idx = i * 256 + t;
        int pl = idx >> 6, cl = idx & 63;
        xt[((size_t)(b * 1024 + p0 + pl)) * 512 + c0 + cl] = f2bf(ts[cl][pl]);
    }
}

// ---------------------------------------------------------------------------
// 128x128 NT MFMA tile body (K=512): acc[4][4] per thread.
// ---------------------------------------------------------------------------
__device__ inline void nt_tile_128(const short* __restrict__ A,
                                   const short* __restrict__ B,
                                   int m0, int n0, int t,
                                   short (*As)[32], short (*Bs)[32],
                                   f32x4 (&acc)[4][4])
{
    int wid = t >> 6, l = t & 63;
    int wm = wid >> 1, wn = wid & 1;
    int srow = t >> 1, half = t & 1;
    int sw = (srow >> 1) & 3;
    int s0 = (half * 2) ^ sw, s1 = (half * 2 + 1) ^ sw;
    for (int k0 = 0; k0 < 512; k0 += 32) {
        const int4 a0 = *(const int4*)(A + (size_t)(m0 + srow) * 512 + k0 + half * 16);
        const int4 a1 = *(const int4*)(A + (size_t)(m0 + srow) * 512 + k0 + half * 16 + 8);
        const int4 b0 = *(const int4*)(B + (size_t)(n0 + srow) * 512 + k0 + half * 16);
        const int4 b1 = *(const int4*)(B + (size_t)(n0 + srow) * 512 + k0 + half * 16 + 8);
        __syncthreads();
        *(int4*)&As[srow][s0 * 8] = a0;
        *(int4*)&As[srow][s1 * 8] = a1;
        *(int4*)&Bs[srow][s0 * 8] = b0;
        *(int4*)&Bs[srow][s1 * 8] = b1;
        __syncthreads();
        bf16x8 af[4], bfr[4];
        #pragma unroll
        for (int mt = 0; mt < 4; ++mt) {
            int r = wm * 64 + mt * 16 + (l & 15);
            af[mt] = *(const bf16x8*)&As[r][(((l >> 4)) ^ ((r >> 1) & 3)) * 8];
        }
        #pragma unroll
        for (int nt = 0; nt < 4; ++nt) {
            int r = wn * 64 + nt * 16 + (l & 15);
            bfr[nt] = *(const bf16x8*)&Bs[r][(((l >> 4)) ^ ((r >> 1) & 3)) * 8];
        }
        #pragma unroll
        for (int mt = 0; mt < 4; ++mt)
            #pragma unroll
            for (int nt = 0; nt < 4; ++nt)
                acc[mt][nt] = __builtin_amdgcn_mfma_f32_16x16x32_bf16(
                    af[mt], bfr[nt], acc[mt][nt], 0, 0, 0);
    }
}

// q projection
__global__ __launch_bounds__(256) void gemm_q(
    const short* __restrict__ A, const short* __restrict__ B,
    const float* __restrict__ bias, short* __restrict__ Ob)
{
    __shared__ short As[128][32];
    __shared__ short Bs[128][32];
    int m0 = blockIdx.x * 128, n0 = blockIdx.y * 128;
    int t = threadIdx.x, wid = t >> 6, l = t & 63;
    int wm = wid >> 1, wn = wid & 1;
    f32x4 acc[4][4] = {};
    nt_tile_128(A, B, m0, n0, t, As, Bs, acc);
    #pragma unroll
    for (int mt = 0; mt < 4; ++mt)
        #pragma unroll
        for (int nt = 0; nt < 4; ++nt)
            #pragma unroll
            for (int r = 0; r < 4; ++r) {
                int m = m0 + wm * 64 + mt * 16 + (l >> 4) * 4 + r;
                int n = n0 + wn * 64 + nt * 16 + (l & 15);
                Ob[(size_t)m * 512 + n] = f2bf(acc[mt][nt][r] + bias[n]);
            }
}

// k-gemm (bid<128, bf16 out) + v-gemm (bid>=128, f16 out)
__global__ __launch_bounds__(256) void gemm_kv(
    const short* __restrict__ xsb, const short* __restrict__ kwb,
    const float* __restrict__ k_b, short* __restrict__ kbf,
    const short* __restrict__ vwb, const float* __restrict__ v_b,
    short* __restrict__ vhf)
{
    __shared__ short As[128][32];
    __shared__ short Bs[128][32];
    int bid = blockIdx.x;
    int t = threadIdx.x, wid = t >> 6, l = t & 63;
    int wm = wid >> 1, wn = wid & 1;
    f32x4 acc[4][4] = {};
    if (bid < 128) {
        int m0 = (bid >> 2) * 128, n0 = (bid & 3) * 128;
        nt_tile_128(xsb, kwb, m0, n0, t, As, Bs, acc);
        #pragma unroll
        for (int mt = 0; mt < 4; ++mt)
            #pragma unroll
            for (int nt = 0; nt < 4; ++nt)
                #pragma unroll
                for (int r = 0; r < 4; ++r) {
                    int m = m0 + wm * 64 + mt * 16 + (l >> 4) * 4 + r;
                    int n = n0 + wn * 64 + nt * 16 + (l & 15);
                    kbf[(size_t)m * 512 + n] = f2bf(acc[mt][nt][r] + k_b[n]);
                }
    } else {
        int id2 = bid - 128;
        int z = id2 >> 5, rr = id2 & 31;
        int m0 = (rr >> 3) * 128, n0 = (rr & 7) * 128;
        nt_tile_128(vwb, xsb + (size_t)z * 524288, m0, n0, t, As, Bs, acc);
        #pragma unroll
        for (int mt = 0; mt < 4; ++mt)
            #pragma unroll
            for (int nt = 0; nt < 4; ++nt)
                #pragma unroll
                for (int r = 0; r < 4; ++r) {
                    int m = m0 + wm * 64 + mt * 16 + (l >> 4) * 4 + r;
                    int n = n0 + wn * 64 + nt * 16 + (l & 15);
                    _Float16 hv = (_Float16)(acc[mt][nt][r] + v_b[m]);
                    vhf[((size_t)z * 512 + m) * 1024 + n] = __builtin_bit_cast(short, hv);
                }
    }
}

// ---------------------------------------------------------------------------
// FUSED offset network + deformable sampling: pos computed per (b,p), then
// block samples xt at pos -> xs. pos also written to global for attn.
// ---------------------------------------------------------------------------
__global__ __launch_bounds__(256) void offset_sample(
    const short* __restrict__ qbf, const float* __restrict__ dw_w,
    const float* __restrict__ dw_b, const float* __restrict__ ln_w,
    const float* __restrict__ ln_b, const float* __restrict__ pw_w,
    const short* __restrict__ xt, float* __restrict__ pos,
    short* __restrict__ xs)
{
    __shared__ float red[8];
    __shared__ float2 psh;
    int bid = blockIdx.x;
    int b = bid >> 10, p = bid & 1023;
    int y = p >> 5, x = p & 31;
    int t = threadIdx.x;
    int c0 = 2 * t;
    const short* qb = qbf + (size_t)b * 524288;
    float h0, h1;
    {
        const float* w0 = dw_w + c0 * 9;
        const float* w1 = w0 + 9;
        float s0 = 0.f, s1 = 0.f;
        #pragma unroll
        for (int ky = 0; ky < 3; ++ky) {
            int yy = y + ky - 1;
            if (yy < 0 || yy > 31) continue;
            #pragma unroll
            for (int kx = 0; kx < 3; ++kx) {
                int xx = x + kx - 1;
                if (xx < 0 || xx > 31) continue;
                unsigned u = *(const unsigned*)(qb + (size_t)(yy * 32 + xx) * 512 + c0);
                s0 += bf2f((short)(u & 0xFFFF)) * w0[ky * 3 + kx];
                s1 += bf2f((short)(u >> 16)) * w1[ky * 3 + kx];
            }
        }
        float2 db = *(const float2*)(dw_b + c0);
        h0 = s0 + db.x; h1 = s1 + db.y;
    }
    float ls = h0 + h1;
    float lq = h0 * h0 + h1 * h1;
    #pragma unroll
    for (int s = 32; s >= 1; s >>= 1) {
        ls += __shfl_xor(ls, s);
        lq += __shfl_xor(lq, s);
    }
    int wid = t >> 6, lane = t & 63;
    if (lane == 0) { red[wid] = ls; red[4 + wid] = lq; }
    __syncthreads();
    float mu  = (red[0] + red[1] + red[2] + red[3]) * (1.f / 512.f);
    float var = (red[4] + red[5] + red[6] + red[7]) * (1.f / 512.f) - mu * mu;
    float rstd = rsqrtf(var + 1e-5f);
    float o0, o1;
    {
        float2 lw = *(const float2*)(ln_w + c0);
        float2 lb = *(const float2*)(ln_b + c0);
        float2 p0 = *(const float2*)(pw_w + c0);
        float2 p1 = *(const float2*)(pw_w + 512 + c0);
        float hn0 = (h0 - mu) * rstd * lw.x + lb.x;
        float hn1 = (h1 - mu) * rstd * lw.y + lb.y;
        float g0 = 0.5f * hn0 * (1.f + erff(hn0 * 0.70710678118f));
        float g1 = 0.5f * hn1 * (1.f + erff(hn1 * 0.70710678118f));
        o0 = g0 * p0.x + g1 * p0.y;
        o1 = g0 * p1.x + g1 * p1.y;
    }
    #pragma unroll
    for (int s = 32; s >= 1; s >>= 1) {
        o0 += __shfl_xor(o0, s);
        o1 += __shfl_xor(o1, s);
    }
    __syncthreads();
    if (lane == 0) { red[wid] = o0; red[4 + wid] = o1; }
    __syncthreads();
    if (t == 0) {
        float oy = tanhf(red[0] + red[1] + red[2] + red[3]) * 0.0625f;
        float ox = tanhf(red[4] + red[5] + red[6] + red[7]) * 0.0625f;
        float ry = ((y + 0.5f) * (1.f / 32.f)) * 2.f - 1.f;
        float rx = ((x + 0.5f) * (1.f / 32.f)) * 2.f - 1.f;
        float py = oy + ry, px = ox + rx;
        pos[bid * 2]     = py;
        pos[bid * 2 + 1] = px;
        psh = make_float2(py, px);
    }
    __syncthreads();
    // ---- sampling phase
    float py = psh.x, px = psh.y;
    float gx = (px + 1.f) * 15.5f;
    float gy = (py + 1.f) * 15.5f;
    float x0f = floorf(gx), y0f = floorf(gy);
    int ix0 = (int)x0f, iy0 = (int)y0f;
    float wx1 = gx - x0f, wx0 = 1.f - wx1;
    float wy1 = gy - y0f, wy0 = 1.f - wy1;
    const short* base = xt + (size_t)b * 524288;
    float a0 = 0.f, a1 = 0.f;
    #pragma unroll
    for (int tap = 0; tap < 4; ++tap) {
        int ix = ix0 + (tap & 1), iy = iy0 + (tap >> 1);
        float w = ((tap & 1) ? wx1 : wx0) * ((tap >> 1) ? wy1 : wy0);
        if (ix >= 0 && ix < 32 && iy >= 0 && iy < 32) {
            unsigned u = *(const unsigned*)(base + (size_t)(iy * 32 + ix) * 512 + c0);
            a0 += bf2f((short)(u & 0xFFFF)) * w;
            a1 += bf2f((short)(u >> 16)) * w;
        }
    }
    unsigned o = ((unsigned)(unsigned short)f2bf(a0)) |
                 (((unsigned)(unsigned short)f2bf(a1)) << 16);
    *(unsigned*)(xs + (size_t)bid * 512 + c0) = o;
}

// ---------------------------------------------------------------------------
// FUSED attention, 512 threads (8 waves), swapped QK^T (lane owns m=c16).
// RPE table pre-scaled by log2(e); exp via raw v_exp_f32; K frags register
// double-buffered; per-n (32-py*15.5, 32-px*15.5) precomputed at staging.
// Raw exp f16 pairs -> Pn; invS deferred to PV epilogue / stream via shfl.
// grid (64 m-tiles, 8 h, 4 b)
// ---------------------------------------------------------------------------
__global__ __launch_bounds__(512, 4) void attn_fused(
    const short* __restrict__ qbf, const short* __restrict__ kbf,
    const short* __restrict__ vhf, const float* __restrict__ pos,
    const float* __restrict__ rpe, const float* __restrict__ x,
    const float* __restrict__ gamma, float* __restrict__ attn_out,
    float* __restrict__ out0)
{
    __shared__ __align__(16) char smem_raw[33024];   // rpe(16900)+ccs(8192) | Pn 16*1032*2
    __shared__ float S_part[16][8];
    h2*     rpe_s = (h2*)smem_raw;                    // [65*65] pair table (x log2e)
    float2* ccs   = (float2*)(smem_raw + 16960);      // [1024] (32-py*15.5, 32-px*15.5)
    short*  Pn    = (short*)smem_raw;                 // [16][1032] f16 RAW exp

    const float L2E = 1.44269504f;
    int m0 = blockIdx.x * 16, h = blockIdx.y, b = blockIdx.z;
    int t = threadIdx.x, wn = t >> 6, l = t & 63;
    int g = l >> 4, c16 = l & 15;

    #pragma unroll
    for (int i = 0; i < 9; ++i) {
        int e = i * 512 + t;
        if (e < 4225) rpe_s[e] = (h2)((_Float16)0.f);
    }
    __syncthreads();
    const float* rh = rpe + h * 3969;
    #pragma unroll
    for (int i = 0; i < 8; ++i) {
        int e = i * 512 + t;
        if (e < 3969) {
            int iy = (int)(((unsigned)e * 16645u) >> 20);   // e/63 exact for e<3969
            int ix = e - iy * 63;
            float v0 = rh[e] * L2E;
            float v1 = (ix < 62) ? rh[e + 1] * L2E : 0.f;
            h2 pr; pr[0] = (_Float16)v0; pr[1] = (_Float16)v1;
            rpe_s[(iy + 1) * 65 + ix + 1] = pr;
        }
    }
    if (t < 63) {
        h2 pr; pr[0] = (_Float16)0.f; pr[1] = (_Float16)(rh[t * 63] * L2E);
        rpe_s[(t + 1) * 65] = pr;
    }
    #pragma unroll
    for (int i = 0; i < 2; ++i) {
        int idx = i * 512 + t;
        float2 pf = *(const float2*)(pos + b * 2048 + idx * 2);
        ccs[idx] = make_float2(fmaf(-15.5f, pf.x, 32.f), fmaf(-15.5f, pf.y, 32.f));
    }
    // q fragments; lane's m = m0 + c16
    int rowm = m0 + c16;
    const short* qrow = qbf + ((size_t)(b * 1024 + rowm) * 512 + h * 64 + g * 8);
    bf16x8 aq0 = *(const bf16x8*)qrow;
    bf16x8 aq1 = *(const bf16x8*)(qrow + 32);
    float qy = (((rowm >> 5) + 0.5f) * (1.f / 16.f) - 1.f) * 15.5f;
    float qx = (((rowm & 31) + 0.5f) * (1.f / 16.f) - 1.f) * 15.5f;
    __syncthreads();

    // ---- pass A: 8 n-tiles of 16; K frags double-buffered
    float Ssum = 0.f;
    float e0, e1;
    unsigned ep[16];
    const short* kr = kbf + ((size_t)(b * 1024 + wn * 128 + c16) * 512 + h * 64 + g * 8);
    bf16x8 nk0 = *(const bf16x8*)kr;
    bf16x8 nk1 = *(const bf16x8*)(kr + 32);
    #pragma unroll
    for (int nt = 0; nt < 8; ++nt) {
        bf16x8 bk0 = nk0, bk1 = nk1;
        if (nt < 7) {
            kr += 16 * 512;
            nk0 = *(const bf16x8*)kr;
            nk1 = *(const bf16x8*)(kr + 32);
        }
        __builtin_amdgcn_s_setprio(1);
        f32x4 acc = {0.f, 0.f, 0.f, 0.f};
        acc = __builtin_amdgcn_mfma_f32_16x16x32_bf16(bk0, aq0, acc, 0, 0, 0);
        acc = __builtin_amdgcn_mfma_f32_16x16x32_bf16(bk1, aq1, acc, 0, 0, 0);
        __builtin_amdgcn_s_setprio(0);
        int nb = wn * 128 + nt * 16;
        #pragma unroll
        for (int r = 0; r < 4; ++r) {
            float2 cc = ccs[nb + g * 4 + r];           // broadcast across c16
            float gyp = qy + cc.x;
            float gxp = qx + cc.y;
            float fy = floorf(gyp), fx = floorf(gxp);
            float wy1 = gyp - fy, wx1 = gxp - fx;
            int ad = (int)(fy * 65.f + fx);
            h2 r0 = rpe_s[ad];
            h2 r1 = rpe_s[ad + 65];
            h2 wp = pkrtz(1.f - wx1, wx1);
            float t0 = dot2(r0, wp);
            float t1 = dot2(r1, wp);
            float bias2 = t0 + wy1 * (t1 - t0);        // already x log2e
            float logit2 = fmaf(acc[r], 0.1803368801f, bias2);  // 0.125*log2e
            float e = fast_exp2(logit2);
            Ssum += e;
            if (r == 0) e0 = e;
            else if (r == 1) ep[nt * 2] = __builtin_bit_cast(unsigned, pkrtz(e0, e));
            else if (r == 2) e1 = e;
            else ep[nt * 2 + 1] = __builtin_bit_cast(unsigned, pkrtz(e1, e));
        }
    }
    Ssum += __shfl_xor(Ssum, 16);
    Ssum += __shfl_xor(Ssum, 32);
    if (l < 16) S_part[c16][wn] = Ssum;
    __syncthreads();   // pass-A LDS reads done; rpe/ccs region dead
    float4 sa = *(const float4*)&S_part[c16][0];
    float4 sb = *(const float4*)&S_part[c16][4];
    float invS = 1.f / (sa.x + sa.y + sa.z + sa.w + sb.x + sb.y + sb.z + sb.w);

    // ---- raw exp pairs -> Pn[m=c16][n]
    short* prow = Pn + c16 * 1032 + wn * 128;
    #pragma unroll
    for (int nt = 0; nt < 8; ++nt) {
        uint2 w;
        w.x = ep[nt * 2];
        w.y = ep[nt * 2 + 1];
        *(uint2*)(prow + nt * 16 + g * 4) = w;
    }
    __syncthreads();

    size_t obase = ((size_t)((b * 8 + h) * 1024 + m0)) * 1024;
    if (wn >= 4) {
        // ---- attn fp32 stream: waves 4-7, scale by invS[row] during convert
        int tw = t - 256;
        #pragma unroll
        for (int row = 0; row < 16; ++row) {
            float ivr = __shfl(invS, row);
            const unsigned* pr = (const unsigned*)(Pn + row * 1032 + tw * 4);
            unsigned u0 = pr[0], u1 = pr[1];
            h2 a = __builtin_bit_cast(h2, u0);
            h2 bb = __builtin_bit_cast(h2, u1);
            float4 vv = make_float4((float)a[0] * ivr, (float)a[1] * ivr,
                                    (float)bb[0] * ivr, (float)bb[1] * ivr);
            *(float4*)(attn_out + obase + (size_t)row * 1024 + tw * 4) = vv;
        }
    } else {
        // ---- PV: wave wn owns channels wn*16..+15; f16 MFMA on RAW P
        const short* Vb = vhf + ((size_t)(b * 512 + h * 64 + wn * 16 + c16)) * 1024;
        const short* Prow = Pn + c16 * 1032 + g * 8;
        f32x4 dacc = {0.f, 0.f, 0.f, 0.f};
        __builtin_amdgcn_s_setprio(1);
        #pragma unroll
        for (int cc = 0; cc < 32; ++cc) {
            int n0 = cc * 32;
            f16x8 pa  = *(const f16x8*)(Prow + n0);
            f16x8 vb8 = *(const f16x8*)(Vb + n0 + g * 8);
            dacc = __builtin_amdgcn_mfma_f32_16x16x32_f16(pa, vb8, dacc, 0, 0, 0);
        }
        __builtin_amdgcn_s_setprio(0);
        float gm = gamma[0];
        float gi0 = gm * __shfl(invS, g * 4);
        float gi1 = gm * __shfl(invS, g * 4 + 1);
        float gi2 = gm * __shfl(invS, g * 4 + 2);
        float gi3 = gm * __shfl(invS, g * 4 + 3);
        int ch = h * 64 + wn * 16 + c16;
        int m = m0 + g * 4;
        size_t idx = ((size_t)(b * 512 + ch)) * 1024 + m;
        float4 xv = *(const float4*)(x + idx);
        float4 ov;
        ov.x = gi0 * dacc[0] + xv.x;
        ov.y = gi1 * dacc[1] + xv.y;
        ov.z = gi2 * dacc[2] + xv.z;
        ov.w = gi3 * dacc[3] + xv.w;
        *(float4*)(out0 + idx) = ov;
    }
}

extern "C" void kernel_launch(void* const* d_in, const int* in_sizes, int n_in,
                              void* d_out, int out_size, void* d_ws, size_t ws_size,
                              hipStream_t stream) {
    const float* x     = (const float*)d_in[0];
    const float* dw_w  = (const float*)d_in[1];
    const float* dw_b  = (const float*)d_in[2];
    const float* ln_w  = (const float*)d_in[3];
    const float* ln_b  = (const float*)d_in[4];
    const float* pw_w  = (const float*)d_in[5];
    const float* q_w   = (const float*)d_in[6];
    const float* q_b   = (const float*)d_in[7];
    const float* k_w   = (const float*)d_in[8];
    const float* k_b   = (const float*)d_in[9];
    const float* v_w   = (const float*)d_in[10];
    const float* v_b   = (const float*)d_in[11];
    const float* rpe   = (const float*)d_in[12];
    const float* gamma = (const float*)d_in[13];

    float* out0 = (float*)d_out;
    float* attn = out0 + (size_t)4 * 512 * 1024;

    char* w = (char*)d_ws;
    short* xt   = (short*)w;                      // 4 MB
    short* qwb  = (short*)(w + 4194304);
    short* kwb  = (short*)(w + 4718592);
    short* vwb  = (short*)(w + 5242880);
    short* qbf  = (short*)(w + 5767168);          // 4 MB
    short* xsb  = (short*)(w + 9961472);          // 4 MB
    short* kbf  = (short*)(w + 14155776);         // 4 MB
    short* vhf  = (short*)(w + 18350080);         // 4 MB (f16)
    float* pos  = (float*)(w + 22544384);         // 32 KB

    prep_x<<<dim3(16, 8, 5), 256, 0, stream>>>(x, xt, q_w, k_w, v_w, qwb, kwb, vwb);
    gemm_q<<<dim3(32, 4), 256, 0, stream>>>(xt, qwb, q_b, qbf);
    offset_sample<<<4096, 256, 0, stream>>>(qbf, dw_w, dw_b, ln_w, ln_b, pw_w,
                                            xt, pos, xsb);
    gemm_kv<<<256, 256, 0, stream>>>(xsb, kwb, k_b, kbf, vwb, v_b, vhf);
    attn_fused<<<dim3(64, 8, 4), 512, 0, stream>>>(qbf, kbf, vhf, pos, rpe, x,
                                                   gamma, attn, out0);
}

// Round 10
// 118.436 us; speedup vs baseline: 3.7251x; 1.2309x over previous
//
#include <hip/hip_runtime.h>
#include <hip/hip_bf16.h>
#include <math.h>

typedef short bf16x8 __attribute__((ext_vector_type(8)));
typedef _Float16 f16x8 __attribute__((ext_vector_type(8)));
typedef float f32x4 __attribute__((ext_vector_type(4)));
typedef _Float16 h2 __attribute__((ext_vector_type(2)));

__device__ inline short f2bf(float f) {
    union { float f; unsigned u; } v; v.f = f;
    unsigned r = v.u + 0x7FFFu + ((v.u >> 16) & 1u);
    return (short)(r >> 16);
}
__device__ inline float bf2f(short s) {
    union { unsigned u; float f; } v; v.u = ((unsigned)(unsigned short)s) << 16;
    return v.f;
}
__device__ inline h2 pkrtz(float a, float b) {
    return __builtin_bit_cast(h2, __builtin_amdgcn_cvt_pkrtz(a, b));
}
__device__ inline float fast_exp2(float x) {
    float r;
    asm("v_exp_f32 %0, %1" : "=v"(r) : "v"(x));
    return r;
}
__device__ inline float dot2(h2 a, h2 b) {
#if __has_builtin(__builtin_amdgcn_fdot2)
    return __builtin_amdgcn_fdot2(a, b, 0.f, false);
#else
    return (float)a[0] * (float)b[0] + (float)a[1] * (float)b[1];
#endif
}

// ---------------------------------------------------------------------------
// z<4: transpose-cast x -> xt [b][p][c] bf16.  z==4: weight cast.
// z==5 (x<8,y==0): build padded 65x65 RPE pair-table (x log2e) per head.
// ---------------------------------------------------------------------------
__global__ __launch_bounds__(256) void prep_x(
    const float* __restrict__ x, short* __restrict__ xt,
    const float* __restrict__ qw, const float* __restrict__ kw,
    const float* __restrict__ vw, short* __restrict__ qwb,
    short* __restrict__ kwb, short* __restrict__ vwb,
    const float* __restrict__ rpe, unsigned* __restrict__ rpet)
{
    __shared__ float ts[64][65];
    int t = threadIdx.x;
    if (blockIdx.z == 5) {   // RPE pre-pad plane: head = blockIdx.x
        if (blockIdx.y != 0 || blockIdx.x >= 8) return;
        int hh = blockIdx.x;
        const float* rh = rpe + hh * 3969;
        const float L2E = 1.44269504f;
        #pragma unroll
        for (int i = 0; i < 17; ++i) {
            int j = i * 256 + t;
            if (j < 4225) {
                int iy = j / 65;
                int ix = j - iy * 65;
                float v0 = 0.f, v1 = 0.f;
                if (iy >= 1 && iy <= 63) {
                    const float* rr = rh + (iy - 1) * 63;
                    if (ix >= 1 && ix <= 63) v0 = rr[ix - 1] * L2E;
                    if (ix <= 62)            v1 = rr[ix] * L2E;
                }
                h2 pr; pr[0] = (_Float16)v0; pr[1] = (_Float16)v1;
                rpet[hh * 4225 + j] = __builtin_bit_cast(unsigned, pr);
            }
        }
        return;
    }
    if (blockIdx.z == 4) {   // weight cast plane
        int f = blockIdx.y * 16 + blockIdx.x;
        int base = (f * 256 + t) * 8;
        #pragma unroll
        for (int w = 0; w < 3; ++w) {
            const float* src = (w == 0) ? qw : (w == 1) ? kw : vw;
            short* dst = (w == 0) ? qwb : (w == 1) ? kwb : vwb;
            float4 f0 = *(const float4*)(src + base);
            float4 f1 = *(const float4*)(src + base + 4);
            bf16x8 o;
            o[0] = f2bf(f0.x); o[1] = f2bf(f0.y); o[2] = f2bf(f0.z); o[3] = f2bf(f0.w);
            o[4] = f2bf(f1.x); o[5] = f2bf(f1.y); o[6] = f2bf(f1.z); o[7] = f2bf(f1.w);
            *(bf16x8*)(dst + base) = o;
        }
        return;
    }
    int p0 = blockIdx.x * 64, c0 = blockIdx.y * 64, b = blockIdx.z;
    #pragma unroll
    for (int i = 0; i < 16; ++i) {
        int idx = i * 256 + t;
        int cl = idx >> 6, pl = idx & 63;
        ts[cl][pl] = x[((size_t)(b * 512 + c0 + cl)) * 1024 + p0 + pl];
    }
    __syncthreads();
    #pragma unroll
    for (int i = 0; i < 16; ++i) {
        int idx = i * 256 + t;
        int pl = idx >> 6, cl = idx & 63;
        xt[((size_t)(b * 1024 + p0 + pl)) * 512 + c0 + cl] = f2bf(ts[cl][pl]);
    }
}

// ---------------------------------------------------------------------------
// 128x128 NT MFMA tile body (K=512): acc[4][4] per thread.
// ---------------------------------------------------------------------------
__device__ inline void nt_tile_128(const short* __restrict__ A,
                                   const short* __restrict__ B,
                                   int m0, int n0, int t,
                                   short (*As)[32], short (*Bs)[32],
                                   f32x4 (&acc)[4][4])
{
    int wid = t >> 6, l = t & 63;
    int wm = wid >> 1, wn = wid & 1;
    int srow = t >> 1, half = t & 1;
    int sw = (srow >> 1) & 3;
    int s0 = (half * 2) ^ sw, s1 = (half * 2 + 1) ^ sw;
    for (int k0 = 0; k0 < 512; k0 += 32) {
        const int4 a0 = *(const int4*)(A + (size_t)(m0 + srow) * 512 + k0 + half * 16);
        const int4 a1 = *(const int4*)(A + (size_t)(m0 + srow) * 512 + k0 + half * 16 + 8);
        const int4 b0 = *(const int4*)(B + (size_t)(n0 + srow) * 512 + k0 + half * 16);
        const int4 b1 = *(const int4*)(B + (size_t)(n0 + srow) * 512 + k0 + half * 16 + 8);
        __syncthreads();
        *(int4*)&As[srow][s0 * 8] = a0;
        *(int4*)&As[srow][s1 * 8] = a1;
        *(int4*)&Bs[srow][s0 * 8] = b0;
        *(int4*)&Bs[srow][s1 * 8] = b1;
        __syncthreads();
        bf16x8 af[4], bfr[4];
        #pragma unroll
        for (int mt = 0; mt < 4; ++mt) {
            int r = wm * 64 + mt * 16 + (l & 15);
            af[mt] = *(const bf16x8*)&As[r][(((l >> 4)) ^ ((r >> 1) & 3)) * 8];
        }
        #pragma unroll
        for (int nt = 0; nt < 4; ++nt) {
            int r = wn * 64 + nt * 16 + (l & 15);
            bfr[nt] = *(const bf16x8*)&Bs[r][(((l >> 4)) ^ ((r >> 1) & 3)) * 8];
        }
        #pragma unroll
        for (int mt = 0; mt < 4; ++mt)
            #pragma unroll
            for (int nt = 0; nt < 4; ++nt)
                acc[mt][nt] = __builtin_amdgcn_mfma_f32_16x16x32_bf16(
                    af[mt], bfr[nt], acc[mt][nt], 0, 0, 0);
    }
}

// q projection (dense [m][n] bf16 out; offset net + attn Q read it)
__global__ __launch_bounds__(256) void gemm_q(
    const short* __restrict__ A, const short* __restrict__ B,
    const float* __restrict__ bias, short* __restrict__ Ob)
{
    __shared__ short As[128][32];
    __shared__ short Bs[128][32];
    int m0 = blockIdx.x * 128, n0 = blockIdx.y * 128;
    int t = threadIdx.x, wid = t >> 6, l = t & 63;
    int wm = wid >> 1, wn = wid & 1;
    f32x4 acc[4][4] = {};
    nt_tile_128(A, B, m0, n0, t, As, Bs, acc);
    #pragma unroll
    for (int mt = 0; mt < 4; ++mt)
        #pragma unroll
        for (int nt = 0; nt < 4; ++nt)
            #pragma unroll
            for (int r = 0; r < 4; ++r) {
                int m = m0 + wm * 64 + mt * 16 + (l >> 4) * 4 + r;
                int n = n0 + wn * 64 + nt * 16 + (l & 15);
                Ob[(size_t)m * 512 + n] = f2bf(acc[mt][nt][r] + bias[n]);
            }
}

// k-gemm (bid<128) + v-gemm (bid>=128), outputs in MFMA-FRAGMENT ORDER:
// kfr[((bh*64+T)*2+frag)*64 + g*16+cs][8] bf16 (T = sample tile, cs = sample%16)
// vfr[((bh*4+wg)*32+cc)*64 + g*16+cs][8] f16  (wg = chgrp, cs = ch%16)
__global__ __launch_bounds__(256) void gemm_kv(
    const short* __restrict__ xsb, const short* __restrict__ kwb,
    const float* __restrict__ k_b, short* __restrict__ kfr,
    const short* __restrict__ vwb, const float* __restrict__ v_b,
    short* __restrict__ vfr)
{
    __shared__ short As[128][32];
    __shared__ short Bs[128][32];
    int bid = blockIdx.x;
    int t = threadIdx.x, wid = t >> 6, l = t & 63;
    int wm = wid >> 1, wn = wid & 1;
    f32x4 acc[4][4] = {};
    if (bid < 128) {
        int m0 = (bid >> 2) * 128, n0 = (bid & 3) * 128;
        nt_tile_128(xsb, kwb, m0, n0, t, As, Bs, acc);
        #pragma unroll
        for (int mt = 0; mt < 4; ++mt)
            #pragma unroll
            for (int nt = 0; nt < 4; ++nt)
                #pragma unroll
                for (int r = 0; r < 4; ++r) {
                    int m = m0 + wm * 64 + mt * 16 + (l >> 4) * 4 + r;  // sample
                    int n = n0 + wn * 64 + nt * 16 + (l & 15);          // channel
                    int bq = m >> 10, p = m & 1023;
                    int T = p >> 4, cs = p & 15;
                    int h = n >> 6, ch = n & 63;
                    int frag = ch >> 5, gg = (ch >> 3) & 3, e = ch & 7;
                    kfr[((((size_t)(bq * 8 + h) * 64 + T) * 2 + frag) * 64
                         + gg * 16 + cs) * 8 + e] = f2bf(acc[mt][nt][r] + k_b[n]);
                }
    } else {
        int id2 = bid - 128;
        int z = id2 >> 5, rr2 = id2 & 31;
        int m0 = (rr2 >> 3) * 128, n0 = (rr2 & 7) * 128;
        nt_tile_128(vwb, xsb + (size_t)z * 524288, m0, n0, t, As, Bs, acc);
        #pragma unroll
        for (int mt = 0; mt < 4; ++mt)
            #pragma unroll
            for (int nt = 0; nt < 4; ++nt)
                #pragma unroll
                for (int r = 0; r < 4; ++r) {
                    int m = m0 + wm * 64 + mt * 16 + (l >> 4) * 4 + r;  // channel
                    int n = n0 + wn * 64 + nt * 16 + (l & 15);          // sample
                    int h = m >> 6, wg = (m & 63) >> 4, cs = m & 15;
                    int cc = n >> 5, gg = (n >> 3) & 3, e = n & 7;
                    _Float16 hv = (_Float16)(acc[mt][nt][r] + v_b[m]);
                    vfr[((((size_t)(z * 8 + h) * 4 + wg) * 32 + cc) * 64
                         + gg * 16 + cs) * 8 + e] = __builtin_bit_cast(short, hv);
                }
    }
}

// ---------------------------------------------------------------------------
// FUSED offset network + deformable sampling
// ---------------------------------------------------------------------------
__global__ __launch_bounds__(256) void offset_sample(
    const short* __restrict__ qbf, const float* __restrict__ dw_w,
    const float* __restrict__ dw_b, const float* __restrict__ ln_w,
    const float* __restrict__ ln_b, const float* __restrict__ pw_w,
    const short* __restrict__ xt, float* __restrict__ pos,
    short* __restrict__ xs)
{
    __shared__ float red[8];
    __shared__ float2 psh;
    int bid = blockIdx.x;
    int b = bid >> 10, p = bid & 1023;
    int y = p >> 5, x = p & 31;
    int t = threadIdx.x;
    int c0 = 2 * t;
    const short* qb = qbf + (size_t)b * 524288;
    float h0, h1;
    {
        const float* w0 = dw_w + c0 * 9;
        const float* w1 = w0 + 9;
        float s0 = 0.f, s1 = 0.f;
        #pragma unroll
        for (int ky = 0; ky < 3; ++ky) {
            int yy = y + ky - 1;
            if (yy < 0 || yy > 31) continue;
            #pragma unroll
            for (int kx = 0; kx < 3; ++kx) {
                int xx = x + kx - 1;
                if (xx < 0 || xx > 31) continue;
                unsigned u = *(const unsigned*)(qb + (size_t)(yy * 32 + xx) * 512 + c0);
                s0 += bf2f((short)(u & 0xFFFF)) * w0[ky * 3 + kx];
                s1 += bf2f((short)(u >> 16)) * w1[ky * 3 + kx];
            }
        }
        float2 db = *(const float2*)(dw_b + c0);
        h0 = s0 + db.x; h1 = s1 + db.y;
    }
    float ls = h0 + h1;
    float lq = h0 * h0 + h1 * h1;
    #pragma unroll
    for (int s = 32; s >= 1; s >>= 1) {
        ls += __shfl_xor(ls, s);
        lq += __shfl_xor(lq, s);
    }
    int wid = t >> 6, lane = t & 63;
    if (lane == 0) { red[wid] = ls; red[4 + wid] = lq; }
    __syncthreads();
    float mu  = (red[0] + red[1] + red[2] + red[3]) * (1.f / 512.f);
    float var = (red[4] + red[5] + red[6] + red[7]) * (1.f / 512.f) - mu * mu;
    float rstd = rsqrtf(var + 1e-5f);
    float o0, o1;
    {
        float2 lw = *(const float2*)(ln_w + c0);
        float2 lb = *(const float2*)(ln_b + c0);
        float2 p0 = *(const float2*)(pw_w + c0);
        float2 p1 = *(const float2*)(pw_w + 512 + c0);
        float hn0 = (h0 - mu) * rstd * lw.x + lb.x;
        float hn1 = (h1 - mu) * rstd * lw.y + lb.y;
        float g0 = 0.5f * hn0 * (1.f + erff(hn0 * 0.70710678118f));
        float g1 = 0.5f * hn1 * (1.f + erff(hn1 * 0.70710678118f));
        o0 = g0 * p0.x + g1 * p0.y;
        o1 = g0 * p1.x + g1 * p1.y;
    }
    #pragma unroll
    for (int s = 32; s >= 1; s >>= 1) {
        o0 += __shfl_xor(o0, s);
        o1 += __shfl_xor(o1, s);
    }
    __syncthreads();
    if (lane == 0) { red[wid] = o0; red[4 + wid] = o1; }
    __syncthreads();
    if (t == 0) {
        float oy = tanhf(red[0] + red[1] + red[2] + red[3]) * 0.0625f;
        float ox = tanhf(red[4] + red[5] + red[6] + red[7]) * 0.0625f;
        float ry = ((y + 0.5f) * (1.f / 32.f)) * 2.f - 1.f;
        float rx = ((x + 0.5f) * (1.f / 32.f)) * 2.f - 1.f;
        float py = oy + ry, px = ox + rx;
        pos[bid * 2]     = py;
        pos[bid * 2 + 1] = px;
        psh = make_float2(py, px);
    }
    __syncthreads();
    float py = psh.x, px = psh.y;
    float gx = (px + 1.f) * 15.5f;
    float gy = (py + 1.f) * 15.5f;
    float x0f = floorf(gx), y0f = floorf(gy);
    int ix0 = (int)x0f, iy0 = (int)y0f;
    float wx1 = gx - x0f, wx0 = 1.f - wx1;
    float wy1 = gy - y0f, wy0 = 1.f - wy1;
    const short* base = xt + (size_t)b * 524288;
    float a0 = 0.f, a1 = 0.f;
    #pragma unroll
    for (int tap = 0; tap < 4; ++tap) {
        int ix = ix0 + (tap & 1), iy = iy0 + (tap >> 1);
        float w = ((tap & 1) ? wx1 : wx0) * ((tap >> 1) ? wy1 : wy0);
        if (ix >= 0 && ix < 32 && iy >= 0 && iy < 32) {
            unsigned u = *(const unsigned*)(base + (size_t)(iy * 32 + ix) * 512 + c0);
            a0 += bf2f((short)(u & 0xFFFF)) * w;
            a1 += bf2f((short)(u >> 16)) * w;
        }
    }
    unsigned o = ((unsigned)(unsigned short)f2bf(a0)) |
                 (((unsigned)(unsigned short)f2bf(a1)) << 16);
    *(unsigned*)(xs + (size_t)bid * 512 + c0) = o;
}

// ---------------------------------------------------------------------------
// FUSED attention, 512 threads, swapped QK^T, FRAGMENT-ORDERED K/V:
// every K/V fragment load = base + lane*16B (one coalesced 1KB wave load).
// RPE staged by linear copy from pre-padded global table.
// grid (64 m-tiles, 8 h, 4 b)
// ---------------------------------------------------------------------------
__global__ __launch_bounds__(512, 4) void attn_fused(
    const short* __restrict__ qbf, const short* __restrict__ kfr,
    const short* __restrict__ vfr, const float* __restrict__ pos,
    const unsigned* __restrict__ rpet, const float* __restrict__ x,
    const float* __restrict__ gamma, float* __restrict__ attn_out,
    float* __restrict__ out0)
{
    __shared__ __align__(16) char smem_raw[33024];   // rpe(16900)+ccs(8192) | Pn 16*1032*2
    __shared__ float S_part[16][8];
    h2*     rpe_s = (h2*)smem_raw;                    // [65*65] pair table (x log2e)
    float2* ccs   = (float2*)(smem_raw + 16960);      // [1024]
    short*  Pn    = (short*)smem_raw;                 // [16][1032] f16 RAW exp

    int m0 = blockIdx.x * 16, h = blockIdx.y, b = blockIdx.z;
    int t = threadIdx.x, wn = t >> 6, l = t & 63;
    int g = l >> 4, c16 = l & 15;
    int bh = b * 8 + h;

    const unsigned* rt = rpet + h * 4225;
    #pragma unroll
    for (int i = 0; i < 9; ++i) {
        int e = i * 512 + t;
        if (e < 4225) ((unsigned*)rpe_s)[e] = rt[e];
    }
    #pragma unroll
    for (int i = 0; i < 2; ++i) {
        int idx = i * 512 + t;
        float2 pf = *(const float2*)(pos + b * 2048 + idx * 2);
        ccs[idx] = make_float2(fmaf(-15.5f, pf.x, 32.f), fmaf(-15.5f, pf.y, 32.f));
    }
    // q fragments (dense layout; only 2 loads/thread)
    int rowm = m0 + c16;
    const short* qrow = qbf + ((size_t)(b * 1024 + rowm) * 512 + h * 64 + g * 8);
    bf16x8 aq0 = *(const bf16x8*)qrow;
    bf16x8 aq1 = *(const bf16x8*)(qrow + 32);
    float qy = (((rowm >> 5) + 0.5f) * (1.f / 16.f) - 1.f) * 15.5f;
    float qx = (((rowm & 31) + 0.5f) * (1.f / 16.f) - 1.f) * 15.5f;
    __syncthreads();

    // ---- pass A: 8 n-tiles; K frags coalesced + register double-buffered
    float Ssum = 0.f;
    float e0, e1;
    unsigned ep[16];
    const short* kr = kfr + (size_t)((bh * 64 + wn * 8)) * 1024;
    bf16x8 nk0 = *(const bf16x8*)(kr + l * 8);
    bf16x8 nk1 = *(const bf16x8*)(kr + 512 + l * 8);
    #pragma unroll
    for (int nt = 0; nt < 8; ++nt) {
        bf16x8 bk0 = nk0, bk1 = nk1;
        if (nt < 7) {
            kr += 1024;
            nk0 = *(const bf16x8*)(kr + l * 8);
            nk1 = *(const bf16x8*)(kr + 512 + l * 8);
        }
        __builtin_amdgcn_s_setprio(1);
        f32x4 acc = {0.f, 0.f, 0.f, 0.f};
        acc = __builtin_amdgcn_mfma_f32_16x16x32_bf16(bk0, aq0, acc, 0, 0, 0);
        acc = __builtin_amdgcn_mfma_f32_16x16x32_bf16(bk1, aq1, acc, 0, 0, 0);
        __builtin_amdgcn_s_setprio(0);
        int nb = wn * 128 + nt * 16;
        #pragma unroll
        for (int r = 0; r < 4; ++r) {
            float2 cc = ccs[nb + g * 4 + r];           // broadcast across c16
            float gyp = qy + cc.x;
            float gxp = qx + cc.y;
            float fy = floorf(gyp), fx = floorf(gxp);
            float wy1 = gyp - fy, wx1 = gxp - fx;
            int ad = (int)(fy * 65.f + fx);
            h2 r0 = rpe_s[ad];
            h2 r1 = rpe_s[ad + 65];
            h2 wp = pkrtz(1.f - wx1, wx1);
            float t0 = dot2(r0, wp);
            float t1 = dot2(r1, wp);
            float bias2 = t0 + wy1 * (t1 - t0);        // already x log2e
            float logit2 = fmaf(acc[r], 0.1803368801f, bias2);  // 0.125*log2e
            float e = fast_exp2(logit2);
            Ssum += e;
            if (r == 0) e0 = e;
            else if (r == 1) ep[nt * 2] = __builtin_bit_cast(unsigned, pkrtz(e0, e));
            else if (r == 2) e1 = e;
            else ep[nt * 2 + 1] = __builtin_bit_cast(unsigned, pkrtz(e1, e));
        }
    }
    Ssum += __shfl_xor(Ssum, 16);
    Ssum += __shfl_xor(Ssum, 32);
    if (l < 16) S_part[c16][wn] = Ssum;
    __syncthreads();   // pass-A LDS reads done; rpe/ccs region dead
    float4 sa = *(const float4*)&S_part[c16][0];
    float4 sb = *(const float4*)&S_part[c16][4];
    float invS = 1.f / (sa.x + sa.y + sa.z + sa.w + sb.x + sb.y + sb.z + sb.w);

    // ---- raw exp pairs -> Pn[m=c16][n]
    short* prow = Pn + c16 * 1032 + wn * 128;
    #pragma unroll
    for (int nt = 0; nt < 8; ++nt) {
        uint2 w;
        w.x = ep[nt * 2];
        w.y = ep[nt * 2 + 1];
        *(uint2*)(prow + nt * 16 + g * 4) = w;
    }
    __syncthreads();

    size_t obase = ((size_t)(bh * 1024 + m0)) * 1024;
    if (wn >= 4) {
        // ---- attn fp32 stream: waves 4-7, scale by invS[row] during convert
        int tw = t - 256;
        #pragma unroll
        for (int row = 0; row < 16; ++row) {
            float ivr = __shfl(invS, row);
            const unsigned* pr = (const unsigned*)(Pn + row * 1032 + tw * 4);
            unsigned u0 = pr[0], u1 = pr[1];
            h2 a = __builtin_bit_cast(h2, u0);
            h2 bb = __builtin_bit_cast(h2, u1);
            float4 vv = make_float4((float)a[0] * ivr, (float)a[1] * ivr,
                                    (float)bb[0] * ivr, (float)bb[1] * ivr);
            *(float4*)(attn_out + obase + (size_t)row * 1024 + tw * 4) = vv;
        }
    } else {
        // ---- PV: wave wn owns channels wn*16..+15; V fragment-ordered
        const short* Vb = vfr + (size_t)((bh * 4 + wn) * 32) * 512;
        const short* Prow = Pn + c16 * 1032 + g * 8;
        f32x4 dacc = {0.f, 0.f, 0.f, 0.f};
        __builtin_amdgcn_s_setprio(1);
        #pragma unroll
        for (int cc = 0; cc < 32; ++cc) {
            f16x8 pa  = *(const f16x8*)(Prow + cc * 32);
            f16x8 vb8 = *(const f16x8*)(Vb + cc * 512 + l * 8);
            dacc = __builtin_amdgcn_mfma_f32_16x16x32_f16(pa, vb8, dacc, 0, 0, 0);
        }
        __builtin_amdgcn_s_setprio(0);
        float gm = gamma[0];
        float gi0 = gm * __shfl(invS, g * 4);
        float gi1 = gm * __shfl(invS, g * 4 + 1);
        float gi2 = gm * __shfl(invS, g * 4 + 2);
        float gi3 = gm * __shfl(invS, g * 4 + 3);
        int ch = h * 64 + wn * 16 + c16;
        int m = m0 + g * 4;
        size_t idx = ((size_t)(b * 512 + ch)) * 1024 + m;
        float4 xv = *(const float4*)(x + idx);
        float4 ov;
        ov.x = gi0 * dacc[0] + xv.x;
        ov.y = gi1 * dacc[1] + xv.y;
        ov.z = gi2 * dacc[2] + xv.z;
        ov.w = gi3 * dacc[3] + xv.w;
        *(float4*)(out0 + idx) = ov;
    }
}

extern "C" void kernel_launch(void* const* d_in, const int* in_sizes, int n_in,
                              void* d_out, int out_size, void* d_ws, size_t ws_size,
                              hipStream_t stream) {
    const float* x     = (const float*)d_in[0];
    const float* dw_w  = (const float*)d_in[1];
    const float* dw_b  = (const float*)d_in[2];
    const float* ln_w  = (const float*)d_in[3];
    const float* ln_b  = (const float*)d_in[4];
    const float* pw_w  = (const float*)d_in[5];
    const float* q_w   = (const float*)d_in[6];
    const float* q_b   = (const float*)d_in[7];
    const float* k_w   = (const float*)d_in[8];
    const float* k_b   = (const float*)d_in[9];
    const float* v_w   = (const float*)d_in[10];
    const float* v_b   = (const float*)d_in[11];
    const float* rpe   = (const float*)d_in[12];
    const float* gamma = (const float*)d_in[13];

    float* out0 = (float*)d_out;
    float* attn = out0 + (size_t)4 * 512 * 1024;

    char* w = (char*)d_ws;
    short*    xt   = (short*)w;                    // 4 MB
    short*    qwb  = (short*)(w + 4194304);
    short*    kwb  = (short*)(w + 4718592);
    short*    vwb  = (short*)(w + 5242880);
    short*    qbf  = (short*)(w + 5767168);        // 4 MB dense q
    short*    xsb  = (short*)(w + 9961472);        // 4 MB
    short*    kfr  = (short*)(w + 14155776);       // 4 MB frag-ordered K
    short*    vfr  = (short*)(w + 18350080);       // 4 MB frag-ordered V (f16)
    float*    pos  = (float*)(w + 22544384);       // 32 KB
    unsigned* rpet = (unsigned*)(w + 22577152);    // 8*4225*4 = 135 KB

    prep_x<<<dim3(16, 8, 6), 256, 0, stream>>>(x, xt, q_w, k_w, v_w, qwb, kwb,
                                               vwb, rpe, rpet);
    gemm_q<<<dim3(32, 4), 256, 0, stream>>>(xt, qwb, q_b, qbf);
    offset_sample<<<4096, 256, 0, stream>>>(qbf, dw_w, dw_b, ln_w, ln_b, pw_w,
                                            xt, pos, xsb);
    gemm_kv<<<256, 256, 0, stream>>>(xsb, kwb, k_b, kfr, vwb, v_b, vfr);
    attn_fused<<<dim3(64, 8, 4), 512, 0, stream>>>(qbf, kfr, vfr, pos, rpet, x,
                                                   gamma, attn, out0);
}

// Round 11
// 112.996 us; speedup vs baseline: 3.9045x; 1.0481x over previous
//
#include <hip/hip_runtime.h>
#include <hip/hip_bf16.h>
#include <math.h>

typedef short bf16x8 __attribute__((ext_vector_type(8)));
typedef _Float16 f16x8 __attribute__((ext_vector_type(8)));
typedef float f32x4 __attribute__((ext_vector_type(4)));
typedef _Float16 h2 __attribute__((ext_vector_type(2)));

__device__ inline short f2bf(float f) {
    union { float f; unsigned u; } v; v.f = f;
    unsigned r = v.u + 0x7FFFu + ((v.u >> 16) & 1u);
    return (short)(r >> 16);
}
__device__ inline float bf2f(short s) {
    union { unsigned u; float f; } v; v.u = ((unsigned)(unsigned short)s) << 16;
    return v.f;
}
__device__ inline h2 pkrtz(float a, float b) {
    return __builtin_bit_cast(h2, __builtin_amdgcn_cvt_pkrtz(a, b));
}
__device__ inline float fast_exp2(float x) {
    float r;
    asm("v_exp_f32 %0, %1" : "=v"(r) : "v"(x));
    return r;
}
__device__ inline float dot2(h2 a, h2 b) {
#if __has_builtin(__builtin_amdgcn_fdot2)
    return __builtin_amdgcn_fdot2(a, b, 0.f, false);
#else
    return (float)a[0] * (float)b[0] + (float)a[1] * (float)b[1];
#endif
}

// ---------------------------------------------------------------------------
// z<4: transpose-cast x -> xt [b][p][c] bf16.  z==4: weight cast.
// z==5 (x<8,y==0): build padded 65x65 RPE pair-table (x log2e) per head.
// ---------------------------------------------------------------------------
__global__ __launch_bounds__(256) void prep_x(
    const float* __restrict__ x, short* __restrict__ xt,
    const float* __restrict__ qw, const float* __restrict__ kw,
    const float* __restrict__ vw, short* __restrict__ qwb,
    short* __restrict__ kwb, short* __restrict__ vwb,
    const float* __restrict__ rpe, unsigned* __restrict__ rpet)
{
    __shared__ float ts[64][65];
    int t = threadIdx.x;
    if (blockIdx.z == 5) {   // RPE pre-pad plane: head = blockIdx.x
        if (blockIdx.y != 0 || blockIdx.x >= 8) return;
        int hh = blockIdx.x;
        const float* rh = rpe + hh * 3969;
        const float L2E = 1.44269504f;
        #pragma unroll
        for (int i = 0; i < 17; ++i) {
            int j = i * 256 + t;
            if (j < 4225) {
                int iy = j / 65;
                int ix = j - iy * 65;
                float v0 = 0.f, v1 = 0.f;
                if (iy >= 1 && iy <= 63) {
                    const float* rr = rh + (iy - 1) * 63;
                    if (ix >= 1 && ix <= 63) v0 = rr[ix - 1] * L2E;
                    if (ix <= 62)            v1 = rr[ix] * L2E;
                }
                h2 pr; pr[0] = (_Float16)v0; pr[1] = (_Float16)v1;
                rpet[hh * 4225 + j] = __builtin_bit_cast(unsigned, pr);
            }
        }
        return;
    }
    if (blockIdx.z == 4) {   // weight cast plane
        int f = blockIdx.y * 16 + blockIdx.x;
        int base = (f * 256 + t) * 8;
        #pragma unroll
        for (int w = 0; w < 3; ++w) {
            const float* src = (w == 0) ? qw : (w == 1) ? kw : vw;
            short* dst = (w == 0) ? qwb : (w == 1) ? kwb : vwb;
            float4 f0 = *(const float4*)(src + base);
            float4 f1 = *(const float4*)(src + base + 4);
            bf16x8 o;
            o[0] = f2bf(f0.x); o[1] = f2bf(f0.y); o[2] = f2bf(f0.z); o[3] = f2bf(f0.w);
            o[4] = f2bf(f1.x); o[5] = f2bf(f1.y); o[6] = f2bf(f1.z); o[7] = f2bf(f1.w);
            *(bf16x8*)(dst + base) = o;
        }
        return;
    }
    int p0 = blockIdx.x * 64, c0 = blockIdx.y * 64, b = blockIdx.z;
    #pragma unroll
    for (int i = 0; i < 16; ++i) {
        int idx = i * 256 + t;
        int cl = idx >> 6, pl = idx & 63;
        ts[cl][pl] = x[((size_t)(b * 512 + c0 + cl)) * 1024 + p0 + pl];
    }
    __syncthreads();
    #pragma unroll
    for (int i = 0; i < 16; ++i) {
        int idx = i * 256 + t;
        int pl = idx >> 6, cl = idx & 63;
        xt[((size_t)(b * 1024 + p0 + pl)) * 512 + c0 + cl] = f2bf(ts[cl][pl]);
    }
}

// ---------------------------------------------------------------------------
// 64x128 NT MFMA tile body (K=512): acc[2][4] per thread; 12 KB LDS.
// waves: wm = m-half (2x32 rows), wn = n-half (2x64 cols)
// ---------------------------------------------------------------------------
__device__ inline void nt_tile_64x128(const short* __restrict__ A,
                                      const short* __restrict__ B,
                                      int m0, int n0, int t,
                                      short (*As)[32], short (*Bs)[32],
                                      f32x4 (&acc)[2][4])
{
    int wid = t >> 6, l = t & 63;
    int wm = wid >> 1, wn = wid & 1;
    int srB = t >> 1, halfB = t & 1;
    int swB = (srB >> 1) & 3;
    int sB0 = (halfB * 2) ^ swB, sB1 = (halfB * 2 + 1) ^ swB;
    int srA = t >> 2, qA = t & 3;
    int sA = qA ^ ((srA >> 1) & 3);
    for (int k0 = 0; k0 < 512; k0 += 32) {
        const int4 a0 = *(const int4*)(A + (size_t)(m0 + srA) * 512 + k0 + qA * 8);
        const int4 b0 = *(const int4*)(B + (size_t)(n0 + srB) * 512 + k0 + halfB * 16);
        const int4 b1 = *(const int4*)(B + (size_t)(n0 + srB) * 512 + k0 + halfB * 16 + 8);
        __syncthreads();
        *(int4*)&As[srA][sA * 8] = a0;
        *(int4*)&Bs[srB][sB0 * 8] = b0;
        *(int4*)&Bs[srB][sB1 * 8] = b1;
        __syncthreads();
        bf16x8 af[2], bfr[4];
        #pragma unroll
        for (int mt = 0; mt < 2; ++mt) {
            int r = wm * 32 + mt * 16 + (l & 15);
            af[mt] = *(const bf16x8*)&As[r][(((l >> 4)) ^ ((r >> 1) & 3)) * 8];
        }
        #pragma unroll
        for (int nt = 0; nt < 4; ++nt) {
            int r = wn * 64 + nt * 16 + (l & 15);
            bfr[nt] = *(const bf16x8*)&Bs[r][(((l >> 4)) ^ ((r >> 1) & 3)) * 8];
        }
        #pragma unroll
        for (int mt = 0; mt < 2; ++mt)
            #pragma unroll
            for (int nt = 0; nt < 4; ++nt)
                acc[mt][nt] = __builtin_amdgcn_mfma_f32_16x16x32_bf16(
                    af[mt], bfr[nt], acc[mt][nt], 0, 0, 0);
    }
}

// q projection (dense [m][n] bf16 out); grid (64, 4) = 256 blocks
__global__ __launch_bounds__(256) void gemm_q(
    const short* __restrict__ A, const short* __restrict__ B,
    const float* __restrict__ bias, short* __restrict__ Ob)
{
    __shared__ short As[64][32];
    __shared__ short Bs[128][32];
    int m0 = blockIdx.x * 64, n0 = blockIdx.y * 128;
    int t = threadIdx.x, wid = t >> 6, l = t & 63;
    int wm = wid >> 1, wn = wid & 1;
    f32x4 acc[2][4] = {};
    nt_tile_64x128(A, B, m0, n0, t, As, Bs, acc);
    #pragma unroll
    for (int mt = 0; mt < 2; ++mt)
        #pragma unroll
        for (int nt = 0; nt < 4; ++nt)
            #pragma unroll
            for (int r = 0; r < 4; ++r) {
                int m = m0 + wm * 32 + mt * 16 + (l >> 4) * 4 + r;
                int n = n0 + wn * 64 + nt * 16 + (l & 15);
                Ob[(size_t)m * 512 + n] = f2bf(acc[mt][nt][r] + bias[n]);
            }
}

// k-gemm (bid<256) + v-gemm (bid>=256); grid 512 = 2 blocks/CU.
// Outputs in MFMA-FRAGMENT ORDER (same layout as round 10):
// kfr[((bh*64+T)*2+frag)*64 + g*16+cs][8] bf16; vfr[((bh*4+wg)*32+cc)*64+g*16+cs][8] f16
__global__ __launch_bounds__(256) void gemm_kv(
    const short* __restrict__ xsb, const short* __restrict__ kwb,
    const float* __restrict__ k_b, short* __restrict__ kfr,
    const short* __restrict__ vwb, const float* __restrict__ v_b,
    short* __restrict__ vfr)
{
    __shared__ short As[64][32];
    __shared__ short Bs[128][32];
    int bid = blockIdx.x;
    int t = threadIdx.x, wid = t >> 6, l = t & 63;
    int wm = wid >> 1, wn = wid & 1;
    f32x4 acc[2][4] = {};
    if (bid < 256) {
        int m0 = (bid >> 2) * 64, n0 = (bid & 3) * 128;
        nt_tile_64x128(xsb, kwb, m0, n0, t, As, Bs, acc);
        #pragma unroll
        for (int mt = 0; mt < 2; ++mt)
            #pragma unroll
            for (int nt = 0; nt < 4; ++nt)
                #pragma unroll
                for (int r = 0; r < 4; ++r) {
                    int m = m0 + wm * 32 + mt * 16 + (l >> 4) * 4 + r;  // sample
                    int n = n0 + wn * 64 + nt * 16 + (l & 15);          // channel
                    int bq = m >> 10, p = m & 1023;
                    int T = p >> 4, cs = p & 15;
                    int h = n >> 6, ch = n & 63;
                    int frag = ch >> 5, gg = (ch >> 3) & 3, e = ch & 7;
                    kfr[((((size_t)(bq * 8 + h) * 64 + T) * 2 + frag) * 64
                         + gg * 16 + cs) * 8 + e] = f2bf(acc[mt][nt][r] + k_b[n]);
                }
    } else {
        int id2 = bid - 256;
        int z = id2 >> 6, rr2 = id2 & 63;
        int m0 = (rr2 >> 3) * 64, n0 = (rr2 & 7) * 128;
        nt_tile_64x128(vwb, xsb + (size_t)z * 524288, m0, n0, t, As, Bs, acc);
        #pragma unroll
        for (int mt = 0; mt < 2; ++mt)
            #pragma unroll
            for (int nt = 0; nt < 4; ++nt)
                #pragma unroll
                for (int r = 0; r < 4; ++r) {
                    int m = m0 + wm * 32 + mt * 16 + (l >> 4) * 4 + r;  // channel
                    int n = n0 + wn * 64 + nt * 16 + (l & 15);          // sample
                    int h = m >> 6, wg = (m & 63) >> 4, cs = m & 15;
                    int cc = n >> 5, gg = (n >> 3) & 3, e = n & 7;
                    _Float16 hv = (_Float16)(acc[mt][nt][r] + v_b[m]);
                    vfr[((((size_t)(z * 8 + h) * 4 + wg) * 32 + cc) * 64
                         + gg * 16 + cs) * 8 + e] = __builtin_bit_cast(short, hv);
                }
    }
}

// ---------------------------------------------------------------------------
// FUSED offset network + deformable sampling
// ---------------------------------------------------------------------------
__global__ __launch_bounds__(256) void offset_sample(
    const short* __restrict__ qbf, const float* __restrict__ dw_w,
    const float* __restrict__ dw_b, const float* __restrict__ ln_w,
    const float* __restrict__ ln_b, const float* __restrict__ pw_w,
    const short* __restrict__ xt, float* __restrict__ pos,
    short* __restrict__ xs)
{
    __shared__ float red[8];
    __shared__ float2 psh;
    int bid = blockIdx.x;
    int b = bid >> 10, p = bid & 1023;
    int y = p >> 5, x = p & 31;
    int t = threadIdx.x;
    int c0 = 2 * t;
    const short* qb = qbf + (size_t)b * 524288;
    float h0, h1;
    {
        const float* w0 = dw_w + c0 * 9;
        const float* w1 = w0 + 9;
        float s0 = 0.f, s1 = 0.f;
        #pragma unroll
        for (int ky = 0; ky < 3; ++ky) {
            int yy = y + ky - 1;
            if (yy < 0 || yy > 31) continue;
            #pragma unroll
            for (int kx = 0; kx < 3; ++kx) {
                int xx = x + kx - 1;
                if (xx < 0 || xx > 31) continue;
                unsigned u = *(const unsigned*)(qb + (size_t)(yy * 32 + xx) * 512 + c0);
                s0 += bf2f((short)(u & 0xFFFF)) * w0[ky * 3 + kx];
                s1 += bf2f((short)(u >> 16)) * w1[ky * 3 + kx];
            }
        }
        float2 db = *(const float2*)(dw_b + c0);
        h0 = s0 + db.x; h1 = s1 + db.y;
    }
    float ls = h0 + h1;
    float lq = h0 * h0 + h1 * h1;
    #pragma unroll
    for (int s = 32; s >= 1; s >>= 1) {
        ls += __shfl_xor(ls, s);
        lq += __shfl_xor(lq, s);
    }
    int wid = t >> 6, lane = t & 63;
    if (lane == 0) { red[wid] = ls; red[4 + wid] = lq; }
    __syncthreads();
    float mu  = (red[0] + red[1] + red[2] + red[3]) * (1.f / 512.f);
    float var = (red[4] + red[5] + red[6] + red[7]) * (1.f / 512.f) - mu * mu;
    float rstd = rsqrtf(var + 1e-5f);
    float o0, o1;
    {
        float2 lw = *(const float2*)(ln_w + c0);
        float2 lb = *(const float2*)(ln_b + c0);
        float2 p0 = *(const float2*)(pw_w + c0);
        float2 p1 = *(const float2*)(pw_w + 512 + c0);
        float hn0 = (h0 - mu) * rstd * lw.x + lb.x;
        float hn1 = (h1 - mu) * rstd * lw.y + lb.y;
        float g0 = 0.5f * hn0 * (1.f + erff(hn0 * 0.70710678118f));
        float g1 = 0.5f * hn1 * (1.f + erff(hn1 * 0.70710678118f));
        o0 = g0 * p0.x + g1 * p0.y;
        o1 = g0 * p1.x + g1 * p1.y;
    }
    #pragma unroll
    for (int s = 32; s >= 1; s >>= 1) {
        o0 += __shfl_xor(o0, s);
        o1 += __shfl_xor(o1, s);
    }
    __syncthreads();
    if (lane == 0) { red[wid] = o0; red[4 + wid] = o1; }
    __syncthreads();
    if (t == 0) {
        float oy = tanhf(red[0] + red[1] + red[2] + red[3]) * 0.0625f;
        float ox = tanhf(red[4] + red[5] + red[6] + red[7]) * 0.0625f;
        float ry = ((y + 0.5f) * (1.f / 32.f)) * 2.f - 1.f;
        float rx = ((x + 0.5f) * (1.f / 32.f)) * 2.f - 1.f;
        float py = oy + ry, px = ox + rx;
        pos[bid * 2]     = py;
        pos[bid * 2 + 1] = px;
        psh = make_float2(py, px);
    }
    __syncthreads();
    float py = psh.x, px = psh.y;
    float gx = (px + 1.f) * 15.5f;
    float gy = (py + 1.f) * 15.5f;
    float x0f = floorf(gx), y0f = floorf(gy);
    int ix0 = (int)x0f, iy0 = (int)y0f;
    float wx1 = gx - x0f, wx0 = 1.f - wx1;
    float wy1 = gy - y0f, wy0 = 1.f - wy1;
    const short* base = xt + (size_t)b * 524288;
    float a0 = 0.f, a1 = 0.f;
    #pragma unroll
    for (int tap = 0; tap < 4; ++tap) {
        int ix = ix0 + (tap & 1), iy = iy0 + (tap >> 1);
        float w = ((tap & 1) ? wx1 : wx0) * ((tap >> 1) ? wy1 : wy0);
        if (ix >= 0 && ix < 32 && iy >= 0 && iy < 32) {
            unsigned u = *(const unsigned*)(base + (size_t)(iy * 32 + ix) * 512 + c0);
            a0 += bf2f((short)(u & 0xFFFF)) * w;
            a1 += bf2f((short)(u >> 16)) * w;
        }
    }
    unsigned o = ((unsigned)(unsigned short)f2bf(a0)) |
                 (((unsigned)(unsigned short)f2bf(a1)) << 16);
    *(unsigned*)(xs + (size_t)bid * 512 + c0) = o;
}

// ---------------------------------------------------------------------------
// FUSED attention, 512 threads, swapped QK^T, FRAGMENT-ORDERED K/V:
// every K/V fragment load = base + lane*16B (one coalesced 1KB wave load).
// RPE staged by linear copy from pre-padded global table.
// grid (64 m-tiles, 8 h, 4 b)
// ---------------------------------------------------------------------------
__global__ __launch_bounds__(512, 4) void attn_fused(
    const short* __restrict__ qbf, const short* __restrict__ kfr,
    const short* __restrict__ vfr, const float* __restrict__ pos,
    const unsigned* __restrict__ rpet, const float* __restrict__ x,
    const float* __restrict__ gamma, float* __restrict__ attn_out,
    float* __restrict__ out0)
{
    __shared__ __align__(16) char smem_raw[33024];   // rpe(16900)+ccs(8192) | Pn 16*1032*2
    __shared__ float S_part[16][8];
    h2*     rpe_s = (h2*)smem_raw;                    // [65*65] pair table (x log2e)
    float2* ccs   = (float2*)(smem_raw + 16960);      // [1024]
    short*  Pn    = (short*)smem_raw;                 // [16][1032] f16 RAW exp

    int m0 = blockIdx.x * 16, h = blockIdx.y, b = blockIdx.z;
    int t = threadIdx.x, wn = t >> 6, l = t & 63;
    int g = l >> 4, c16 = l & 15;
    int bh = b * 8 + h;

    const unsigned* rt = rpet + h * 4225;
    #pragma unroll
    for (int i = 0; i < 9; ++i) {
        int e = i * 512 + t;
        if (e < 4225) ((unsigned*)rpe_s)[e] = rt[e];
    }
    #pragma unroll
    for (int i = 0; i < 2; ++i) {
        int idx = i * 512 + t;
        float2 pf = *(const float2*)(pos + b * 2048 + idx * 2);
        ccs[idx] = make_float2(fmaf(-15.5f, pf.x, 32.f), fmaf(-15.5f, pf.y, 32.f));
    }
    // q fragments (dense layout; only 2 loads/thread)
    int rowm = m0 + c16;
    const short* qrow = qbf + ((size_t)(b * 1024 + rowm) * 512 + h * 64 + g * 8);
    bf16x8 aq0 = *(const bf16x8*)qrow;
    bf16x8 aq1 = *(const bf16x8*)(qrow + 32);
    float qy = (((rowm >> 5) + 0.5f) * (1.f / 16.f) - 1.f) * 15.5f;
    float qx = (((rowm & 31) + 0.5f) * (1.f / 16.f) - 1.f) * 15.5f;
    __syncthreads();

    // ---- pass A: 8 n-tiles; K frags coalesced + register double-buffered
    float Ssum = 0.f;
    float e0, e1;
    unsigned ep[16];
    const short* kr = kfr + (size_t)((bh * 64 + wn * 8)) * 1024;
    bf16x8 nk0 = *(const bf16x8*)(kr + l * 8);
    bf16x8 nk1 = *(const bf16x8*)(kr + 512 + l * 8);
    #pragma unroll
    for (int nt = 0; nt < 8; ++nt) {
        bf16x8 bk0 = nk0, bk1 = nk1;
        if (nt < 7) {
            kr += 1024;
            nk0 = *(const bf16x8*)(kr + l * 8);
            nk1 = *(const bf16x8*)(kr + 512 + l * 8);
        }
        __builtin_amdgcn_s_setprio(1);
        f32x4 acc = {0.f, 0.f, 0.f, 0.f};
        acc = __builtin_amdgcn_mfma_f32_16x16x32_bf16(bk0, aq0, acc, 0, 0, 0);
        acc = __builtin_amdgcn_mfma_f32_16x16x32_bf16(bk1, aq1, acc, 0, 0, 0);
        __builtin_amdgcn_s_setprio(0);
        int nb = wn * 128 + nt * 16;
        #pragma unroll
        for (int r = 0; r < 4; ++r) {
            float2 cc = ccs[nb + g * 4 + r];           // broadcast across c16
            float gyp = qy + cc.x;
            float gxp = qx + cc.y;
            float fy = floorf(gyp), fx = floorf(gxp);
            float wy1 = gyp - fy, wx1 = gxp - fx;
            int ad = (int)(fy * 65.f + fx);
            h2 r0 = rpe_s[ad];
            h2 r1 = rpe_s[ad + 65];
            h2 wp = pkrtz(1.f - wx1, wx1);
            float t0 = dot2(r0, wp);
            float t1 = dot2(r1, wp);
            float bias2 = t0 + wy1 * (t1 - t0);        // already x log2e
            float logit2 = fmaf(acc[r], 0.1803368801f, bias2);  // 0.125*log2e
            float e = fast_exp2(logit2);
            Ssum += e;
            if (r == 0) e0 = e;
            else if (r == 1) ep[nt * 2] = __builtin_bit_cast(unsigned, pkrtz(e0, e));
            else if (r == 2) e1 = e;
            else ep[nt * 2 + 1] = __builtin_bit_cast(unsigned, pkrtz(e1, e));
        }
    }
    Ssum += __shfl_xor(Ssum, 16);
    Ssum += __shfl_xor(Ssum, 32);
    if (l < 16) S_part[c16][wn] = Ssum;
    __syncthreads();   // pass-A LDS reads done; rpe/ccs region dead
    float4 sa = *(const float4*)&S_part[c16][0];
    float4 sb = *(const float4*)&S_part[c16][4];
    float invS = 1.f / (sa.x + sa.y + sa.z + sa.w + sb.x + sb.y + sb.z + sb.w);

    // ---- raw exp pairs -> Pn[m=c16][n]
    short* prow = Pn + c16 * 1032 + wn * 128;
    #pragma unroll
    for (int nt = 0; nt < 8; ++nt) {
        uint2 w;
        w.x = ep[nt * 2];
        w.y = ep[nt * 2 + 1];
        *(uint2*)(prow + nt * 16 + g * 4) = w;
    }
    __syncthreads();

    size_t obase = ((size_t)(bh * 1024 + m0)) * 1024;
    if (wn >= 4) {
        // ---- attn fp32 stream: waves 4-7, scale by invS[row] during convert
        int tw = t - 256;
        #pragma unroll
        for (int row = 0; row < 16; ++row) {
            float ivr = __shfl(invS, row);
            const unsigned* pr = (const unsigned*)(Pn + row * 1032 + tw * 4);
            unsigned u0 = pr[0], u1 = pr[1];
            h2 a = __builtin_bit_cast(h2, u0);
            h2 bb = __builtin_bit_cast(h2, u1);
            float4 vv = make_float4((float)a[0] * ivr, (float)a[1] * ivr,
                                    (float)bb[0] * ivr, (float)bb[1] * ivr);
            *(float4*)(attn_out + obase + (size_t)row * 1024 + tw * 4) = vv;
        }
    } else {
        // ---- PV: wave wn owns channels wn*16..+15; V fragment-ordered
        const short* Vb = vfr + (size_t)((bh * 4 + wn) * 32) * 512;
        const short* Prow = Pn + c16 * 1032 + g * 8;
        f32x4 dacc = {0.f, 0.f, 0.f, 0.f};
        __builtin_amdgcn_s_setprio(1);
        #pragma unroll
        for (int cc = 0; cc < 32; ++cc) {
            f16x8 pa  = *(const f16x8*)(Prow + cc * 32);
            f16x8 vb8 = *(const f16x8*)(Vb + cc * 512 + l * 8);
            dacc = __builtin_amdgcn_mfma_f32_16x16x32_f16(pa, vb8, dacc, 0, 0, 0);
        }
        __builtin_amdgcn_s_setprio(0);
        float gm = gamma[0];
        float gi0 = gm * __shfl(invS, g * 4);
        float gi1 = gm * __shfl(invS, g * 4 + 1);
        float gi2 = gm * __shfl(invS, g * 4 + 2);
        float gi3 = gm * __shfl(invS, g * 4 + 3);
        int ch = h * 64 + wn * 16 + c16;
        int m = m0 + g * 4;
        size_t idx = ((size_t)(b * 512 + ch)) * 1024 + m;
        float4 xv = *(const float4*)(x + idx);
        float4 ov;
        ov.x = gi0 * dacc[0] + xv.x;
        ov.y = gi1 * dacc[1] + xv.y;
        ov.z = gi2 * dacc[2] + xv.z;
        ov.w = gi3 * dacc[3] + xv.w;
        *(float4*)(out0 + idx) = ov;
    }
}

extern "C" void kernel_launch(void* const* d_in, const int* in_sizes, int n_in,
                              void* d_out, int out_size, void* d_ws, size_t ws_size,
                              hipStream_t stream) {
    const float* x     = (const float*)d_in[0];
    const float* dw_w  = (const float*)d_in[1];
    const float* dw_b  = (const float*)d_in[2];
    const float* ln_w  = (const float*)d_in[3];
    const float* ln_b  = (const float*)d_in[4];
    const float* pw_w  = (const float*)d_in[5];
    const float* q_w   = (const float*)d_in[6];
    const float* q_b   = (const float*)d_in[7];
    const float* k_w   = (const float*)d_in[8];
    const float* k_b   = (const float*)d_in[9];
    const float* v_w   = (const float*)d_in[10];
    const float* v_b   = (const float*)d_in[11];
    const float* rpe   = (const float*)d_in[12];
    const float* gamma = (const float*)d_in[13];

    float* out0 = (float*)d_out;
    float* attn = out0 + (size_t)4 * 512 * 1024;

    char* w = (char*)d_ws;
    short*    xt   = (short*)w;                    // 4 MB
    short*    qwb  = (short*)(w + 4194304);
    short*    kwb  = (short*)(w + 4718592);
    short*    vwb  = (short*)(w + 5242880);
    short*    qbf  = (short*)(w + 5767168);        // 4 MB dense q
    short*    xsb  = (short*)(w + 9961472);        // 4 MB
    short*    kfr  = (short*)(w + 14155776);       // 4 MB frag-ordered K
    short*    vfr  = (short*)(w + 18350080);       // 4 MB frag-ordered V (f16)
    float*    pos  = (float*)(w + 22544384);       // 32 KB
    unsigned* rpet = (unsigned*)(w + 22577152);    // 8*4225*4 = 135 KB

    prep_x<<<dim3(16, 8, 6), 256, 0, stream>>>(x, xt, q_w, k_w, v_w, qwb, kwb,
                                               vwb, rpe, rpet);
    gemm_q<<<dim3(64, 4), 256, 0, stream>>>(xt, qwb, q_b, qbf);
    offset_sample<<<4096, 256, 0, stream>>>(qbf, dw_w, dw_b, ln_w, ln_b, pw_w,
                                            xt, pos, xsb);
    gemm_kv<<<512, 256, 0, stream>>>(xsb, kwb, k_b, kfr, vwb, v_b, vfr);
    attn_fused<<<dim3(64, 8, 4), 512, 0, stream>>>(qbf, kfr, vfr, pos, rpet, x,
                                                   gamma, attn, out0);
}

// Round 13
// 110.656 us; speedup vs baseline: 3.9870x; 1.0211x over previous
//
#include <hip/hip_runtime.h>
#include <hip/hip_bf16.h>
#include <math.h>

typedef short bf16x8 __attribute__((ext_vector_type(8)));
typedef _Float16 f16x8 __attribute__((ext_vector_type(8)));
typedef float f32x4 __attribute__((ext_vector_type(4)));
typedef _Float16 h2 __attribute__((ext_vector_type(2)));

__device__ inline short f2bf(float f) {
    union { float f; unsigned u; } v; v.f = f;
    unsigned r = v.u + 0x7FFFu + ((v.u >> 16) & 1u);
    return (short)(r >> 16);
}
__device__ inline float bf2f(short s) {
    union { unsigned u; float f; } v; v.u = ((unsigned)(unsigned short)s) << 16;
    return v.f;
}
__device__ inline h2 pkrtz(float a, float b) {
    return __builtin_bit_cast(h2, __builtin_amdgcn_cvt_pkrtz(a, b));
}
__device__ inline float fast_exp2(float x) {
    float r;
    asm("v_exp_f32 %0, %1" : "=v"(r) : "v"(x));
    return r;
}
__device__ inline float dot2(h2 a, h2 b) {
#if __has_builtin(__builtin_amdgcn_fdot2)
    return __builtin_amdgcn_fdot2(a, b, 0.f, false);
#else
    return (float)a[0] * (float)b[0] + (float)a[1] * (float)b[1];
#endif
}
__device__ inline void nt_store4(float4 v, float* p) {
    __builtin_nontemporal_store(__builtin_bit_cast(f32x4, v), (f32x4*)p);
}

// ---------------------------------------------------------------------------
// z<4: transpose-cast x -> xt [b][p][c] bf16.  z==4: weight cast.
// z==5 (x<8,y==0): build padded 65x65 RPE pair-table (x log2e) per head.
// ---------------------------------------------------------------------------
__global__ __launch_bounds__(256) void prep_x(
    const float* __restrict__ x, short* __restrict__ xt,
    const float* __restrict__ qw, const float* __restrict__ kw,
    const float* __restrict__ vw, short* __restrict__ qwb,
    short* __restrict__ kwb, short* __restrict__ vwb,
    const float* __restrict__ rpe, unsigned* __restrict__ rpet)
{
    __shared__ float ts[64][65];
    int t = threadIdx.x;
    if (blockIdx.z == 5) {   // RPE pre-pad plane: head = blockIdx.x
        if (blockIdx.y != 0 || blockIdx.x >= 8) return;
        int hh = blockIdx.x;
        const float* rh = rpe + hh * 3969;
        const float L2E = 1.44269504f;
        #pragma unroll
        for (int i = 0; i < 17; ++i) {
            int j = i * 256 + t;
            if (j < 4225) {
                int iy = j / 65;
                int ix = j - iy * 65;
                float v0 = 0.f, v1 = 0.f;
                if (iy >= 1 && iy <= 63) {
                    const float* rr = rh + (iy - 1) * 63;
                    if (ix >= 1 && ix <= 63) v0 = rr[ix - 1] * L2E;
                    if (ix <= 62)            v1 = rr[ix] * L2E;
                }
                h2 pr; pr[0] = (_Float16)v0; pr[1] = (_Float16)v1;
                rpet[hh * 4225 + j] = __builtin_bit_cast(unsigned, pr);
            }
        }
        return;
    }
    if (blockIdx.z == 4) {   // weight cast plane
        int f = blockIdx.y * 16 + blockIdx.x;
        int base = (f * 256 + t) * 8;
        #pragma unroll
        for (int w = 0; w < 3; ++w) {
            const float* src = (w == 0) ? qw : (w == 1) ? kw : vw;
            short* dst = (w == 0) ? qwb : (w == 1) ? kwb : vwb;
            float4 f0 = *(const float4*)(src + base);
            float4 f1 = *(const float4*)(src + base + 4);
            bf16x8 o;
            o[0] = f2bf(f0.x); o[1] = f2bf(f0.y); o[2] = f2bf(f0.z); o[3] = f2bf(f0.w);
            o[4] = f2bf(f1.x); o[5] = f2bf(f1.y); o[6] = f2bf(f1.z); o[7] = f2bf(f1.w);
            *(bf16x8*)(dst + base) = o;
        }
        return;
    }
    int p0 = blockIdx.x * 64, c0 = blockIdx.y * 64, b = blockIdx.z;
    #pragma unroll
    for (int i = 0; i < 16; ++i) {
        int idx = i * 256 + t;
        int cl = idx >> 6, pl = idx & 63;
        ts[cl][pl] = x[((size_t)(b * 512 + c0 + cl)) * 1024 + p0 + pl];
    }
    __syncthreads();
    #pragma unroll
    for (int i = 0; i < 16; ++i) {
        int idx = i * 256 + t;
        int pl = idx >> 6, cl = idx & 63;
        xt[((size_t)(b * 1024 + p0 + pl)) * 512 + c0 + cl] = f2bf(ts[cl][pl]);
    }
}

// ---------------------------------------------------------------------------
// 64x128 NT MFMA tile body (K=512): acc[2][4] per thread; 12 KB LDS.
// ---------------------------------------------------------------------------
__device__ inline void nt_tile_64x128(const short* __restrict__ A,
                                      const short* __restrict__ B,
                                      int m0, int n0, int t,
                                      short (*As)[32], short (*Bs)[32],
                                      f32x4 (&acc)[2][4])
{
    int wid = t >> 6, l = t & 63;
    int wm = wid >> 1, wn = wid & 1;
    int srB = t >> 1, halfB = t & 1;
    int swB = (srB >> 1) & 3;
    int sB0 = (halfB * 2) ^ swB, sB1 = (halfB * 2 + 1) ^ swB;
    int srA = t >> 2, qA = t & 3;
    int sA = qA ^ ((srA >> 1) & 3);
    for (int k0 = 0; k0 < 512; k0 += 32) {
        const int4 a0 = *(const int4*)(A + (size_t)(m0 + srA) * 512 + k0 + qA * 8);
        const int4 b0 = *(const int4*)(B + (size_t)(n0 + srB) * 512 + k0 + halfB * 16);
        const int4 b1 = *(const int4*)(B + (size_t)(n0 + srB) * 512 + k0 + halfB * 16 + 8);
        __syncthreads();
        *(int4*)&As[srA][sA * 8] = a0;
        *(int4*)&Bs[srB][sB0 * 8] = b0;
        *(int4*)&Bs[srB][sB1 * 8] = b1;
        __syncthreads();
        bf16x8 af[2], bfr[4];
        #pragma unroll
        for (int mt = 0; mt < 2; ++mt) {
            int r = wm * 32 + mt * 16 + (l & 15);
            af[mt] = *(const bf16x8*)&As[r][(((l >> 4)) ^ ((r >> 1) & 3)) * 8];
        }
        #pragma unroll
        for (int nt = 0; nt < 4; ++nt) {
            int r = wn * 64 + nt * 16 + (l & 15);
            bfr[nt] = *(const bf16x8*)&Bs[r][(((l >> 4)) ^ ((r >> 1) & 3)) * 8];
        }
        #pragma unroll
        for (int mt = 0; mt < 2; ++mt)
            #pragma unroll
            for (int nt = 0; nt < 4; ++nt)
                acc[mt][nt] = __builtin_amdgcn_mfma_f32_16x16x32_bf16(
                    af[mt], bfr[nt], acc[mt][nt], 0, 0, 0);
    }
}

// q projection (dense [m][n] bf16 out); grid (64, 4) = 256 blocks
__global__ __launch_bounds__(256) void gemm_q(
    const short* __restrict__ A, const short* __restrict__ B,
    const float* __restrict__ bias, short* __restrict__ Ob)
{
    __shared__ short As[64][32];
    __shared__ short Bs[128][32];
    int m0 = blockIdx.x * 64, n0 = blockIdx.y * 128;
    int t = threadIdx.x, wid = t >> 6, l = t & 63;
    int wm = wid >> 1, wn = wid & 1;
    f32x4 acc[2][4] = {};
    nt_tile_64x128(A, B, m0, n0, t, As, Bs, acc);
    #pragma unroll
    for (int mt = 0; mt < 2; ++mt)
        #pragma unroll
        for (int nt = 0; nt < 4; ++nt)
            #pragma unroll
            for (int r = 0; r < 4; ++r) {
                int m = m0 + wm * 32 + mt * 16 + (l >> 4) * 4 + r;
                int n = n0 + wn * 64 + nt * 16 + (l & 15);
                Ob[(size_t)m * 512 + n] = f2bf(acc[mt][nt][r] + bias[n]);
            }
}

// k-gemm (bid<256) + v-gemm (bid>=256); grid 512 = 2 blocks/CU.
// Outputs in MFMA-FRAGMENT ORDER:
// kfr[((bh*64+T)*2+frag)*64 + g*16+cs][8] bf16; vfr[((bh*4+wg)*32+cc)*64+g*16+cs][8] f16
__global__ __launch_bounds__(256) void gemm_kv(
    const short* __restrict__ xsb, const short* __restrict__ kwb,
    const float* __restrict__ k_b, short* __restrict__ kfr,
    const short* __restrict__ vwb, const float* __restrict__ v_b,
    short* __restrict__ vfr)
{
    __shared__ short As[64][32];
    __shared__ short Bs[128][32];
    int bid = blockIdx.x;
    int t = threadIdx.x, wid = t >> 6, l = t & 63;
    int wm = wid >> 1, wn = wid & 1;
    f32x4 acc[2][4] = {};
    if (bid < 256) {
        int m0 = (bid >> 2) * 64, n0 = (bid & 3) * 128;
        nt_tile_64x128(xsb, kwb, m0, n0, t, As, Bs, acc);
        #pragma unroll
        for (int mt = 0; mt < 2; ++mt)
            #pragma unroll
            for (int nt = 0; nt < 4; ++nt)
                #pragma unroll
                for (int r = 0; r < 4; ++r) {
                    int m = m0 + wm * 32 + mt * 16 + (l >> 4) * 4 + r;  // sample
                    int n = n0 + wn * 64 + nt * 16 + (l & 15);          // channel
                    int bq = m >> 10, p = m & 1023;
                    int T = p >> 4, cs = p & 15;
                    int h = n >> 6, ch = n & 63;
                    int frag = ch >> 5, gg = (ch >> 3) & 3, e = ch & 7;
                    kfr[((((size_t)(bq * 8 + h) * 64 + T) * 2 + frag) * 64
                         + gg * 16 + cs) * 8 + e] = f2bf(acc[mt][nt][r] + k_b[n]);
                }
    } else {
        int id2 = bid - 256;
        int z = id2 >> 6, rr2 = id2 & 63;
        int m0 = (rr2 >> 3) * 64, n0 = (rr2 & 7) * 128;
        nt_tile_64x128(vwb, xsb + (size_t)z * 524288, m0, n0, t, As, Bs, acc);
        #pragma unroll
        for (int mt = 0; mt < 2; ++mt)
            #pragma unroll
            for (int nt = 0; nt < 4; ++nt)
                #pragma unroll
                for (int r = 0; r < 4; ++r) {
                    int m = m0 + wm * 32 + mt * 16 + (l >> 4) * 4 + r;  // channel
                    int n = n0 + wn * 64 + nt * 16 + (l & 15);          // sample
                    int h = m >> 6, wg = (m & 63) >> 4, cs = m & 15;
                    int cc = n >> 5, gg = (n >> 3) & 3, e = n & 7;
                    _Float16 hv = (_Float16)(acc[mt][nt][r] + v_b[m]);
                    vfr[((((size_t)(z * 8 + h) * 4 + wg) * 32 + cc) * 64
                         + gg * 16 + cs) * 8 + e] = __builtin_bit_cast(short, hv);
                }
    }
}

// ---------------------------------------------------------------------------
// FUSED offset network + deformable sampling
// ---------------------------------------------------------------------------
__global__ __launch_bounds__(256) void offset_sample(
    const short* __restrict__ qbf, const float* __restrict__ dw_w,
    const float* __restrict__ dw_b, const float* __restrict__ ln_w,
    const float* __restrict__ ln_b, const float* __restrict__ pw_w,
    const short* __restrict__ xt, float* __restrict__ pos,
    short* __restrict__ xs)
{
    __shared__ float red[8];
    __shared__ float2 psh;
    int bid = blockIdx.x;
    int b = bid >> 10, p = bid & 1023;
    int y = p >> 5, x = p & 31;
    int t = threadIdx.x;
    int c0 = 2 * t;
    const short* qb = qbf + (size_t)b * 524288;
    float h0, h1;
    {
        const float* w0 = dw_w + c0 * 9;
        const float* w1 = w0 + 9;
        float s0 = 0.f, s1 = 0.f;
        #pragma unroll
        for (int ky = 0; ky < 3; ++ky) {
            int yy = y + ky - 1;
            if (yy < 0 || yy > 31) continue;
            #pragma unroll
            for (int kx = 0; kx < 3; ++kx) {
                int xx = x + kx - 1;
                if (xx < 0 || xx > 31) continue;
                unsigned u = *(const unsigned*)(qb + (size_t)(yy * 32 + xx) * 512 + c0);
                s0 += bf2f((short)(u & 0xFFFF)) * w0[ky * 3 + kx];
                s1 += bf2f((short)(u >> 16)) * w1[ky * 3 + kx];
            }
        }
        float2 db = *(const float2*)(dw_b + c0);
        h0 = s0 + db.x; h1 = s1 + db.y;
    }
    float ls = h0 + h1;
    float lq = h0 * h0 + h1 * h1;
    #pragma unroll
    for (int s = 32; s >= 1; s >>= 1) {
        ls += __shfl_xor(ls, s);
        lq += __shfl_xor(lq, s);
    }
    int wid = t >> 6, lane = t & 63;
    if (lane == 0) { red[wid] = ls; red[4 + wid] = lq; }
    __syncthreads();
    float mu  = (red[0] + red[1] + red[2] + red[3]) * (1.f / 512.f);
    float var = (red[4] + red[5] + red[6] + red[7]) * (1.f / 512.f) - mu * mu;
    float rstd = rsqrtf(var + 1e-5f);
    float o0, o1;
    {
        float2 lw = *(const float2*)(ln_w + c0);
        float2 lb = *(const float2*)(ln_b + c0);
        float2 p0 = *(const float2*)(pw_w + c0);
        float2 p1 = *(const float2*)(pw_w + 512 + c0);
        float hn0 = (h0 - mu) * rstd * lw.x + lb.x;
        float hn1 = (h1 - mu) * rstd * lw.y + lb.y;
        float g0 = 0.5f * hn0 * (1.f + erff(hn0 * 0.70710678118f));
        float g1 = 0.5f * hn1 * (1.f + erff(hn1 * 0.70710678118f));
        o0 = g0 * p0.x + g1 * p0.y;
        o1 = g0 * p1.x + g1 * p1.y;
    }
    #pragma unroll
    for (int s = 32; s >= 1; s >>= 1) {
        o0 += __shfl_xor(o0, s);
        o1 += __shfl_xor(o1, s);
    }
    __syncthreads();
    if (lane == 0) { red[wid] = o0; red[4 + wid] = o1; }
    __syncthreads();
    if (t == 0) {
        float oy = tanhf(red[0] + red[1] + red[2] + red[3]) * 0.0625f;
        float ox = tanhf(red[4] + red[5] + red[6] + red[7]) * 0.0625f;
        float ry = ((y + 0.5f) * (1.f / 32.f)) * 2.f - 1.f;
        float rx = ((x + 0.5f) * (1.f / 32.f)) * 2.f - 1.f;
        float py = oy + ry, px = ox + rx;
        pos[bid * 2]     = py;
        pos[bid * 2 + 1] = px;
        psh = make_float2(py, px);
    }
    __syncthreads();
    float py = psh.x, px = psh.y;
    float gx = (px + 1.f) * 15.5f;
    float gy = (py + 1.f) * 15.5f;
    float x0f = floorf(gx), y0f = floorf(gy);
    int ix0 = (int)x0f, iy0 = (int)y0f;
    float wx1 = gx - x0f, wx0 = 1.f - wx1;
    float wy1 = gy - y0f, wy0 = 1.f - wy1;
    const short* base = xt + (size_t)b * 524288;
    float a0 = 0.f, a1 = 0.f;
    #pragma unroll
    for (int tap = 0; tap < 4; ++tap) {
        int ix = ix0 + (tap & 1), iy = iy0 + (tap >> 1);
        float w = ((tap & 1) ? wx1 : wx0) * ((tap >> 1) ? wy1 : wy0);
        if (ix >= 0 && ix < 32 && iy >= 0 && iy < 32) {
            unsigned u = *(const unsigned*)(base + (size_t)(iy * 32 + ix) * 512 + c0);
            a0 += bf2f((short)(u & 0xFFFF)) * w;
            a1 += bf2f((short)(u >> 16)) * w;
        }
    }
    unsigned o = ((unsigned)(unsigned short)f2bf(a0)) |
                 (((unsigned)(unsigned short)f2bf(a1)) << 16);
    *(unsigned*)(xs + (size_t)bid * 512 + c0) = o;
}

// ---------------------------------------------------------------------------
// FUSED attention, 512 threads, swapped QK^T, FRAGMENT-ORDERED K/V.
// 1D grid 2048 with XCD-pinned mapping: xcd = bid&7 serves ONLY head h=xcd
// (4 batches x 64 m-tiles) -> its K/V+rpe working set (~1.1 MB) stays
// L2-resident. attn/out stores are NONTEMPORAL (never re-read; keep L2
// clean for K/V).
// ---------------------------------------------------------------------------
__global__ __launch_bounds__(512, 4) void attn_fused(
    const short* __restrict__ qbf, const short* __restrict__ kfr,
    const short* __restrict__ vfr, const float* __restrict__ pos,
    const unsigned* __restrict__ rpet, const float* __restrict__ x,
    const float* __restrict__ gamma, float* __restrict__ attn_out,
    float* __restrict__ out0)
{
    __shared__ __align__(16) char smem_raw[33024];   // rpe(16900)+ccs(8192) | Pn 16*1032*2
    __shared__ float S_part[16][8];
    h2*     rpe_s = (h2*)smem_raw;                    // [65*65] pair table (x log2e)
    float2* ccs   = (float2*)(smem_raw + 16960);      // [1024]
    short*  Pn    = (short*)smem_raw;                 // [16][1032] f16 RAW exp

    int bid = blockIdx.x;
    int xcd = bid & 7, seq = bid >> 3;
    int m0 = (seq & 63) * 16;
    int bh = xcd + 8 * (seq >> 6);          // h = bh & 7 == xcd
    int b = bh >> 3, h = bh & 7;
    int t = threadIdx.x, wn = t >> 6, l = t & 63;
    int g = l >> 4, c16 = l & 15;

    const unsigned* rt = rpet + h * 4225;
    #pragma unroll
    for (int i = 0; i < 9; ++i) {
        int e = i * 512 + t;
        if (e < 4225) ((unsigned*)rpe_s)[e] = rt[e];
    }
    #pragma unroll
    for (int i = 0; i < 2; ++i) {
        int idx = i * 512 + t;
        float2 pf = *(const float2*)(pos + b * 2048 + idx * 2);
        ccs[idx] = make_float2(fmaf(-15.5f, pf.x, 32.f), fmaf(-15.5f, pf.y, 32.f));
    }
    // q fragments (dense layout; only 2 loads/thread)
    int rowm = m0 + c16;
    const short* qrow = qbf + ((size_t)(b * 1024 + rowm) * 512 + h * 64 + g * 8);
    bf16x8 aq0 = *(const bf16x8*)qrow;
    bf16x8 aq1 = *(const bf16x8*)(qrow + 32);
    float qy = (((rowm >> 5) + 0.5f) * (1.f / 16.f) - 1.f) * 15.5f;
    float qx = (((rowm & 31) + 0.5f) * (1.f / 16.f) - 1.f) * 15.5f;
    __syncthreads();

    // ---- pass A: 8 n-tiles; K frags coalesced + register double-buffered
    float Ssum = 0.f;
    float e0, e1;
    unsigned ep[16];
    const short* kr = kfr + (size_t)((bh * 64 + wn * 8)) * 1024;
    bf16x8 nk0 = *(const bf16x8*)(kr + l * 8);
    bf16x8 nk1 = *(const bf16x8*)(kr + 512 + l * 8);
    #pragma unroll
    for (int nt = 0; nt < 8; ++nt) {
        bf16x8 bk0 = nk0, bk1 = nk1;
        if (nt < 7) {
            kr += 1024;
            nk0 = *(const bf16x8*)(kr + l * 8);
            nk1 = *(const bf16x8*)(kr + 512 + l * 8);
        }
        __builtin_amdgcn_s_setprio(1);
        f32x4 acc = {0.f, 0.f, 0.f, 0.f};
        acc = __builtin_amdgcn_mfma_f32_16x16x32_bf16(bk0, aq0, acc, 0, 0, 0);
        acc = __builtin_amdgcn_mfma_f32_16x16x32_bf16(bk1, aq1, acc, 0, 0, 0);
        __builtin_amdgcn_s_setprio(0);
        int nb = wn * 128 + nt * 16;
        #pragma unroll
        for (int r = 0; r < 4; ++r) {
            float2 cc = ccs[nb + g * 4 + r];           // broadcast across c16
            float gyp = qy + cc.x;
            float gxp = qx + cc.y;
            float fy = floorf(gyp), fx = floorf(gxp);
            float wy1 = gyp - fy, wx1 = gxp - fx;
            int ad = (int)(fy * 65.f + fx);
            h2 r0 = rpe_s[ad];
            h2 r1 = rpe_s[ad + 65];
            h2 wp = pkrtz(1.f - wx1, wx1);
            float t0 = dot2(r0, wp);
            float t1 = dot2(r1, wp);
            float bias2 = t0 + wy1 * (t1 - t0);        // already x log2e
            float logit2 = fmaf(acc[r], 0.1803368801f, bias2);  // 0.125*log2e
            float e = fast_exp2(logit2);
            Ssum += e;
            if (r == 0) e0 = e;
            else if (r == 1) ep[nt * 2] = __builtin_bit_cast(unsigned, pkrtz(e0, e));
            else if (r == 2) e1 = e;
            else ep[nt * 2 + 1] = __builtin_bit_cast(unsigned, pkrtz(e1, e));
        }
    }
    Ssum += __shfl_xor(Ssum, 16);
    Ssum += __shfl_xor(Ssum, 32);
    if (l < 16) S_part[c16][wn] = Ssum;
    __syncthreads();   // pass-A LDS reads done; rpe/ccs region dead
    float4 sa = *(const float4*)&S_part[c16][0];
    float4 sb = *(const float4*)&S_part[c16][4];
    float invS = 1.f / (sa.x + sa.y + sa.z + sa.w + sb.x + sb.y + sb.z + sb.w);

    // ---- raw exp pairs -> Pn[m=c16][n]
    short* prow = Pn + c16 * 1032 + wn * 128;
    #pragma unroll
    for (int nt = 0; nt < 8; ++nt) {
        uint2 w;
        w.x = ep[nt * 2];
        w.y = ep[nt * 2 + 1];
        *(uint2*)(prow + nt * 16 + g * 4) = w;
    }
    __syncthreads();

    size_t obase = ((size_t)(bh * 1024 + m0)) * 1024;
    if (wn >= 4) {
        // ---- attn fp32 stream: waves 4-7, nontemporal float4 stores
        int tw = t - 256;
        #pragma unroll
        for (int row = 0; row < 16; ++row) {
            float ivr = __shfl(invS, row);
            const unsigned* pr = (const unsigned*)(Pn + row * 1032 + tw * 4);
            unsigned u0 = pr[0], u1 = pr[1];
            h2 a = __builtin_bit_cast(h2, u0);
            h2 bb = __builtin_bit_cast(h2, u1);
            float4 vv = make_float4((float)a[0] * ivr, (float)a[1] * ivr,
                                    (float)bb[0] * ivr, (float)bb[1] * ivr);
            nt_store4(vv, attn_out + obase + (size_t)row * 1024 + tw * 4);
        }
    } else {
        // ---- PV: wave wn owns channels wn*16..+15; V fragment-ordered
        const short* Vb = vfr + (size_t)((bh * 4 + wn) * 32) * 512;
        const short* Prow = Pn + c16 * 1032 + g * 8;
        f32x4 dacc = {0.f, 0.f, 0.f, 0.f};
        __builtin_amdgcn_s_setprio(1);
        #pragma unroll
        for (int cc = 0; cc < 32; ++cc) {
            f16x8 pa  = *(const f16x8*)(Prow + cc * 32);
            f16x8 vb8 = *(const f16x8*)(Vb + cc * 512 + l * 8);
            dacc = __builtin_amdgcn_mfma_f32_16x16x32_f16(pa, vb8, dacc, 0, 0, 0);
        }
        __builtin_amdgcn_s_setprio(0);
        float gm = gamma[0];
        float gi0 = gm * __shfl(invS, g * 4);
        float gi1 = gm * __shfl(invS, g * 4 + 1);
        float gi2 = gm * __shfl(invS, g * 4 + 2);
        float gi3 = gm * __shfl(invS, g * 4 + 3);
        int ch = h * 64 + wn * 16 + c16;
        int m = m0 + g * 4;
        size_t idx = ((size_t)(b * 512 + ch)) * 1024 + m;
        float4 xv = *(const float4*)(x + idx);
        float4 ov;
        ov.x = gi0 * dacc[0] + xv.x;
        ov.y = gi1 * dacc[1] + xv.y;
        ov.z = gi2 * dacc[2] + xv.z;
        ov.w = gi3 * dacc[3] + xv.w;
        nt_store4(ov, out0 + idx);
    }
}

extern "C" void kernel_launch(void* const* d_in, const int* in_sizes, int n_in,
                              void* d_out, int out_size, void* d_ws, size_t ws_size,
                              hipStream_t stream) {
    const float* x     = (const float*)d_in[0];
    const float* dw_w  = (const float*)d_in[1];
    const float* dw_b  = (const float*)d_in[2];
    const float* ln_w  = (const float*)d_in[3];
    const float* ln_b  = (const float*)d_in[4];
    const float* pw_w  = (const float*)d_in[5];
    const float* q_w   = (const float*)d_in[6];
    const float* q_b   = (const float*)d_in[7];
    const float* k_w   = (const float*)d_in[8];
    const float* k_b   = (const float*)d_in[9];
    const float* v_w   = (const float*)d_in[10];
    const float* v_b   = (const float*)d_in[11];
    const float* rpe   = (const float*)d_in[12];
    const float* gamma = (const float*)d_in[13];

    float* out0 = (float*)d_out;
    float* attn = out0 + (size_t)4 * 512 * 1024;

    char* w = (char*)d_ws;
    short*    xt   = (short*)w;                    // 4 MB
    short*    qwb  = (short*)(w + 4194304);
    short*    kwb  = (short*)(w + 4718592);
    short*    vwb  = (short*)(w + 5242880);
    short*    qbf  = (short*)(w + 5767168);        // 4 MB dense q
    short*    xsb  = (short*)(w + 9961472);        // 4 MB
    short*    kfr  = (short*)(w + 14155776);       // 4 MB frag-ordered K
    short*    vfr  = (short*)(w + 18350080);       // 4 MB frag-ordered V (f16)
    float*    pos  = (float*)(w + 22544384);       // 32 KB
    unsigned* rpet = (unsigned*)(w + 22577152);    // 8*4225*4 = 135 KB

    prep_x<<<dim3(16, 8, 6), 256, 0, stream>>>(x, xt, q_w, k_w, v_w, qwb, kwb,
                                               vwb, rpe, rpet);
    gemm_q<<<dim3(64, 4), 256, 0, stream>>>(xt, qwb, q_b, qbf);
    offset_sample<<<4096, 256, 0, stream>>>(qbf, dw_w, dw_b, ln_w, ln_b, pw_w,
                                            xt, pos, xsb);
    gemm_kv<<<512, 256, 0, stream>>>(xsb, kwb, k_b, kfr, vwb, v_b, vfr);
    attn_fused<<<2048, 512, 0, stream>>>(qbf, kfr, vfr, pos, rpet, x,
                                         gamma, attn, out0);
}

// Round 14
// 109.199 us; speedup vs baseline: 4.0402x; 1.0133x over previous
//
#include <hip/hip_runtime.h>
#include <hip/hip_bf16.h>
#include <math.h>

typedef short bf16x8 __attribute__((ext_vector_type(8)));
typedef _Float16 f16x8 __attribute__((ext_vector_type(8)));
typedef float f32x4 __attribute__((ext_vector_type(4)));
typedef _Float16 h2 __attribute__((ext_vector_type(2)));

__device__ inline short f2bf(float f) {
    union { float f; unsigned u; } v; v.f = f;
    unsigned r = v.u + 0x7FFFu + ((v.u >> 16) & 1u);
    return (short)(r >> 16);
}
__device__ inline float bf2f(short s) {
    union { unsigned u; float f; } v; v.u = ((unsigned)(unsigned short)s) << 16;
    return v.f;
}
__device__ inline h2 pkrtz(float a, float b) {
    return __builtin_bit_cast(h2, __builtin_amdgcn_cvt_pkrtz(a, b));
}
__device__ inline float fast_exp2(float x) {
    float r;
    asm("v_exp_f32 %0, %1" : "=v"(r) : "v"(x));
    return r;
}
__device__ inline float dot2(h2 a, h2 b) {
#if __has_builtin(__builtin_amdgcn_fdot2)
    return __builtin_amdgcn_fdot2(a, b, 0.f, false);
#else
    return (float)a[0] * (float)b[0] + (float)a[1] * (float)b[1];
#endif
}
__device__ inline void nt_store4(float4 v, float* p) {
    __builtin_nontemporal_store(__builtin_bit_cast(f32x4, v), (f32x4*)p);
}

// ---------------------------------------------------------------------------
// z<4: transpose-cast x -> xt [b][p][c] bf16.  z==4: weight cast.
// z==5 (x<8,y==0): build padded 65x65 RPE pair-table (x log2e) per head.
// ---------------------------------------------------------------------------
__global__ __launch_bounds__(256) void prep_x(
    const float* __restrict__ x, short* __restrict__ xt,
    const float* __restrict__ qw, const float* __restrict__ kw,
    const float* __restrict__ vw, short* __restrict__ qwb,
    short* __restrict__ kwb, short* __restrict__ vwb,
    const float* __restrict__ rpe, unsigned* __restrict__ rpet)
{
    __shared__ float ts[64][65];
    int t = threadIdx.x;
    if (blockIdx.z == 5) {   // RPE pre-pad plane: head = blockIdx.x
        if (blockIdx.y != 0 || blockIdx.x >= 8) return;
        int hh = blockIdx.x;
        const float* rh = rpe + hh * 3969;
        const float L2E = 1.44269504f;
        #pragma unroll
        for (int i = 0; i < 17; ++i) {
            int j = i * 256 + t;
            if (j < 4225) {
                int iy = j / 65;
                int ix = j - iy * 65;
                float v0 = 0.f, v1 = 0.f;
                if (iy >= 1 && iy <= 63) {
                    const float* rr = rh + (iy - 1) * 63;
                    if (ix >= 1 && ix <= 63) v0 = rr[ix - 1] * L2E;
                    if (ix <= 62)            v1 = rr[ix] * L2E;
                }
                h2 pr; pr[0] = (_Float16)v0; pr[1] = (_Float16)v1;
                rpet[hh * 4225 + j] = __builtin_bit_cast(unsigned, pr);
            }
        }
        return;
    }
    if (blockIdx.z == 4) {   // weight cast plane
        int f = blockIdx.y * 16 + blockIdx.x;
        int base = (f * 256 + t) * 8;
        #pragma unroll
        for (int w = 0; w < 3; ++w) {
            const float* src = (w == 0) ? qw : (w == 1) ? kw : vw;
            short* dst = (w == 0) ? qwb : (w == 1) ? kwb : vwb;
            float4 f0 = *(const float4*)(src + base);
            float4 f1 = *(const float4*)(src + base + 4);
            bf16x8 o;
            o[0] = f2bf(f0.x); o[1] = f2bf(f0.y); o[2] = f2bf(f0.z); o[3] = f2bf(f0.w);
            o[4] = f2bf(f1.x); o[5] = f2bf(f1.y); o[6] = f2bf(f1.z); o[7] = f2bf(f1.w);
            *(bf16x8*)(dst + base) = o;
        }
        return;
    }
    int p0 = blockIdx.x * 64, c0 = blockIdx.y * 64, b = blockIdx.z;
    #pragma unroll
    for (int i = 0; i < 16; ++i) {
        int idx = i * 256 + t;
        int cl = idx >> 6, pl = idx & 63;
        ts[cl][pl] = x[((size_t)(b * 512 + c0 + cl)) * 1024 + p0 + pl];
    }
    __syncthreads();
    #pragma unroll
    for (int i = 0; i < 16; ++i) {
        int idx = i * 256 + t;
        int pl = idx >> 6, cl = idx & 63;
        xt[((size_t)(b * 1024 + p0 + pl)) * 512 + c0 + cl] = f2bf(ts[cl][pl]);
    }
}

// ---------------------------------------------------------------------------
// 64x128 NT MFMA tile body (K=512): acc[2][4] per thread; 12 KB LDS.
// ---------------------------------------------------------------------------
__device__ inline void nt_tile_64x128(const short* __restrict__ A,
                                      const short* __restrict__ B,
                                      int m0, int n0, int t,
                                      short (*As)[32], short (*Bs)[32],
                                      f32x4 (&acc)[2][4])
{
    int wid = t >> 6, l = t & 63;
    int wm = wid >> 1, wn = wid & 1;
    int srB = t >> 1, halfB = t & 1;
    int swB = (srB >> 1) & 3;
    int sB0 = (halfB * 2) ^ swB, sB1 = (halfB * 2 + 1) ^ swB;
    int srA = t >> 2, qA = t & 3;
    int sA = qA ^ ((srA >> 1) & 3);
    for (int k0 = 0; k0 < 512; k0 += 32) {
        const int4 a0 = *(const int4*)(A + (size_t)(m0 + srA) * 512 + k0 + qA * 8);
        const int4 b0 = *(const int4*)(B + (size_t)(n0 + srB) * 512 + k0 + halfB * 16);
        const int4 b1 = *(const int4*)(B + (size_t)(n0 + srB) * 512 + k0 + halfB * 16 + 8);
        __syncthreads();
        *(int4*)&As[srA][sA * 8] = a0;
        *(int4*)&Bs[srB][sB0 * 8] = b0;
        *(int4*)&Bs[srB][sB1 * 8] = b1;
        __syncthreads();
        bf16x8 af[2], bfr[4];
        #pragma unroll
        for (int mt = 0; mt < 2; ++mt) {
            int r = wm * 32 + mt * 16 + (l & 15);
            af[mt] = *(const bf16x8*)&As[r][(((l >> 4)) ^ ((r >> 1) & 3)) * 8];
        }
        #pragma unroll
        for (int nt = 0; nt < 4; ++nt) {
            int r = wn * 64 + nt * 16 + (l & 15);
            bfr[nt] = *(const bf16x8*)&Bs[r][(((l >> 4)) ^ ((r >> 1) & 3)) * 8];
        }
        #pragma unroll
        for (int mt = 0; mt < 2; ++mt)
            #pragma unroll
            for (int nt = 0; nt < 4; ++nt)
                acc[mt][nt] = __builtin_amdgcn_mfma_f32_16x16x32_bf16(
                    af[mt], bfr[nt], acc[mt][nt], 0, 0, 0);
    }
}

// q projection (dense [m][n] bf16 out); grid (64, 4) = 256 blocks
__global__ __launch_bounds__(256) void gemm_q(
    const short* __restrict__ A, const short* __restrict__ B,
    const float* __restrict__ bias, short* __restrict__ Ob)
{
    __shared__ short As[64][32];
    __shared__ short Bs[128][32];
    int m0 = blockIdx.x * 64, n0 = blockIdx.y * 128;
    int t = threadIdx.x, wid = t >> 6, l = t & 63;
    int wm = wid >> 1, wn = wid & 1;
    f32x4 acc[2][4] = {};
    nt_tile_64x128(A, B, m0, n0, t, As, Bs, acc);
    #pragma unroll
    for (int mt = 0; mt < 2; ++mt)
        #pragma unroll
        for (int nt = 0; nt < 4; ++nt)
            #pragma unroll
            for (int r = 0; r < 4; ++r) {
                int m = m0 + wm * 32 + mt * 16 + (l >> 4) * 4 + r;
                int n = n0 + wn * 64 + nt * 16 + (l & 15);
                Ob[(size_t)m * 512 + n] = f2bf(acc[mt][nt][r] + bias[n]);
            }
}

// k-gemm (bid<256, SWAPPED: D[channel][sample]) + v-gemm (bid>=256, SWAPPED:
// D[sample][channel]); operand swap makes each lane's 4 acc values hit 4
// CONSECUTIVE e positions of the fragment layout -> one coalesced uint2 store.
// Layouts unchanged:
// kfr[((bh*64+T)*2+frag)*64 + gg*16+cs][8] bf16; vfr[((bh*4+wg)*32+cc)*64+gg*16+cs][8] f16
__global__ __launch_bounds__(256) void gemm_kv(
    const short* __restrict__ xsb, const short* __restrict__ kwb,
    const float* __restrict__ k_b, short* __restrict__ kfr,
    const short* __restrict__ vwb, const float* __restrict__ v_b,
    short* __restrict__ vfr)
{
    __shared__ short As[64][32];
    __shared__ short Bs[128][32];
    int bid = blockIdx.x;
    int t = threadIdx.x, wid = t >> 6, l = t & 63;
    int wm = wid >> 1, wn = wid & 1;
    f32x4 acc[2][4] = {};
    if (bid < 256) {
        // K: m = channel (64 of one head), n = global sample
        int m0 = (bid >> 5) * 64, n0 = (bid & 31) * 128;
        nt_tile_64x128(kwb, xsb, m0, n0, t, As, Bs, acc);
        int h = m0 >> 6;
        #pragma unroll
        for (int mt = 0; mt < 2; ++mt) {
            int ch0 = m0 + wm * 32 + mt * 16 + (l >> 4) * 4;
            float4 kb4 = *(const float4*)(k_b + ch0);
            int frag = (ch0 >> 5) & 1, gg = (ch0 >> 3) & 3, e = ch0 & 7;
            #pragma unroll
            for (int nt = 0; nt < 4; ++nt) {
                int sm = n0 + wn * 64 + nt * 16 + (l & 15);
                int bq = sm >> 10, p = sm & 1023;
                int T = p >> 4, cs = p & 15;
                uint2 w;
                w.x = (unsigned)(unsigned short)f2bf(acc[mt][nt][0] + kb4.x)
                    | ((unsigned)(unsigned short)f2bf(acc[mt][nt][1] + kb4.y) << 16);
                w.y = (unsigned)(unsigned short)f2bf(acc[mt][nt][2] + kb4.z)
                    | ((unsigned)(unsigned short)f2bf(acc[mt][nt][3] + kb4.w) << 16);
                *(uint2*)(kfr + ((((size_t)(bq * 8 + h) * 64 + T) * 2 + frag) * 64
                                 + gg * 16 + cs) * 8 + e) = w;
            }
        }
    } else {
        // V: m = sample within batch z, n = channel
        int id2 = bid - 256;
        int z = id2 >> 6, rr2 = id2 & 63;
        int m0 = (rr2 >> 2) * 64, n0 = (rr2 & 3) * 128;
        nt_tile_64x128(xsb + (size_t)z * 524288, vwb, m0, n0, t, As, Bs, acc);
        #pragma unroll
        for (int mt = 0; mt < 2; ++mt) {
            int p0 = m0 + wm * 32 + mt * 16 + (l >> 4) * 4;
            int cc = p0 >> 5, gg = (p0 >> 3) & 3, e = p0 & 7;
            #pragma unroll
            for (int nt = 0; nt < 4; ++nt) {
                int ch = n0 + wn * 64 + nt * 16 + (l & 15);
                int h = ch >> 6, wg = (ch & 63) >> 4, cs = ch & 15;
                float vb = v_b[ch];
                h2 plo, phi;
                plo[0] = (_Float16)(acc[mt][nt][0] + vb);
                plo[1] = (_Float16)(acc[mt][nt][1] + vb);
                phi[0] = (_Float16)(acc[mt][nt][2] + vb);
                phi[1] = (_Float16)(acc[mt][nt][3] + vb);
                uint2 w;
                w.x = __builtin_bit_cast(unsigned, plo);
                w.y = __builtin_bit_cast(unsigned, phi);
                *(uint2*)(vfr + ((((size_t)(z * 8 + h) * 4 + wg) * 32 + cc) * 64
                                 + gg * 16 + cs) * 8 + e) = w;
            }
        }
    }
}

// ---------------------------------------------------------------------------
// FUSED offset network + deformable sampling
// ---------------------------------------------------------------------------
__global__ __launch_bounds__(256) void offset_sample(
    const short* __restrict__ qbf, const float* __restrict__ dw_w,
    const float* __restrict__ dw_b, const float* __restrict__ ln_w,
    const float* __restrict__ ln_b, const float* __restrict__ pw_w,
    const short* __restrict__ xt, float* __restrict__ pos,
    short* __restrict__ xs)
{
    __shared__ float red[8];
    __shared__ float2 psh;
    int bid = blockIdx.x;
    int b = bid >> 10, p = bid & 1023;
    int y = p >> 5, x = p & 31;
    int t = threadIdx.x;
    int c0 = 2 * t;
    const short* qb = qbf + (size_t)b * 524288;
    float h0, h1;
    {
        const float* w0 = dw_w + c0 * 9;
        const float* w1 = w0 + 9;
        float s0 = 0.f, s1 = 0.f;
        #pragma unroll
        for (int ky = 0; ky < 3; ++ky) {
            int yy = y + ky - 1;
            if (yy < 0 || yy > 31) continue;
            #pragma unroll
            for (int kx = 0; kx < 3; ++kx) {
                int xx = x + kx - 1;
                if (xx < 0 || xx > 31) continue;
                unsigned u = *(const unsigned*)(qb + (size_t)(yy * 32 + xx) * 512 + c0);
                s0 += bf2f((short)(u & 0xFFFF)) * w0[ky * 3 + kx];
                s1 += bf2f((short)(u >> 16)) * w1[ky * 3 + kx];
            }
        }
        float2 db = *(const float2*)(dw_b + c0);
        h0 = s0 + db.x; h1 = s1 + db.y;
    }
    float ls = h0 + h1;
    float lq = h0 * h0 + h1 * h1;
    #pragma unroll
    for (int s = 32; s >= 1; s >>= 1) {
        ls += __shfl_xor(ls, s);
        lq += __shfl_xor(lq, s);
    }
    int wid = t >> 6, lane = t & 63;
    if (lane == 0) { red[wid] = ls; red[4 + wid] = lq; }
    __syncthreads();
    float mu  = (red[0] + red[1] + red[2] + red[3]) * (1.f / 512.f);
    float var = (red[4] + red[5] + red[6] + red[7]) * (1.f / 512.f) - mu * mu;
    float rstd = rsqrtf(var + 1e-5f);
    float o0, o1;
    {
        float2 lw = *(const float2*)(ln_w + c0);
        float2 lb = *(const float2*)(ln_b + c0);
        float2 p0 = *(const float2*)(pw_w + c0);
        float2 p1 = *(const float2*)(pw_w + 512 + c0);
        float hn0 = (h0 - mu) * rstd * lw.x + lb.x;
        float hn1 = (h1 - mu) * rstd * lw.y + lb.y;
        float g0 = 0.5f * hn0 * (1.f + erff(hn0 * 0.70710678118f));
        float g1 = 0.5f * hn1 * (1.f + erff(hn1 * 0.70710678118f));
        o0 = g0 * p0.x + g1 * p0.y;
        o1 = g0 * p1.x + g1 * p1.y;
    }
    #pragma unroll
    for (int s = 32; s >= 1; s >>= 1) {
        o0 += __shfl_xor(o0, s);
        o1 += __shfl_xor(o1, s);
    }
    __syncthreads();
    if (lane == 0) { red[wid] = o0; red[4 + wid] = o1; }
    __syncthreads();
    if (t == 0) {
        float oy = tanhf(red[0] + red[1] + red[2] + red[3]) * 0.0625f;
        float ox = tanhf(red[4] + red[5] + red[6] + red[7]) * 0.0625f;
        float ry = ((y + 0.5f) * (1.f / 32.f)) * 2.f - 1.f;
        float rx = ((x + 0.5f) * (1.f / 32.f)) * 2.f - 1.f;
        float py = oy + ry, px = ox + rx;
        pos[bid * 2]     = py;
        pos[bid * 2 + 1] = px;
        psh = make_float2(py, px);
    }
    __syncthreads();
    float py = psh.x, px = psh.y;
    float gx = (px + 1.f) * 15.5f;
    float gy = (py + 1.f) * 15.5f;
    float x0f = floorf(gx), y0f = floorf(gy);
    int ix0 = (int)x0f, iy0 = (int)y0f;
    float wx1 = gx - x0f, wx0 = 1.f - wx1;
    float wy1 = gy - y0f, wy0 = 1.f - wy1;
    const short* base = xt + (size_t)b * 524288;
    float a0 = 0.f, a1 = 0.f;
    #pragma unroll
    for (int tap = 0; tap < 4; ++tap) {
        int ix = ix0 + (tap & 1), iy = iy0 + (tap >> 1);
        float w = ((tap & 1) ? wx1 : wx0) * ((tap >> 1) ? wy1 : wy0);
        if (ix >= 0 && ix < 32 && iy >= 0 && iy < 32) {
            unsigned u = *(const unsigned*)(base + (size_t)(iy * 32 + ix) * 512 + c0);
            a0 += bf2f((short)(u & 0xFFFF)) * w;
            a1 += bf2f((short)(u >> 16)) * w;
        }
    }
    unsigned o = ((unsigned)(unsigned short)f2bf(a0)) |
                 (((unsigned)(unsigned short)f2bf(a1)) << 16);
    *(unsigned*)(xs + (size_t)bid * 512 + c0) = o;
}

// ---------------------------------------------------------------------------
// FUSED attention, 512 threads, swapped QK^T, FRAGMENT-ORDERED K/V.
// XCD-pinned 1D grid; nontemporal attn/out streams; 2-deep K prefetch.
// ---------------------------------------------------------------------------
__global__ __launch_bounds__(512, 4) void attn_fused(
    const short* __restrict__ qbf, const short* __restrict__ kfr,
    const short* __restrict__ vfr, const float* __restrict__ pos,
    const unsigned* __restrict__ rpet, const float* __restrict__ x,
    const float* __restrict__ gamma, float* __restrict__ attn_out,
    float* __restrict__ out0)
{
    __shared__ __align__(16) char smem_raw[33024];   // rpe(16900)+ccs(8192) | Pn 16*1032*2
    __shared__ float S_part[16][8];
    h2*     rpe_s = (h2*)smem_raw;                    // [65*65] pair table (x log2e)
    float2* ccs   = (float2*)(smem_raw + 16960);      // [1024]
    short*  Pn    = (short*)smem_raw;                 // [16][1032] f16 RAW exp

    int bid = blockIdx.x;
    int xcd = bid & 7, seq = bid >> 3;
    int m0 = (seq & 63) * 16;
    int bh = xcd + 8 * (seq >> 6);          // h = bh & 7 == xcd
    int b = bh >> 3, h = bh & 7;
    int t = threadIdx.x, wn = t >> 6, l = t & 63;
    int g = l >> 4, c16 = l & 15;

    const unsigned* rt = rpet + h * 4225;
    #pragma unroll
    for (int i = 0; i < 9; ++i) {
        int e = i * 512 + t;
        if (e < 4225) ((unsigned*)rpe_s)[e] = rt[e];
    }
    #pragma unroll
    for (int i = 0; i < 2; ++i) {
        int idx = i * 512 + t;
        float2 pf = *(const float2*)(pos + b * 2048 + idx * 2);
        ccs[idx] = make_float2(fmaf(-15.5f, pf.x, 32.f), fmaf(-15.5f, pf.y, 32.f));
    }
    // q fragments (dense layout; only 2 loads/thread)
    int rowm = m0 + c16;
    const short* qrow = qbf + ((size_t)(b * 1024 + rowm) * 512 + h * 64 + g * 8);
    bf16x8 aq0 = *(const bf16x8*)qrow;
    bf16x8 aq1 = *(const bf16x8*)(qrow + 32);
    float qy = (((rowm >> 5) + 0.5f) * (1.f / 16.f) - 1.f) * 15.5f;
    float qx = (((rowm & 31) + 0.5f) * (1.f / 16.f) - 1.f) * 15.5f;
    __syncthreads();

    // ---- pass A: 8 n-tiles; K frags coalesced + 2-deep register prefetch
    float Ssum = 0.f;
    float e0, e1;
    unsigned ep[16];
    const short* kr = kfr + (size_t)(bh * 64 + wn * 8) * 1024 + l * 8;
    bf16x8 ka0 = *(const bf16x8*)kr;
    bf16x8 kb0 = *(const bf16x8*)(kr + 512);
    bf16x8 ka1 = *(const bf16x8*)(kr + 1024);
    bf16x8 kb1 = *(const bf16x8*)(kr + 1536);
    #pragma unroll
    for (int nt = 0; nt < 8; ++nt) {
        bf16x8 bk0 = ka0, bk1 = kb0;
        ka0 = ka1; kb0 = kb1;
        if (nt < 6) {
            ka1 = *(const bf16x8*)(kr + (nt + 2) * 1024);
            kb1 = *(const bf16x8*)(kr + (nt + 2) * 1024 + 512);
        }
        __builtin_amdgcn_s_setprio(1);
        f32x4 acc = {0.f, 0.f, 0.f, 0.f};
        acc = __builtin_amdgcn_mfma_f32_16x16x32_bf16(bk0, aq0, acc, 0, 0, 0);
        acc = __builtin_amdgcn_mfma_f32_16x16x32_bf16(bk1, aq1, acc, 0, 0, 0);
        __builtin_amdgcn_s_setprio(0);
        int nb = wn * 128 + nt * 16;
        #pragma unroll
        for (int r = 0; r < 4; ++r) {
            float2 cc = ccs[nb + g * 4 + r];           // broadcast across c16
            float gyp = qy + cc.x;
            float gxp = qx + cc.y;
            float fy = floorf(gyp), fx = floorf(gxp);
            float wy1 = gyp - fy, wx1 = gxp - fx;
            int ad = (int)(fy * 65.f + fx);
            h2 r0 = rpe_s[ad];
            h2 r1 = rpe_s[ad + 65];
            h2 wp = pkrtz(1.f - wx1, wx1);
            float t0 = dot2(r0, wp);
            float t1 = dot2(r1, wp);
            float bias2 = t0 + wy1 * (t1 - t0);        // already x log2e
            float logit2 = fmaf(acc[r], 0.1803368801f, bias2);  // 0.125*log2e
            float e = fast_exp2(logit2);
            Ssum += e;
            if (r == 0) e0 = e;
            else if (r == 1) ep[nt * 2] = __builtin_bit_cast(unsigned, pkrtz(e0, e));
            else if (r == 2) e1 = e;
            else ep[nt * 2 + 1] = __builtin_bit_cast(unsigned, pkrtz(e1, e));
        }
    }
    Ssum += __shfl_xor(Ssum, 16);
    Ssum += __shfl_xor(Ssum, 32);
    if (l < 16) S_part[c16][wn] = Ssum;
    __syncthreads();   // pass-A LDS reads done; rpe/ccs region dead
    float4 sa = *(const float4*)&S_part[c16][0];
    float4 sb = *(const float4*)&S_part[c16][4];
    float invS = 1.f / (sa.x + sa.y + sa.z + sa.w + sb.x + sb.y + sb.z + sb.w);

    // ---- raw exp pairs -> Pn[m=c16][n]
    short* prow = Pn + c16 * 1032 + wn * 128;
    #pragma unroll
    for (int nt = 0; nt < 8; ++nt) {
        uint2 w;
        w.x = ep[nt * 2];
        w.y = ep[nt * 2 + 1];
        *(uint2*)(prow + nt * 16 + g * 4) = w;
    }
    __syncthreads();

    size_t obase = ((size_t)(bh * 1024 + m0)) * 1024;
    if (wn >= 4) {
        // ---- attn fp32 stream: waves 4-7, nontemporal float4 stores
        int tw = t - 256;
        #pragma unroll
        for (int row = 0; row < 16; ++row) {
            float ivr = __shfl(invS, row);
            const unsigned* pr = (const unsigned*)(Pn + row * 1032 + tw * 4);
            unsigned u0 = pr[0], u1 = pr[1];
            h2 a = __builtin_bit_cast(h2, u0);
            h2 bb = __builtin_bit_cast(h2, u1);
            float4 vv = make_float4((float)a[0] * ivr, (float)a[1] * ivr,
                                    (float)bb[0] * ivr, (float)bb[1] * ivr);
            nt_store4(vv, attn_out + obase + (size_t)row * 1024 + tw * 4);
        }
    } else {
        // ---- PV: wave wn owns channels wn*16..+15; V fragment-ordered
        const short* Vb = vfr + (size_t)((bh * 4 + wn) * 32) * 512;
        const short* Prow = Pn + c16 * 1032 + g * 8;
        f32x4 dacc = {0.f, 0.f, 0.f, 0.f};
        __builtin_amdgcn_s_setprio(1);
        #pragma unroll
        for (int cc = 0; cc < 32; ++cc) {
            f16x8 pa  = *(const f16x8*)(Prow + cc * 32);
            f16x8 vb8 = *(const f16x8*)(Vb + cc * 512 + l * 8);
            dacc = __builtin_amdgcn_mfma_f32_16x16x32_f16(pa, vb8, dacc, 0, 0, 0);
        }
        __builtin_amdgcn_s_setprio(0);
        float gm = gamma[0];
        float gi0 = gm * __shfl(invS, g * 4);
        float gi1 = gm * __shfl(invS, g * 4 + 1);
        float gi2 = gm * __shfl(invS, g * 4 + 2);
        float gi3 = gm * __shfl(invS, g * 4 + 3);
        int ch = h * 64 + wn * 16 + c16;
        int m = m0 + g * 4;
        size_t idx = ((size_t)(b * 512 + ch)) * 1024 + m;
        float4 xv = *(const float4*)(x + idx);
        float4 ov;
        ov.x = gi0 * dacc[0] + xv.x;
        ov.y = gi1 * dacc[1] + xv.y;
        ov.z = gi2 * dacc[2] + xv.z;
        ov.w = gi3 * dacc[3] + xv.w;
        nt_store4(ov, out0 + idx);
    }
}

extern "C" void kernel_launch(void* const* d_in, const int* in_sizes, int n_in,
                              void* d_out, int out_size, void* d_ws, size_t ws_size,
                              hipStream_t stream) {
    const float* x     = (const float*)d_in[0];
    const float* dw_w  = (const float*)d_in[1];
    const float* dw_b  = (const float*)d_in[2];
    const float* ln_w  = (const float*)d_in[3];
    const float* ln_b  = (const float*)d_in[4];
    const float* pw_w  = (const float*)d_in[5];
    const float* q_w   = (const float*)d_in[6];
    const float* q_b   = (const float*)d_in[7];
    const float* k_w   = (const float*)d_in[8];
    const float* k_b   = (const float*)d_in[9];
    const float* v_w   = (const float*)d_in[10];
    const float* v_b   = (const float*)d_in[11];
    const float* rpe   = (const float*)d_in[12];
    const float* gamma = (const float*)d_in[13];

    float* out0 = (float*)d_out;
    float* attn = out0 + (size_t)4 * 512 * 1024;

    char* w = (char*)d_ws;
    short*    xt   = (short*)w;                    // 4 MB
    short*    qwb  = (short*)(w + 4194304);
    short*    kwb  = (short*)(w + 4718592);
    short*    vwb  = (short*)(w + 5242880);
    short*    qbf  = (short*)(w + 5767168);        // 4 MB dense q
    short*    xsb  = (short*)(w + 9961472);        // 4 MB
    short*    kfr  = (short*)(w + 14155776);       // 4 MB frag-ordered K
    short*    vfr  = (short*)(w + 18350080);       // 4 MB frag-ordered V (f16)
    float*    pos  = (float*)(w + 22544384);       // 32 KB
    unsigned* rpet = (unsigned*)(w + 22577152);    // 8*4225*4 = 135 KB

    prep_x<<<dim3(16, 8, 6), 256, 0, stream>>>(x, xt, q_w, k_w, v_w, qwb, kwb,
                                               vwb, rpe, rpet);
    gemm_q<<<dim3(64, 4), 256, 0, stream>>>(xt, qwb, q_b, qbf);
    offset_sample<<<4096, 256, 0, stream>>>(qbf, dw_w, dw_b, ln_w, ln_b, pw_w,
                                            xt, pos, xsb);
    gemm_kv<<<512, 256, 0, stream>>>(xsb, kwb, k_b, kfr, vwb, v_b, vfr);
    attn_fused<<<2048, 512, 0, stream>>>(qbf, kfr, vfr, pos, rpet, x,
                                         gamma, attn, out0);
}

// Round 15
// 108.907 us; speedup vs baseline: 4.0510x; 1.0027x over previous
//
#include <hip/hip_runtime.h>
#include <hip/hip_bf16.h>
#include <math.h>

typedef short bf16x8 __attribute__((ext_vector_type(8)));
typedef _Float16 f16x8 __attribute__((ext_vector_type(8)));
typedef float f32x4 __attribute__((ext_vector_type(4)));
typedef _Float16 h2 __attribute__((ext_vector_type(2)));

__device__ inline short f2bf(float f) {
    union { float f; unsigned u; } v; v.f = f;
    unsigned r = v.u + 0x7FFFu + ((v.u >> 16) & 1u);
    return (short)(r >> 16);
}
__device__ inline float bf2f(short s) {
    union { unsigned u; float f; } v; v.u = ((unsigned)(unsigned short)s) << 16;
    return v.f;
}
__device__ inline h2 pkrtz(float a, float b) {
    return __builtin_bit_cast(h2, __builtin_amdgcn_cvt_pkrtz(a, b));
}
__device__ inline float fast_exp2(float x) {
    float r;
    asm("v_exp_f32 %0, %1" : "=v"(r) : "v"(x));
    return r;
}
__device__ inline float dot2(h2 a, h2 b) {
#if __has_builtin(__builtin_amdgcn_fdot2)
    return __builtin_amdgcn_fdot2(a, b, 0.f, false);
#else
    return (float)a[0] * (float)b[0] + (float)a[1] * (float)b[1];
#endif
}
__device__ inline void nt_store4(float4 v, float* p) {
    __builtin_nontemporal_store(__builtin_bit_cast(f32x4, v), (f32x4*)p);
}

// ---------------------------------------------------------------------------
// z<4: transpose-cast x -> xt [b][p][c] bf16.  z==4: weight cast.
// z==5 (x<8,y==0): per-head 64x64 QUAD RPE table (4 bilinear taps packed as
// 4xf16 in 8B, pre-scaled by log2e). Entry (fy,fx) = taps at rows fy,fy+1 and
// cols fx,fx+1 of the zero-padded 65x65 grid.
// ---------------------------------------------------------------------------
__global__ __launch_bounds__(256) void prep_x(
    const float* __restrict__ x, short* __restrict__ xt,
    const float* __restrict__ qw, const float* __restrict__ kw,
    const float* __restrict__ vw, short* __restrict__ qwb,
    short* __restrict__ kwb, short* __restrict__ vwb,
    const float* __restrict__ rpe, uint2* __restrict__ rpet)
{
    __shared__ float ts[64][65];
    int t = threadIdx.x;
    if (blockIdx.z == 5) {   // quad RPE plane: head = blockIdx.x
        if (blockIdx.y != 0 || blockIdx.x >= 8) return;
        int hh = blockIdx.x;
        const float* rh = rpe + hh * 3969;
        const float L2E = 1.44269504f;
        auto P = [&](int y, int xx) -> float {
            return (y >= 1 && y <= 63 && xx >= 1 && xx <= 63)
                 ? rh[(y - 1) * 63 + (xx - 1)] * L2E : 0.f;
        };
        #pragma unroll
        for (int i = 0; i < 16; ++i) {
            int j = i * 256 + t;          // j < 4096
            int qy = j >> 6, qx = j & 63;
            h2 lo, hi;
            lo[0] = (_Float16)P(qy, qx);     lo[1] = (_Float16)P(qy, qx + 1);
            hi[0] = (_Float16)P(qy + 1, qx); hi[1] = (_Float16)P(qy + 1, qx + 1);
            uint2 w;
            w.x = __builtin_bit_cast(unsigned, lo);
            w.y = __builtin_bit_cast(unsigned, hi);
            rpet[hh * 4096 + j] = w;
        }
        return;
    }
    if (blockIdx.z == 4) {   // weight cast plane
        int f = blockIdx.y * 16 + blockIdx.x;
        int base = (f * 256 + t) * 8;
        #pragma unroll
        for (int w = 0; w < 3; ++w) {
            const float* src = (w == 0) ? qw : (w == 1) ? kw : vw;
            short* dst = (w == 0) ? qwb : (w == 1) ? kwb : vwb;
            float4 f0 = *(const float4*)(src + base);
            float4 f1 = *(const float4*)(src + base + 4);
            bf16x8 o;
            o[0] = f2bf(f0.x); o[1] = f2bf(f0.y); o[2] = f2bf(f0.z); o[3] = f2bf(f0.w);
            o[4] = f2bf(f1.x); o[5] = f2bf(f1.y); o[6] = f2bf(f1.z); o[7] = f2bf(f1.w);
            *(bf16x8*)(dst + base) = o;
        }
        return;
    }
    int p0 = blockIdx.x * 64, c0 = blockIdx.y * 64, b = blockIdx.z;
    #pragma unroll
    for (int i = 0; i < 16; ++i) {
        int idx = i * 256 + t;
        int cl = idx >> 6, pl = idx & 63;
        ts[cl][pl] = x[((size_t)(b * 512 + c0 + cl)) * 1024 + p0 + pl];
    }
    __syncthreads();
    #pragma unroll
    for (int i = 0; i < 16; ++i) {
        int idx = i * 256 + t;
        int pl = idx >> 6, cl = idx & 63;
        xt[((size_t)(b * 1024 + p0 + pl)) * 512 + c0 + cl] = f2bf(ts[cl][pl]);
    }
}

// ---------------------------------------------------------------------------
// 64x128 NT MFMA tile body (K=512): acc[2][4] per thread; 12 KB LDS.
// ---------------------------------------------------------------------------
__device__ inline void nt_tile_64x128(const short* __restrict__ A,
                                      const short* __restrict__ B,
                                      int m0, int n0, int t,
                                      short (*As)[32], short (*Bs)[32],
                                      f32x4 (&acc)[2][4])
{
    int wid = t >> 6, l = t & 63;
    int wm = wid >> 1, wn = wid & 1;
    int srB = t >> 1, halfB = t & 1;
    int swB = (srB >> 1) & 3;
    int sB0 = (halfB * 2) ^ swB, sB1 = (halfB * 2 + 1) ^ swB;
    int srA = t >> 2, qA = t & 3;
    int sA = qA ^ ((srA >> 1) & 3);
    for (int k0 = 0; k0 < 512; k0 += 32) {
        const int4 a0 = *(const int4*)(A + (size_t)(m0 + srA) * 512 + k0 + qA * 8);
        const int4 b0 = *(const int4*)(B + (size_t)(n0 + srB) * 512 + k0 + halfB * 16);
        const int4 b1 = *(const int4*)(B + (size_t)(n0 + srB) * 512 + k0 + halfB * 16 + 8);
        __syncthreads();
        *(int4*)&As[srA][sA * 8] = a0;
        *(int4*)&Bs[srB][sB0 * 8] = b0;
        *(int4*)&Bs[srB][sB1 * 8] = b1;
        __syncthreads();
        bf16x8 af[2], bfr[4];
        #pragma unroll
        for (int mt = 0; mt < 2; ++mt) {
            int r = wm * 32 + mt * 16 + (l & 15);
            af[mt] = *(const bf16x8*)&As[r][(((l >> 4)) ^ ((r >> 1) & 3)) * 8];
        }
        #pragma unroll
        for (int nt = 0; nt < 4; ++nt) {
            int r = wn * 64 + nt * 16 + (l & 15);
            bfr[nt] = *(const bf16x8*)&Bs[r][(((l >> 4)) ^ ((r >> 1) & 3)) * 8];
        }
        #pragma unroll
        for (int mt = 0; mt < 2; ++mt)
            #pragma unroll
            for (int nt = 0; nt < 4; ++nt)
                acc[mt][nt] = __builtin_amdgcn_mfma_f32_16x16x32_bf16(
                    af[mt], bfr[nt], acc[mt][nt], 0, 0, 0);
    }
}

// q projection (dense [m][n] bf16 out); grid (64, 4) = 256 blocks
__global__ __launch_bounds__(256) void gemm_q(
    const short* __restrict__ A, const short* __restrict__ B,
    const float* __restrict__ bias, short* __restrict__ Ob)
{
    __shared__ short As[64][32];
    __shared__ short Bs[128][32];
    int m0 = blockIdx.x * 64, n0 = blockIdx.y * 128;
    int t = threadIdx.x, wid = t >> 6, l = t & 63;
    int wm = wid >> 1, wn = wid & 1;
    f32x4 acc[2][4] = {};
    nt_tile_64x128(A, B, m0, n0, t, As, Bs, acc);
    #pragma unroll
    for (int mt = 0; mt < 2; ++mt)
        #pragma unroll
        for (int nt = 0; nt < 4; ++nt)
            #pragma unroll
            for (int r = 0; r < 4; ++r) {
                int m = m0 + wm * 32 + mt * 16 + (l >> 4) * 4 + r;
                int n = n0 + wn * 64 + nt * 16 + (l & 15);
                Ob[(size_t)m * 512 + n] = f2bf(acc[mt][nt][r] + bias[n]);
            }
}

// k-gemm (bid<256, SWAPPED: D[channel][sample]) + v-gemm (bid>=256, SWAPPED:
// D[sample][channel]); coalesced uint2 fragment-order stores.
__global__ __launch_bounds__(256) void gemm_kv(
    const short* __restrict__ xsb, const short* __restrict__ kwb,
    const float* __restrict__ k_b, short* __restrict__ kfr,
    const short* __restrict__ vwb, const float* __restrict__ v_b,
    short* __restrict__ vfr)
{
    __shared__ short As[64][32];
    __shared__ short Bs[128][32];
    int bid = blockIdx.x;
    int t = threadIdx.x, wid = t >> 6, l = t & 63;
    int wm = wid >> 1, wn = wid & 1;
    f32x4 acc[2][4] = {};
    if (bid < 256) {
        int m0 = (bid >> 5) * 64, n0 = (bid & 31) * 128;
        nt_tile_64x128(kwb, xsb, m0, n0, t, As, Bs, acc);
        int h = m0 >> 6;
        #pragma unroll
        for (int mt = 0; mt < 2; ++mt) {
            int ch0 = m0 + wm * 32 + mt * 16 + (l >> 4) * 4;
            float4 kb4 = *(const float4*)(k_b + ch0);
            int frag = (ch0 >> 5) & 1, gg = (ch0 >> 3) & 3, e = ch0 & 7;
            #pragma unroll
            for (int nt = 0; nt < 4; ++nt) {
                int sm = n0 + wn * 64 + nt * 16 + (l & 15);
                int bq = sm >> 10, p = sm & 1023;
                int T = p >> 4, cs = p & 15;
                uint2 w;
                w.x = (unsigned)(unsigned short)f2bf(acc[mt][nt][0] + kb4.x)
                    | ((unsigned)(unsigned short)f2bf(acc[mt][nt][1] + kb4.y) << 16);
                w.y = (unsigned)(unsigned short)f2bf(acc[mt][nt][2] + kb4.z)
                    | ((unsigned)(unsigned short)f2bf(acc[mt][nt][3] + kb4.w) << 16);
                *(uint2*)(kfr + ((((size_t)(bq * 8 + h) * 64 + T) * 2 + frag) * 64
                                 + gg * 16 + cs) * 8 + e) = w;
            }
        }
    } else {
        int id2 = bid - 256;
        int z = id2 >> 6, rr2 = id2 & 63;
        int m0 = (rr2 >> 2) * 64, n0 = (rr2 & 3) * 128;
        nt_tile_64x128(xsb + (size_t)z * 524288, vwb, m0, n0, t, As, Bs, acc);
        #pragma unroll
        for (int mt = 0; mt < 2; ++mt) {
            int p0 = m0 + wm * 32 + mt * 16 + (l >> 4) * 4;
            int cc = p0 >> 5, gg = (p0 >> 3) & 3, e = p0 & 7;
            #pragma unroll
            for (int nt = 0; nt < 4; ++nt) {
                int ch = n0 + wn * 64 + nt * 16 + (l & 15);
                int h = ch >> 6, wg = (ch & 63) >> 4, cs = ch & 15;
                float vb = v_b[ch];
                h2 plo, phi;
                plo[0] = (_Float16)(acc[mt][nt][0] + vb);
                plo[1] = (_Float16)(acc[mt][nt][1] + vb);
                phi[0] = (_Float16)(acc[mt][nt][2] + vb);
                phi[1] = (_Float16)(acc[mt][nt][3] + vb);
                uint2 w;
                w.x = __builtin_bit_cast(unsigned, plo);
                w.y = __builtin_bit_cast(unsigned, phi);
                *(uint2*)(vfr + ((((size_t)(z * 8 + h) * 4 + wg) * 32 + cc) * 64
                                 + gg * 16 + cs) * 8 + e) = w;
            }
        }
    }
}

// ---------------------------------------------------------------------------
// FUSED offset network + deformable sampling
// ---------------------------------------------------------------------------
__global__ __launch_bounds__(256) void offset_sample(
    const short* __restrict__ qbf, const float* __restrict__ dw_w,
    const float* __restrict__ dw_b, const float* __restrict__ ln_w,
    const float* __restrict__ ln_b, const float* __restrict__ pw_w,
    const short* __restrict__ xt, float* __restrict__ pos,
    short* __restrict__ xs)
{
    __shared__ float red[8];
    __shared__ float2 psh;
    int bid = blockIdx.x;
    int b = bid >> 10, p = bid & 1023;
    int y = p >> 5, x = p & 31;
    int t = threadIdx.x;
    int c0 = 2 * t;
    const short* qb = qbf + (size_t)b * 524288;
    float h0, h1;
    {
        const float* w0 = dw_w + c0 * 9;
        const float* w1 = w0 + 9;
        float s0 = 0.f, s1 = 0.f;
        #pragma unroll
        for (int ky = 0; ky < 3; ++ky) {
            int yy = y + ky - 1;
            if (yy < 0 || yy > 31) continue;
            #pragma unroll
            for (int kx = 0; kx < 3; ++kx) {
                int xx = x + kx - 1;
                if (xx < 0 || xx > 31) continue;
                unsigned u = *(const unsigned*)(qb + (size_t)(yy * 32 + xx) * 512 + c0);
                s0 += bf2f((short)(u & 0xFFFF)) * w0[ky * 3 + kx];
                s1 += bf2f((short)(u >> 16)) * w1[ky * 3 + kx];
            }
        }
        float2 db = *(const float2*)(dw_b + c0);
        h0 = s0 + db.x; h1 = s1 + db.y;
    }
    float ls = h0 + h1;
    float lq = h0 * h0 + h1 * h1;
    #pragma unroll
    for (int s = 32; s >= 1; s >>= 1) {
        ls += __shfl_xor(ls, s);
        lq += __shfl_xor(lq, s);
    }
    int wid = t >> 6, lane = t & 63;
    if (lane == 0) { red[wid] = ls; red[4 + wid] = lq; }
    __syncthreads();
    float mu  = (red[0] + red[1] + red[2] + red[3]) * (1.f / 512.f);
    float var = (red[4] + red[5] + red[6] + red[7]) * (1.f / 512.f) - mu * mu;
    float rstd = rsqrtf(var + 1e-5f);
    float o0, o1;
    {
        float2 lw = *(const float2*)(ln_w + c0);
        float2 lb = *(const float2*)(ln_b + c0);
        float2 p0 = *(const float2*)(pw_w + c0);
        float2 p1 = *(const float2*)(pw_w + 512 + c0);
        float hn0 = (h0 - mu) * rstd * lw.x + lb.x;
        float hn1 = (h1 - mu) * rstd * lw.y + lb.y;
        float g0 = 0.5f * hn0 * (1.f + erff(hn0 * 0.70710678118f));
        float g1 = 0.5f * hn1 * (1.f + erff(hn1 * 0.70710678118f));
        o0 = g0 * p0.x + g1 * p0.y;
        o1 = g0 * p1.x + g1 * p1.y;
    }
    #pragma unroll
    for (int s = 32; s >= 1; s >>= 1) {
        o0 += __shfl_xor(o0, s);
        o1 += __shfl_xor(o1, s);
    }
    __syncthreads();
    if (lane == 0) { red[wid] = o0; red[4 + wid] = o1; }
    __syncthreads();
    if (t == 0) {
        float oy = tanhf(red[0] + red[1] + red[2] + red[3]) * 0.0625f;
        float ox = tanhf(red[4] + red[5] + red[6] + red[7]) * 0.0625f;
        float ry = ((y + 0.5f) * (1.f / 32.f)) * 2.f - 1.f;
        float rx = ((x + 0.5f) * (1.f / 32.f)) * 2.f - 1.f;
        float py = oy + ry, px = ox + rx;
        pos[bid * 2]     = py;
        pos[bid * 2 + 1] = px;
        psh = make_float2(py, px);
    }
    __syncthreads();
    float py = psh.x, px = psh.y;
    float gx = (px + 1.f) * 15.5f;
    float gy = (py + 1.f) * 15.5f;
    float x0f = floorf(gx), y0f = floorf(gy);
    int ix0 = (int)x0f, iy0 = (int)y0f;
    float wx1 = gx - x0f, wx0 = 1.f - wx1;
    float wy1 = gy - y0f, wy0 = 1.f - wy1;
    const short* base = xt + (size_t)b * 524288;
    float a0 = 0.f, a1 = 0.f;
    #pragma unroll
    for (int tap = 0; tap < 4; ++tap) {
        int ix = ix0 + (tap & 1), iy = iy0 + (tap >> 1);
        float w = ((tap & 1) ? wx1 : wx0) * ((tap >> 1) ? wy1 : wy0);
        if (ix >= 0 && ix < 32 && iy >= 0 && iy < 32) {
            unsigned u = *(const unsigned*)(base + (size_t)(iy * 32 + ix) * 512 + c0);
            a0 += bf2f((short)(u & 0xFFFF)) * w;
            a1 += bf2f((short)(u >> 16)) * w;
        }
    }
    unsigned o = ((unsigned)(unsigned short)f2bf(a0)) |
                 (((unsigned)(unsigned short)f2bf(a1)) << 16);
    *(unsigned*)(xs + (size_t)bid * 512 + c0) = o;
}

// ---------------------------------------------------------------------------
// FUSED attention, 512 threads, swapped QK^T, FRAGMENT-ORDERED K/V,
// QUAD RPE table (1 ds_read_b64 per logit), b128 ccs reads.
// LDS: [0,32768) quad table | [32768,40960) ccs ; after pass A barrier the
// whole region is dead -> Pn raw-exp [0,33024) + S_part @33536.
// ---------------------------------------------------------------------------
__global__ __launch_bounds__(512, 4) void attn_fused(
    const short* __restrict__ qbf, const short* __restrict__ kfr,
    const short* __restrict__ vfr, const float* __restrict__ pos,
    const uint2* __restrict__ rpet, const float* __restrict__ x,
    const float* __restrict__ gamma, float* __restrict__ attn_out,
    float* __restrict__ out0)
{
    __shared__ __align__(16) char smem_raw[40960];
    uint2*  rpq    = (uint2*)smem_raw;                // [64*64] quad table
    float*  ccsf   = (float*)(smem_raw + 32768);      // [1024*2] (cy,cx) pairs
    short*  Pn     = (short*)smem_raw;                // [16][1032] f16 RAW exp
    float*  S_part = (float*)(smem_raw + 33536);      // [16][8]

    int bid = blockIdx.x;
    int xcd = bid & 7, seq = bid >> 3;
    int m0 = (seq & 63) * 16;
    int bh = xcd + 8 * (seq >> 6);          // h = bh & 7 == xcd
    int b = bh >> 3, h = bh & 7;
    int t = threadIdx.x, wn = t >> 6, l = t & 63;
    int g = l >> 4, c16 = l & 15;

    const uint2* rt = rpet + h * 4096;
    #pragma unroll
    for (int i = 0; i < 8; ++i)
        rpq[i * 512 + t] = rt[i * 512 + t];
    #pragma unroll
    for (int i = 0; i < 2; ++i) {
        int idx = i * 512 + t;
        float2 pf = *(const float2*)(pos + b * 2048 + idx * 2);
        ccsf[idx * 2]     = fmaf(-15.5f, pf.x, 32.f);
        ccsf[idx * 2 + 1] = fmaf(-15.5f, pf.y, 32.f);
    }
    // q fragments (dense layout; only 2 loads/thread)
    int rowm = m0 + c16;
    const short* qrow = qbf + ((size_t)(b * 1024 + rowm) * 512 + h * 64 + g * 8);
    bf16x8 aq0 = *(const bf16x8*)qrow;
    bf16x8 aq1 = *(const bf16x8*)(qrow + 32);
    float qy = (((rowm >> 5) + 0.5f) * (1.f / 16.f) - 1.f) * 15.5f;
    float qx = (((rowm & 31) + 0.5f) * (1.f / 16.f) - 1.f) * 15.5f;
    __syncthreads();

    // ---- pass A: 8 n-tiles; K frags coalesced + 2-deep register prefetch
    float Ssum = 0.f;
    float e0, e1;
    unsigned ep[16];
    const short* kr = kfr + (size_t)(bh * 64 + wn * 8) * 1024 + l * 8;
    bf16x8 ka0 = *(const bf16x8*)kr;
    bf16x8 kb0 = *(const bf16x8*)(kr + 512);
    bf16x8 ka1 = *(const bf16x8*)(kr + 1024);
    bf16x8 kb1 = *(const bf16x8*)(kr + 1536);
    #pragma unroll
    for (int nt = 0; nt < 8; ++nt) {
        bf16x8 bk0 = ka0, bk1 = kb0;
        ka0 = ka1; kb0 = kb1;
        if (nt < 6) {
            ka1 = *(const bf16x8*)(kr + (nt + 2) * 1024);
            kb1 = *(const bf16x8*)(kr + (nt + 2) * 1024 + 512);
        }
        __builtin_amdgcn_s_setprio(1);
        f32x4 acc = {0.f, 0.f, 0.f, 0.f};
        acc = __builtin_amdgcn_mfma_f32_16x16x32_bf16(bk0, aq0, acc, 0, 0, 0);
        acc = __builtin_amdgcn_mfma_f32_16x16x32_bf16(bk1, aq1, acc, 0, 0, 0);
        __builtin_amdgcn_s_setprio(0);
        int nb = wn * 128 + nt * 16;
        const float* cbase = ccsf + (nb + g * 4) * 2;
        float4 c01 = *(const float4*)cbase;        // (cy,cx) for r=0,1
        float4 c23 = *(const float4*)(cbase + 4);  // (cy,cx) for r=2,3
        #pragma unroll
        for (int r = 0; r < 4; ++r) {
            float cy = (r == 0) ? c01.x : (r == 1) ? c01.z : (r == 2) ? c23.x : c23.z;
            float cx = (r == 0) ? c01.y : (r == 1) ? c01.w : (r == 2) ? c23.y : c23.w;
            float gyp = qy + cy;
            float gxp = qx + cx;
            float fy = floorf(gyp), fx = floorf(gxp);
            float wy1 = gyp - fy, wx1 = gxp - fx;
            int ad = (int)(fy * 64.f + fx);
            uint2 q4 = rpq[ad];                      // all 4 taps, one b64
            h2 lo = __builtin_bit_cast(h2, q4.x);
            h2 hi = __builtin_bit_cast(h2, q4.y);
            h2 wp = pkrtz(1.f - wx1, wx1);
            float t0 = dot2(lo, wp);
            float t1 = dot2(hi, wp);
            float bias2 = t0 + wy1 * (t1 - t0);      // already x log2e
            float logit2 = fmaf(acc[r], 0.1803368801f, bias2);  // 0.125*log2e
            float e = fast_exp2(logit2);
            Ssum += e;
            if (r == 0) e0 = e;
            else if (r == 1) ep[nt * 2] = __builtin_bit_cast(unsigned, pkrtz(e0, e));
            else if (r == 2) e1 = e;
            else ep[nt * 2 + 1] = __builtin_bit_cast(unsigned, pkrtz(e1, e));
        }
    }
    Ssum += __shfl_xor(Ssum, 16);
    Ssum += __shfl_xor(Ssum, 32);
    __syncthreads();   // ALL pass-A LDS reads retired; quad/ccs region dead
    if (l < 16) S_part[c16 * 8 + wn] = Ssum;
    // ---- raw exp pairs -> Pn[m=c16][n]
    short* prow = Pn + c16 * 1032 + wn * 128;
    #pragma unroll
    for (int nt = 0; nt < 8; ++nt) {
        uint2 w;
        w.x = ep[nt * 2];
        w.y = ep[nt * 2 + 1];
        *(uint2*)(prow + nt * 16 + g * 4) = w;
    }
    __syncthreads();
    float4 sa = *(const float4*)&S_part[c16 * 8];
    float4 sb = *(const float4*)&S_part[c16 * 8 + 4];
    float invS = 1.f / (sa.x + sa.y + sa.z + sa.w + sb.x + sb.y + sb.z + sb.w);

    size_t obase = ((size_t)(bh * 1024 + m0)) * 1024;
    if (wn >= 4) {
        // ---- attn fp32 stream: waves 4-7, nontemporal float4 stores
        int tw = t - 256;
        #pragma unroll
        for (int row = 0; row < 16; ++row) {
            float ivr = __shfl(invS, row);
            uint2 pr8 = *(const uint2*)(Pn + row * 1032 + tw * 4);
            h2 a = __builtin_bit_cast(h2, pr8.x);
            h2 bb = __builtin_bit_cast(h2, pr8.y);
            float4 vv = make_float4((float)a[0] * ivr, (float)a[1] * ivr,
                                    (float)bb[0] * ivr, (float)bb[1] * ivr);
            nt_store4(vv, attn_out + obase + (size_t)row * 1024 + tw * 4);
        }
    } else {
        // ---- PV: wave wn owns channels wn*16..+15; V fragment-ordered
        const short* Vb = vfr + (size_t)((bh * 4 + wn) * 32) * 512;
        const short* Prow = Pn + c16 * 1032 + g * 8;
        f32x4 dacc = {0.f, 0.f, 0.f, 0.f};
        __builtin_amdgcn_s_setprio(1);
        #pragma unroll
        for (int cc = 0; cc < 32; ++cc) {
            f16x8 pa  = *(const f16x8*)(Prow + cc * 32);
            f16x8 vb8 = *(const f16x8*)(Vb + cc * 512 + l * 8);
            dacc = __builtin_amdgcn_mfma_f32_16x16x32_f16(pa, vb8, dacc, 0, 0, 0);
        }
        __builtin_amdgcn_s_setprio(0);
        float gm = gamma[0];
        float gi0 = gm * __shfl(invS, g * 4);
        float gi1 = gm * __shfl(invS, g * 4 + 1);
        float gi2 = gm * __shfl(invS, g * 4 + 2);
        float gi3 = gm * __shfl(invS, g * 4 + 3);
        int ch = h * 64 + wn * 16 + c16;
        int m = m0 + g * 4;
        size_t idx = ((size_t)(b * 512 + ch)) * 1024 + m;
        float4 xv = *(const float4*)(x + idx);
        float4 ov;
        ov.x = gi0 * dacc[0] + xv.x;
        ov.y = gi1 * dacc[1] + xv.y;
        ov.z = gi2 * dacc[2] + xv.z;
        ov.w = gi3 * dacc[3] + xv.w;
        nt_store4(ov, out0 + idx);
    }
}

extern "C" void kernel_launch(void* const* d_in, const int* in_sizes, int n_in,
                              void* d_out, int out_size, void* d_ws, size_t ws_size,
                              hipStream_t stream) {
    const float* x     = (const float*)d_in[0];
    const float* dw_w  = (const float*)d_in[1];
    const float* dw_b  = (const float*)d_in[2];
    const float* ln_w  = (const float*)d_in[3];
    const float* ln_b  = (const float*)d_in[4];
    const float* pw_w  = (const float*)d_in[5];
    const float* q_w   = (const float*)d_in[6];
    const float* q_b   = (const float*)d_in[7];
    const float* k_w   = (const float*)d_in[8];
    const float* k_b   = (const float*)d_in[9];
    const float* v_w   = (const float*)d_in[10];
    const float* v_b   = (const float*)d_in[11];
    const float* rpe   = (const float*)d_in[12];
    const float* gamma = (const float*)d_in[13];

    float* out0 = (float*)d_out;
    float* attn = out0 + (size_t)4 * 512 * 1024;

    char* w = (char*)d_ws;
    short*    xt   = (short*)w;                    // 4 MB
    short*    qwb  = (short*)(w + 4194304);
    short*    kwb  = (short*)(w + 4718592);
    short*    vwb  = (short*)(w + 5242880);
    short*    qbf  = (short*)(w + 5767168);        // 4 MB dense q
    short*    xsb  = (short*)(w + 9961472);        // 4 MB
    short*    kfr  = (short*)(w + 14155776);       // 4 MB frag-ordered K
    short*    vfr  = (short*)(w + 18350080);       // 4 MB frag-ordered V (f16)
    float*    pos  = (float*)(w + 22544384);       // 32 KB
    uint2*    rpet = (uint2*)(w + 22577152);       // 8*4096*8 = 256 KB quad table

    prep_x<<<dim3(16, 8, 6), 256, 0, stream>>>(x, xt, q_w, k_w, v_w, qwb, kwb,
                                               vwb, rpe, rpet);
    gemm_q<<<dim3(64, 4), 256, 0, stream>>>(xt, qwb, q_b, qbf);
    offset_sample<<<4096, 256, 0, stream>>>(qbf, dw_w, dw_b, ln_w, ln_b, pw_w,
                                            xt, pos, xsb);
    gemm_kv<<<512, 256, 0, stream>>>(xsb, kwb, k_b, kfr, vwb, v_b, vfr);
    attn_fused<<<2048, 512, 0, stream>>>(qbf, kfr, vfr, pos, rpet, x,
                                         gamma, attn, out0);
}